// Round 1
// baseline (349.932 us; speedup 1.0000x reference)
//
#include <hip/hip_runtime.h>
#include <math.h>

#define NEG_SLOPE 0.2f

__device__ __forceinline__ float lrelu(float x){ return x > 0.f ? x : NEG_SLOPE*x; }

// ---------------- GEMM1: h[N,128] = x[N,128] @ W1[128,128] ----------------
__global__ __launch_bounds__(256) void k_gemm1(const float* __restrict__ x,
                                               const float* __restrict__ W,
                                               float* __restrict__ hout, int N)
{
    __shared__ __align__(16) float xs[32][68];   // [k][row], transposed x tile
    __shared__ __align__(16) float wl[32][140];  // [k][skewed col], +4 words per 32 cols
    const int tid = threadIdx.x;
    const int tr = tid >> 4, tc = tid & 15;      // 16x16 thread tile
    const int row0 = blockIdx.x * 64;
    const int rr  = tid & 63;                    // x-load: row
    const int kk0 = (tid >> 6) << 3;             // x-load: k group (8 wide)
    const int kw  = tid >> 3;                    // W-load: k row
    const int jc  = (tid & 7) << 4;              // W-load: col base (16 wide)
    const int jb  = tc << 3;                     // compute: col base (8 wide)
    const int pb  = jb + ((jb >> 5) << 2);       // skewed col base
    float acc[4][8];
    #pragma unroll
    for (int r=0;r<4;r++)
        #pragma unroll
        for (int c=0;c<8;c++) acc[r][c]=0.f;

    for (int kc = 0; kc < 128; kc += 32) {
        int gr = row0 + rr;
        float4 a0 = make_float4(0,0,0,0), a1 = a0;
        if (gr < N) {
            const float* xp = &x[(size_t)gr*128 + kc + kk0];
            a0 = *(const float4*)xp;
            a1 = *(const float4*)(xp+4);
        }
        xs[kk0+0][rr]=a0.x; xs[kk0+1][rr]=a0.y; xs[kk0+2][rr]=a0.z; xs[kk0+3][rr]=a0.w;
        xs[kk0+4][rr]=a1.x; xs[kk0+5][rr]=a1.y; xs[kk0+6][rr]=a1.z; xs[kk0+7][rr]=a1.w;
        const float* wsrc = &W[(size_t)(kc+kw)*128 + jc];
        #pragma unroll
        for (int q=0;q<4;q++){
            float4 wv = *(const float4*)(wsrc + q*4);
            int j = jc + q*4;
            int p = j + ((j>>5)<<2);
            *(float4*)&wl[kw][p] = wv;
        }
        __syncthreads();
        #pragma unroll
        for (int k=0;k<32;k++){
            float4 xv = *(float4*)&xs[k][tr<<2];
            float4 w0 = *(float4*)&wl[k][pb];
            float4 w1 = *(float4*)&wl[k][pb+4];
            float xr[4]={xv.x,xv.y,xv.z,xv.w};
            float wv[8]={w0.x,w0.y,w0.z,w0.w,w1.x,w1.y,w1.z,w1.w};
            #pragma unroll
            for (int r=0;r<4;r++)
                #pragma unroll
                for (int c=0;c<8;c++) acc[r][c] = fmaf(xr[r], wv[c], acc[r][c]);
        }
        __syncthreads();
    }
    #pragma unroll
    for (int r=0;r<4;r++){
        int gr = row0 + (tr<<2) + r;
        if (gr < N){
            float4 o0 = make_float4(acc[r][0],acc[r][1],acc[r][2],acc[r][3]);
            float4 o1 = make_float4(acc[r][4],acc[r][5],acc[r][6],acc[r][7]);
            float* hp = &hout[(size_t)gr*128 + jb];
            *(float4*)hp = o0;
            *(float4*)(hp+4) = o1;
        }
    }
}

// ---------------- alpha_src / alpha_dst for layer 1 (wave per node) ----------------
__global__ __launch_bounds__(256) void k_alpha1(const float* __restrict__ h,
        const float* __restrict__ asrc, const float* __restrict__ adst,
        float* __restrict__ as1, float* __restrict__ ad1, int N)
{
    int wid = (blockIdx.x << 2) + (threadIdx.x >> 6);
    int lane = threadIdx.x & 63;
    if (wid >= N) return;
    float v0 = h[(size_t)wid*128 + lane];        // heads 0,1
    float v1 = h[(size_t)wid*128 + 64 + lane];   // heads 2,3
    float sa = v0 * asrc[lane],    sb = v1 * asrc[64+lane];
    float da = v0 * adst[lane],    db = v1 * adst[64+lane];
    #pragma unroll
    for (int d=16; d>=1; d>>=1){
        sa += __shfl_xor(sa,d); sb += __shfl_xor(sb,d);
        da += __shfl_xor(da,d); db += __shfl_xor(db,d);
    }
    if ((lane & 31) == 0){
        int hh = lane >> 5;   // 0 for lanes<32, 1 for >=32
        as1[wid*4+hh]   = sa; as1[wid*4+2+hh] = sb;
        ad1[wid*4+hh]   = da; ad1[wid*4+2+hh] = db;
    }
}

// ---------------- CSR build ----------------
__global__ void k_count(const int* __restrict__ ei, int* __restrict__ counts, int E, int Etot){
    int eid = blockIdx.x*256 + threadIdx.x;
    if (eid >= Etot) return;
    int dst = (eid < E) ? ei[E + eid] : (eid - E);
    atomicAdd(&counts[dst], 1);
}

__global__ __launch_bounds__(256) void k_scan1(const int* __restrict__ counts, int* __restrict__ offs,
                                               int* __restrict__ partials, int N){
    __shared__ int sm[256];
    int tid = threadIdx.x;
    int i = blockIdx.x*256 + tid;
    int v = (i < N) ? counts[i] : 0;
    sm[tid] = v;
    __syncthreads();
    for (int d=1; d<256; d<<=1){
        int t = (tid >= d) ? sm[tid-d] : 0;
        __syncthreads();
        sm[tid] += t;
        __syncthreads();
    }
    if (i < N) offs[i] = sm[tid] - v;     // exclusive within block
    if (tid == 255) partials[blockIdx.x] = sm[255];
}

__global__ void k_scan2(int* partials, int nb){
    int run = 0;
    for (int b=0;b<nb;b++){ int v = partials[b]; partials[b] = run; run += v; }
}

__global__ void k_scan3(int* __restrict__ offs, const int* __restrict__ partials, int N, int Etot){
    int i = blockIdx.x*256 + threadIdx.x;
    if (i < N) offs[i] += partials[blockIdx.x];
    if (i == 0) offs[N] = Etot;
}

__global__ void k_fill(const int* __restrict__ ei, const int* __restrict__ offs,
                       int* __restrict__ cursor, int* __restrict__ bsrc, int E, int Etot){
    int eid = blockIdx.x*256 + threadIdx.x;
    if (eid >= Etot) return;
    int s, d;
    if (eid < E){ s = ei[eid]; d = ei[E+eid]; }
    else        { s = eid - E; d = eid - E; }
    int pos = offs[d] + atomicAdd(&cursor[d], 1);
    bsrc[pos] = s;
}

// ---------------- layer-1 softmax + aggregate + bias + ELU (wave per node) ----------------
__global__ __launch_bounds__(256) void k_agg1(const float* __restrict__ h,
    const float* __restrict__ as1, const float* __restrict__ ad1,
    const int* __restrict__ offs, const int* __restrict__ bsrc,
    const float* __restrict__ b1, float* __restrict__ exb,
    float* __restrict__ h1, int N)
{
    int wid = (blockIdx.x << 2) + (threadIdx.x >> 6);
    int lane = threadIdx.x & 63;
    if (wid >= N) return;
    int base = offs[wid];
    int deg  = offs[wid+1] - base;
    float4 adv = *(const float4*)&ad1[wid*4];
    // pass A: segment max per head
    float m0=-1e30f,m1=-1e30f,m2=-1e30f,m3=-1e30f;
    for (int j=lane; j<deg; j+=64){
        int s = bsrc[base+j];
        float4 av = *(const float4*)&as1[s*4];
        m0 = fmaxf(m0, lrelu(av.x+adv.x));
        m1 = fmaxf(m1, lrelu(av.y+adv.y));
        m2 = fmaxf(m2, lrelu(av.z+adv.z));
        m3 = fmaxf(m3, lrelu(av.w+adv.w));
    }
    #pragma unroll
    for (int d=32; d>=1; d>>=1){
        m0 = fmaxf(m0, __shfl_xor(m0,d));
        m1 = fmaxf(m1, __shfl_xor(m1,d));
        m2 = fmaxf(m2, __shfl_xor(m2,d));
        m3 = fmaxf(m3, __shfl_xor(m3,d));
    }
    // pass B: exp + sum, cache exp per edge
    float s0=0,s1=0,s2=0,s3=0;
    for (int j=lane; j<deg; j+=64){
        int s = bsrc[base+j];
        float4 av = *(const float4*)&as1[s*4];
        float e0 = __expf(lrelu(av.x+adv.x) - m0);
        float e1 = __expf(lrelu(av.y+adv.y) - m1);
        float e2 = __expf(lrelu(av.z+adv.z) - m2);
        float e3 = __expf(lrelu(av.w+adv.w) - m3);
        s0+=e0; s1+=e1; s2+=e2; s3+=e3;
        *(float4*)&exb[(size_t)(base+j)*4] = make_float4(e0,e1,e2,e3);
    }
    #pragma unroll
    for (int d=32; d>=1; d>>=1){
        s0 += __shfl_xor(s0,d); s1 += __shfl_xor(s1,d);
        s2 += __shfl_xor(s2,d); s3 += __shfl_xor(s3,d);
    }
    float inva = (lane < 32) ? (1.f/s0) : (1.f/s1);
    float invb = (lane < 32) ? (1.f/s2) : (1.f/s3);
    int h0 = lane >> 5;
    // pass C: serial over edges, full wave covers 128 channels
    float acc0=0.f, acc1=0.f;
    for (int j=0;j<deg;j++){
        int s = bsrc[base+j];
        float ea = exb[(size_t)(base+j)*4 + h0];
        float eb = exb[(size_t)(base+j)*4 + 2 + h0];
        const float* hp = &h[(size_t)s*128];
        acc0 = fmaf(hp[lane],    ea*inva, acc0);
        acc1 = fmaf(hp[64+lane], eb*invb, acc1);
    }
    float r0 = acc0 + b1[lane];
    float r1 = acc1 + b1[64+lane];
    r0 = r0 > 0.f ? r0 : (__expf(r0) - 1.f);
    r1 = r1 > 0.f ? r1 : (__expf(r1) - 1.f);
    h1[(size_t)wid*128 + lane]      = r0;
    h1[(size_t)wid*128 + 64 + lane] = r1;
}

// ---------------- GEMM2 (h2 = h1 @ W2) + alpha2 (half-wave per node) ----------------
__global__ __launch_bounds__(256) void k_l2pre(const float* __restrict__ h1,
    const float* __restrict__ W2, const float* __restrict__ asrc2,
    const float* __restrict__ adst2, float* __restrict__ h2,
    float* __restrict__ as2, float* __restrict__ ad2, int N)
{
    __shared__ __align__(16) float w2s[4096];
    __shared__ float a2s[32], a2d[32];
    int tid = threadIdx.x;
    #pragma unroll
    for (int q=0;q<4;q++){
        int idx = q*1024 + tid*4;
        *(float4*)&w2s[idx] = *(const float4*)&W2[idx];
    }
    if (tid < 32){ a2s[tid] = asrc2[tid]; a2d[tid] = adst2[tid]; }
    __syncthreads();
    int node = blockIdx.x*8 + (tid>>5);
    if (node >= N) return;
    int c = tid & 31;
    float acc = 0.f;
    #pragma unroll 8
    for (int k=0;k<128;k+=4){
        float4 hv = *(const float4*)&h1[(size_t)node*128 + k];
        acc = fmaf(hv.x, w2s[(k+0)*32+c], acc);
        acc = fmaf(hv.y, w2s[(k+1)*32+c], acc);
        acc = fmaf(hv.z, w2s[(k+2)*32+c], acc);
        acc = fmaf(hv.w, w2s[(k+3)*32+c], acc);
    }
    h2[(size_t)node*32 + c] = acc;
    float ps = acc * a2s[c], pd = acc * a2d[c];
    #pragma unroll
    for (int d=16; d>=1; d>>=1){ ps += __shfl_xor(ps,d); pd += __shfl_xor(pd,d); }
    if (c == 0){ as2[node] = ps; ad2[node] = pd; }
}

// ---------------- layer-2 softmax + aggregate + bias -> output ----------------
__global__ __launch_bounds__(256) void k_agg2(const float* __restrict__ h2,
    const float* __restrict__ as2, const float* __restrict__ ad2,
    const int* __restrict__ offs, const int* __restrict__ bsrc,
    const float* __restrict__ b2, float* __restrict__ exb,
    float* __restrict__ outp, int N)
{
    int wid = (blockIdx.x << 2) + (threadIdx.x >> 6);
    int lane = threadIdx.x & 63;
    if (wid >= N) return;
    int base = offs[wid], deg = offs[wid+1] - base;
    float adn = ad2[wid];
    float m = -1e30f;
    for (int j=lane; j<deg; j+=64){
        int s = bsrc[base+j];
        m = fmaxf(m, lrelu(as2[s] + adn));
    }
    #pragma unroll
    for (int d=32; d>=1; d>>=1) m = fmaxf(m, __shfl_xor(m,d));
    float sum = 0.f;
    for (int j=lane; j<deg; j+=64){
        int s = bsrc[base+j];
        float ex = __expf(lrelu(as2[s] + adn) - m);
        sum += ex;
        exb[base+j] = ex;
    }
    #pragma unroll
    for (int d=32; d>=1; d>>=1) sum += __shfl_xor(sum,d);
    float inv = 1.f/sum;
    int half = lane >> 5, c = lane & 31;
    float acc = 0.f;
    for (int j=half; j<deg; j+=2){
        int s = bsrc[base+j];
        acc = fmaf(h2[(size_t)s*32 + c], exb[base+j]*inv, acc);
    }
    acc += __shfl_xor(acc, 32);
    if (lane < 32) outp[(size_t)wid*32 + c] = acc + b2[c];
}

extern "C" void kernel_launch(void* const* d_in, const int* in_sizes, int n_in,
                              void* d_out, int out_size, void* d_ws, size_t ws_size,
                              hipStream_t stream)
{
    const float* x     = (const float*)d_in[0];
    const int*   ei    = (const int*)d_in[1];
    const float* W1    = (const float*)d_in[2];
    const float* at_s1 = (const float*)d_in[3];
    const float* at_d1 = (const float*)d_in[4];
    const float* b1    = (const float*)d_in[5];
    const float* W2    = (const float*)d_in[6];
    const float* at_s2 = (const float*)d_in[7];
    const float* at_d2 = (const float*)d_in[8];
    const float* b2    = (const float*)d_in[9];
    float* outp = (float*)d_out;

    const int N = in_sizes[0] / 128;
    const int E = in_sizes[1] / 2;
    const int Etot = E + N;

    float* f = (float*)d_ws;
    size_t off = 0;
    float* h   = f + off; off += (size_t)N*128;
    float* h1  = f + off; off += (size_t)N*128;
    float* exb = f + off; off += (size_t)Etot*4;
    float* as1 = f + off; off += (size_t)N*4;
    float* ad1 = f + off; off += (size_t)N*4;
    float* h2  = f + off; off += (size_t)N*32;
    float* as2 = f + off; off += (size_t)N;
    float* ad2 = f + off; off += (size_t)N;
    int* ib      = (int*)(f + off);
    int* counts  = ib;
    int* cursor  = ib + N;
    int* offs    = ib + 2*N;           // N+1 entries
    int* partials= ib + 3*N + 8;       // up to 256
    int* bsrc    = ib + 3*N + 8 + 256; // Etot entries

    hipMemsetAsync(counts, 0, sizeof(int)*(size_t)(2*N), stream);   // counts + cursor
    k_gemm1 <<<(N+63)/64,   256, 0, stream>>>(x, W1, h, N);
    k_alpha1<<<(N+3)/4,     256, 0, stream>>>(h, at_s1, at_d1, as1, ad1, N);
    k_count <<<(Etot+255)/256, 256, 0, stream>>>(ei, counts, E, Etot);
    int nb = (N+255)/256;
    k_scan1 <<<nb, 256, 0, stream>>>(counts, offs, partials, N);
    k_scan2 <<<1, 1, 0, stream>>>(partials, nb);
    k_scan3 <<<nb, 256, 0, stream>>>(offs, partials, N, Etot);
    k_fill  <<<(Etot+255)/256, 256, 0, stream>>>(ei, offs, cursor, bsrc, E, Etot);
    k_agg1  <<<(N+3)/4, 256, 0, stream>>>(h, as1, ad1, offs, bsrc, b1, exb, h1, N);
    k_l2pre <<<(N+7)/8, 256, 0, stream>>>(h1, W2, at_s2, at_d2, h2, as2, ad2, N);
    k_agg2  <<<(N+3)/4, 256, 0, stream>>>(h2, as2, ad2, offs, bsrc, b2, exb, outp, N);
}

// Round 3
// 265.676 us; speedup vs baseline: 1.3171x; 1.3171x over previous
//
#include <hip/hip_runtime.h>
#include <math.h>

#define NEG_SLOPE 0.2f
typedef unsigned int uint;

__device__ __forceinline__ float lrelu(float x){ return x > 0.f ? x : NEG_SLOPE*x; }
__device__ __forceinline__ float sel4(float a,float b,float c,float d,int comp){
    return comp==0 ? a : (comp==1 ? b : (comp==2 ? c : d));
}
__device__ __forceinline__ uint f2bf(float f){
    uint u = __float_as_uint(f);
    return (u + 0x7FFFu + ((u>>16)&1u)) >> 16;
}
__device__ __forceinline__ float bf_lo(uint u){ return __uint_as_float(u<<16); }
__device__ __forceinline__ float bf_hi(uint u){ return __uint_as_float(u & 0xFFFF0000u); }

// ---------------- GEMM1: hb2[N,64] (bf16 pairs) = pack(x[N,128] @ W1[128,128]) ----------------
__global__ __launch_bounds__(256) void k_gemm1(const float* __restrict__ x,
                                               const float* __restrict__ W,
                                               uint* __restrict__ hb2, int N)
{
    __shared__ __align__(16) float xs[32][68];   // [k][row]
    __shared__ __align__(16) float wl[32][140];  // [k][skewed col]
    const int tid = threadIdx.x;
    const int tr = tid >> 4, tc = tid & 15;
    const int row0 = blockIdx.x * 64;
    const int rr  = tid & 63;
    const int kk0 = (tid >> 6) << 3;
    const int kw  = tid >> 3;
    const int jc  = (tid & 7) << 4;
    const int jb  = tc << 3;
    const int pb  = jb + ((jb >> 5) << 2);
    float acc[4][8];
    #pragma unroll
    for (int r=0;r<4;r++)
        #pragma unroll
        for (int c=0;c<8;c++) acc[r][c]=0.f;

    for (int kc = 0; kc < 128; kc += 32) {
        int gr = row0 + rr;
        float4 a0 = make_float4(0,0,0,0), a1 = a0;
        if (gr < N) {
            const float* xp = &x[(size_t)gr*128 + kc + kk0];
            a0 = *(const float4*)xp;
            a1 = *(const float4*)(xp+4);
        }
        xs[kk0+0][rr]=a0.x; xs[kk0+1][rr]=a0.y; xs[kk0+2][rr]=a0.z; xs[kk0+3][rr]=a0.w;
        xs[kk0+4][rr]=a1.x; xs[kk0+5][rr]=a1.y; xs[kk0+6][rr]=a1.z; xs[kk0+7][rr]=a1.w;
        const float* wsrc = &W[(size_t)(kc+kw)*128 + jc];
        #pragma unroll
        for (int q=0;q<4;q++){
            float4 wv = *(const float4*)(wsrc + q*4);
            int j = jc + q*4;
            int p = j + ((j>>5)<<2);
            *(float4*)&wl[kw][p] = wv;
        }
        __syncthreads();
        #pragma unroll
        for (int k=0;k<32;k++){
            float4 xv = *(float4*)&xs[k][tr<<2];
            float4 w0 = *(float4*)&wl[k][pb];
            float4 w1 = *(float4*)&wl[k][pb+4];
            float xr[4]={xv.x,xv.y,xv.z,xv.w};
            float wv[8]={w0.x,w0.y,w0.z,w0.w,w1.x,w1.y,w1.z,w1.w};
            #pragma unroll
            for (int r=0;r<4;r++)
                #pragma unroll
                for (int c=0;c<8;c++) acc[r][c] = fmaf(xr[r], wv[c], acc[r][c]);
        }
        __syncthreads();
    }
    #pragma unroll
    for (int r=0;r<4;r++){
        int gr = row0 + (tr<<2) + r;
        if (gr < N){
            uint4 o;
            o.x = f2bf(acc[r][0]) | (f2bf(acc[r][1])<<16);
            o.y = f2bf(acc[r][2]) | (f2bf(acc[r][3])<<16);
            o.z = f2bf(acc[r][4]) | (f2bf(acc[r][5])<<16);
            o.w = f2bf(acc[r][6]) | (f2bf(acc[r][7])<<16);
            *(uint4*)&hb2[(size_t)gr*64 + (jb>>1)] = o;
        }
    }
}

// ---------------- alpha1 from bf16 h (wave per node, 16-lane head groups) ----------------
__global__ __launch_bounds__(256) void k_alpha1(const uint* __restrict__ hb2,
        const float* __restrict__ at_s, const float* __restrict__ at_d,
        float* __restrict__ as1, float* __restrict__ ad1, int N)
{
    int wid = (blockIdx.x << 2) + (threadIdx.x >> 6);
    int lane = threadIdx.x & 63;
    if (wid >= N) return;
    uint hv = hb2[(size_t)wid*64 + lane];      // channels 2*lane, 2*lane+1
    float f0 = bf_lo(hv), f1 = bf_hi(hv);
    float2 asv = *(const float2*)&at_s[2*lane];
    float2 adv = *(const float2*)&at_d[2*lane];
    float sa = f0*asv.x + f1*asv.y;
    float da = f0*adv.x + f1*adv.y;
    #pragma unroll
    for (int d=8; d>=1; d>>=1){ sa += __shfl_xor(sa,d); da += __shfl_xor(da,d); }
    if ((lane & 15) == 0){
        int head = lane >> 4;                  // channels [32*head, 32*head+32)
        as1[(size_t)wid*4 + head] = sa;
        ad1[(size_t)wid*4 + head] = da;
    }
}

// ---------------- CSR build: count + rank (single atomic pass) ----------------
__global__ void k_count(const int* __restrict__ ei, int* __restrict__ counts,
                        int* __restrict__ erank, int E, int Etot){
    int eid = blockIdx.x*256 + threadIdx.x;
    if (eid >= Etot) return;
    int dst = (eid < E) ? ei[E + eid] : (eid - E);
    erank[eid] = atomicAdd(&counts[dst], 1);
}

__global__ __launch_bounds__(256) void k_scan1(const int* __restrict__ counts, int* __restrict__ offs,
                                               int* __restrict__ partials, int N){
    __shared__ int sm[256];
    int tid = threadIdx.x;
    int i = blockIdx.x*256 + tid;
    int v = (i < N) ? counts[i] : 0;
    sm[tid] = v;
    __syncthreads();
    for (int d=1; d<256; d<<=1){
        int t = (tid >= d) ? sm[tid-d] : 0;
        __syncthreads();
        sm[tid] += t;
        __syncthreads();
    }
    if (i < N) offs[i] = sm[tid] - v;
    if (tid == 255) partials[blockIdx.x] = sm[255];
}

__global__ __launch_bounds__(256) void k_scan2(int* partials, int nb){
    if (nb > 256){
        if (threadIdx.x == 0){
            int run = 0;
            for (int b=0;b<nb;b++){ int v = partials[b]; partials[b] = run; run += v; }
        }
        return;
    }
    __shared__ int sm[256];
    int tid = threadIdx.x;
    int v = (tid < nb) ? partials[tid] : 0;
    sm[tid] = v;
    __syncthreads();
    for (int d=1; d<256; d<<=1){
        int t = (tid >= d) ? sm[tid-d] : 0;
        __syncthreads();
        sm[tid] += t;
        __syncthreads();
    }
    if (tid < nb) partials[tid] = sm[tid] - v;
}

__global__ void k_scan3(int* __restrict__ offs, const int* __restrict__ partials, int N, int Etot){
    int i = blockIdx.x*256 + threadIdx.x;
    if (i < N) offs[i] += partials[blockIdx.x];
    if (i == 0) offs[N] = Etot;
}

__global__ void k_fill(const int* __restrict__ ei, const int* __restrict__ offs,
                       const int* __restrict__ erank, int* __restrict__ bsrc, int E, int Etot){
    int eid = blockIdx.x*256 + threadIdx.x;
    if (eid >= Etot) return;
    int s, d;
    if (eid < E){ s = ei[eid]; d = ei[E+eid]; }
    else        { s = eid - E; d = eid - E; }
    bsrc[offs[d] + erank[eid]] = s;
}

// ---------------- layer-1 softmax + aggregate + bias + ELU (R1 structure, bf16 gather) ----------------
__global__ __launch_bounds__(256) void k_agg1(const uint* __restrict__ hb2,
    const float4* __restrict__ as1v, const float4* __restrict__ ad1v,
    const int* __restrict__ offs, const int* __restrict__ bsrc,
    const float* __restrict__ b1, float* __restrict__ exb,
    float* __restrict__ h1, int N)
{
    int wid = (blockIdx.x << 2) + (threadIdx.x >> 6);
    int lane = threadIdx.x & 63;
    if (wid >= N) return;
    int base = offs[wid];
    int deg  = offs[wid+1] - base;
    float4 adv = ad1v[wid];
    // pass A: segment max per head
    float m0=-1e30f,m1=-1e30f,m2=-1e30f,m3=-1e30f;
    for (int j=lane; j<deg; j+=64){
        int s = bsrc[base+j];
        float4 av = as1v[s];
        m0=fmaxf(m0,lrelu(av.x+adv.x)); m1=fmaxf(m1,lrelu(av.y+adv.y));
        m2=fmaxf(m2,lrelu(av.z+adv.z)); m3=fmaxf(m3,lrelu(av.w+adv.w));
    }
    #pragma unroll
    for (int d=32; d>=1; d>>=1){
        m0=fmaxf(m0,__shfl_xor(m0,d)); m1=fmaxf(m1,__shfl_xor(m1,d));
        m2=fmaxf(m2,__shfl_xor(m2,d)); m3=fmaxf(m3,__shfl_xor(m3,d));
    }
    // pass B: exp + sum, cache exp per edge
    float s0=0,s1=0,s2=0,s3=0;
    for (int j=lane; j<deg; j+=64){
        int s = bsrc[base+j];
        float4 av = as1v[s];
        float e0=__expf(lrelu(av.x+adv.x)-m0);
        float e1=__expf(lrelu(av.y+adv.y)-m1);
        float e2=__expf(lrelu(av.z+adv.z)-m2);
        float e3=__expf(lrelu(av.w+adv.w)-m3);
        s0+=e0; s1+=e1; s2+=e2; s3+=e3;
        *(float4*)&exb[(size_t)(base+j)*4] = make_float4(e0,e1,e2,e3);
    }
    #pragma unroll
    for (int d=32; d>=1; d>>=1){
        s0+=__shfl_xor(s0,d); s1+=__shfl_xor(s1,d);
        s2+=__shfl_xor(s2,d); s3+=__shfl_xor(s3,d);
    }
    const int comp = lane >> 4;              // head of channels 2*lane, 2*lane+1
    float invc = 1.0f / sel4(s0,s1,s2,s3,comp);
    // pass C: serial over edges; lane covers channels 2*lane, 2*lane+1
    float acc0=0.f, acc1=0.f;
    int j=0;
    for (; j+1<deg; j+=2){
        int sA = bsrc[base+j], sB = bsrc[base+j+1];
        float wA = exb[(size_t)(base+j)*4 + comp]*invc;
        float wB = exb[(size_t)(base+j+1)*4 + comp]*invc;
        uint hA = hb2[(size_t)sA*64 + lane];
        uint hB = hb2[(size_t)sB*64 + lane];
        acc0 = fmaf(bf_lo(hA), wA, acc0);
        acc1 = fmaf(bf_hi(hA), wA, acc1);
        acc0 = fmaf(bf_lo(hB), wB, acc0);
        acc1 = fmaf(bf_hi(hB), wB, acc1);
    }
    if (j < deg){
        int sA = bsrc[base+j];
        float wA = exb[(size_t)(base+j)*4 + comp]*invc;
        uint hA = hb2[(size_t)sA*64 + lane];
        acc0 = fmaf(bf_lo(hA), wA, acc0);
        acc1 = fmaf(bf_hi(hA), wA, acc1);
    }
    float2 bv = *(const float2*)&b1[2*lane];
    float r0 = acc0 + bv.x;
    float r1 = acc1 + bv.y;
    r0 = r0 > 0.f ? r0 : (__expf(r0) - 1.f);
    r1 = r1 > 0.f ? r1 : (__expf(r1) - 1.f);
    *(float2*)&h1[(size_t)wid*128 + 2*lane] = make_float2(r0, r1);
}

// ---------------- GEMM2 (h2 = h1 @ W2) + alpha2 (half-wave per node) ----------------
__global__ __launch_bounds__(256) void k_l2pre(const float* __restrict__ h1,
    const float* __restrict__ W2, const float* __restrict__ asrc2,
    const float* __restrict__ adst2, float* __restrict__ h2,
    float* __restrict__ as2, float* __restrict__ ad2, int N)
{
    __shared__ __align__(16) float w2s[4096];
    __shared__ float a2s[32], a2d[32];
    int tid = threadIdx.x;
    #pragma unroll
    for (int q=0;q<4;q++){
        int idx = q*1024 + tid*4;
        *(float4*)&w2s[idx] = *(const float4*)&W2[idx];
    }
    if (tid < 32){ a2s[tid] = asrc2[tid]; a2d[tid] = adst2[tid]; }
    __syncthreads();
    int node = blockIdx.x*8 + (tid>>5);
    if (node >= N) return;
    int c = tid & 31;
    float acc = 0.f;
    #pragma unroll 8
    for (int k=0;k<128;k+=4){
        float4 hv = *(const float4*)&h1[(size_t)node*128 + k];
        acc = fmaf(hv.x, w2s[(k+0)*32+c], acc);
        acc = fmaf(hv.y, w2s[(k+1)*32+c], acc);
        acc = fmaf(hv.z, w2s[(k+2)*32+c], acc);
        acc = fmaf(hv.w, w2s[(k+3)*32+c], acc);
    }
    h2[(size_t)node*32 + c] = acc;
    float ps = acc * a2s[c], pd = acc * a2d[c];
    #pragma unroll
    for (int d=16; d>=1; d>>=1){ ps += __shfl_xor(ps,d); pd += __shfl_xor(pd,d); }
    if (c == 0){ as2[node] = ps; ad2[node] = pd; }
}

// ---------------- layer-2 softmax + aggregate + bias -> output (R1 exact) ----------------
__global__ __launch_bounds__(256) void k_agg2(const float* __restrict__ h2,
    const float* __restrict__ as2, const float* __restrict__ ad2,
    const int* __restrict__ offs, const int* __restrict__ bsrc,
    const float* __restrict__ b2, float* __restrict__ exb,
    float* __restrict__ outp, int N)
{
    int wid = (blockIdx.x << 2) + (threadIdx.x >> 6);
    int lane = threadIdx.x & 63;
    if (wid >= N) return;
    int base = offs[wid], deg = offs[wid+1] - base;
    float adn = ad2[wid];
    float m = -1e30f;
    for (int j=lane; j<deg; j+=64){
        int s = bsrc[base+j];
        m = fmaxf(m, lrelu(as2[s] + adn));
    }
    #pragma unroll
    for (int d=32; d>=1; d>>=1) m = fmaxf(m, __shfl_xor(m,d));
    float sum = 0.f;
    for (int j=lane; j<deg; j+=64){
        int s = bsrc[base+j];
        float ex = __expf(lrelu(as2[s] + adn) - m);
        sum += ex;
        exb[base+j] = ex;
    }
    #pragma unroll
    for (int d=32; d>=1; d>>=1) sum += __shfl_xor(sum,d);
    float inv = 1.f/sum;
    int half = lane >> 5, c = lane & 31;
    float acc = 0.f;
    for (int j=half; j<deg; j+=2){
        int s = bsrc[base+j];
        acc = fmaf(h2[(size_t)s*32 + c], exb[base+j]*inv, acc);
    }
    acc += __shfl_xor(acc, 32);
    if (lane < 32) outp[(size_t)wid*32 + c] = acc + b2[c];
}

extern "C" void kernel_launch(void* const* d_in, const int* in_sizes, int n_in,
                              void* d_out, int out_size, void* d_ws, size_t ws_size,
                              hipStream_t stream)
{
    const float* x     = (const float*)d_in[0];
    const int*   ei    = (const int*)d_in[1];
    const float* W1    = (const float*)d_in[2];
    const float* at_s1 = (const float*)d_in[3];
    const float* at_d1 = (const float*)d_in[4];
    const float* b1    = (const float*)d_in[5];
    const float* W2    = (const float*)d_in[6];
    const float* at_s2 = (const float*)d_in[7];
    const float* at_d2 = (const float*)d_in[8];
    const float* b2    = (const float*)d_in[9];
    float* outp = (float*)d_out;

    const int N = in_sizes[0] / 128;
    const int E = in_sizes[1] / 2;
    const int Etot = E + N;

    float* f = (float*)d_ws;
    size_t off = 0;
    uint*  hb2 = (uint*)(f + off); off += (size_t)N*64;   // bf16-packed h, [N][64] dwords
    float* h1  = f + off; off += (size_t)N*128;
    float* exb = f + off; off += (size_t)Etot*4;
    float* as1 = f + off; off += (size_t)N*4;
    float* ad1 = f + off; off += (size_t)N*4;
    float* h2  = f + off; off += (size_t)N*32;
    float* as2 = f + off; off += (size_t)N;
    float* ad2 = f + off; off += (size_t)N;
    int* ib      = (int*)(f + off);
    int* counts  = ib;                   // N
    int* offs    = ib + N;               // N+1 (+pad)
    int* partials= ib + 2*N + 8;         // 256
    int* erank   = ib + 2*N + 8 + 256;   // Etot
    int* bsrc    = erank + Etot;         // Etot

    hipMemsetAsync(counts, 0, sizeof(int)*(size_t)N, stream);
    k_gemm1 <<<(N+63)/64,   256, 0, stream>>>(x, W1, hb2, N);
    k_alpha1<<<(N+3)/4,     256, 0, stream>>>(hb2, at_s1, at_d1, as1, ad1, N);
    k_count <<<(Etot+255)/256, 256, 0, stream>>>(ei, counts, erank, E, Etot);
    int nb = (N+255)/256;
    k_scan1 <<<nb, 256, 0, stream>>>(counts, offs, partials, N);
    k_scan2 <<<1, 256, 0, stream>>>(partials, nb);
    k_scan3 <<<nb, 256, 0, stream>>>(offs, partials, N, Etot);
    k_fill  <<<(Etot+255)/256, 256, 0, stream>>>(ei, offs, erank, bsrc, E, Etot);
    k_agg1  <<<(N+3)/4, 256, 0, stream>>>(hb2, (const float4*)as1, (const float4*)ad1,
                                          offs, bsrc, b1, exb, h1, N);
    k_l2pre <<<(N+7)/8, 256, 0, stream>>>(h1, W2, at_s2, at_d2, h2, as2, ad2, N);
    k_agg2  <<<(N+3)/4, 256, 0, stream>>>(h2, as2, ad2, offs, bsrc, b2, exb, outp, N);
}

// Round 4
// 209.343 us; speedup vs baseline: 1.6716x; 1.2691x over previous
//
#include <hip/hip_runtime.h>
#include <math.h>

#define NEG_SLOPE 0.2f
typedef unsigned int uint;

__device__ __forceinline__ float lrelu(float x){ return x > 0.f ? x : NEG_SLOPE*x; }
__device__ __forceinline__ float sel4(float a,float b,float c,float d,int comp){
    return comp==0 ? a : (comp==1 ? b : (comp==2 ? c : d));
}
__device__ __forceinline__ uint f2bf(float f){
    uint u = __float_as_uint(f);
    return (u + 0x7FFFu + ((u>>16)&1u)) >> 16;
}
__device__ __forceinline__ float bf_lo(uint u){ return __uint_as_float(u<<16); }
__device__ __forceinline__ float bf_hi(uint u){ return __uint_as_float(u & 0xFFFF0000u); }

// ---------------- GEMM1: hb2[N,64] (bf16 pairs) = pack(x[N,128] @ W1[128,128]) ----------------
__global__ __launch_bounds__(256) void k_gemm1(const float* __restrict__ x,
                                               const float* __restrict__ W,
                                               uint* __restrict__ hb2, int N)
{
    __shared__ __align__(16) float xs[32][68];   // [k][row]
    __shared__ __align__(16) float wl[32][140];  // [k][skewed col]
    const int tid = threadIdx.x;
    const int tr = tid >> 4, tc = tid & 15;
    const int row0 = blockIdx.x * 64;
    const int rr  = tid & 63;
    const int kk0 = (tid >> 6) << 3;
    const int kw  = tid >> 3;
    const int jc  = (tid & 7) << 4;
    const int jb  = tc << 3;
    const int pb  = jb + ((jb >> 5) << 2);
    float acc[4][8];
    #pragma unroll
    for (int r=0;r<4;r++)
        #pragma unroll
        for (int c=0;c<8;c++) acc[r][c]=0.f;

    for (int kc = 0; kc < 128; kc += 32) {
        int gr = row0 + rr;
        float4 a0 = make_float4(0,0,0,0), a1 = a0;
        if (gr < N) {
            const float* xp = &x[(size_t)gr*128 + kc + kk0];
            a0 = *(const float4*)xp;
            a1 = *(const float4*)(xp+4);
        }
        xs[kk0+0][rr]=a0.x; xs[kk0+1][rr]=a0.y; xs[kk0+2][rr]=a0.z; xs[kk0+3][rr]=a0.w;
        xs[kk0+4][rr]=a1.x; xs[kk0+5][rr]=a1.y; xs[kk0+6][rr]=a1.z; xs[kk0+7][rr]=a1.w;
        const float* wsrc = &W[(size_t)(kc+kw)*128 + jc];
        #pragma unroll
        for (int q=0;q<4;q++){
            float4 wv = *(const float4*)(wsrc + q*4);
            int j = jc + q*4;
            int p = j + ((j>>5)<<2);
            *(float4*)&wl[kw][p] = wv;
        }
        __syncthreads();
        #pragma unroll
        for (int k=0;k<32;k++){
            float4 xv = *(float4*)&xs[k][tr<<2];
            float4 w0 = *(float4*)&wl[k][pb];
            float4 w1 = *(float4*)&wl[k][pb+4];
            float xr[4]={xv.x,xv.y,xv.z,xv.w};
            float wv[8]={w0.x,w0.y,w0.z,w0.w,w1.x,w1.y,w1.z,w1.w};
            #pragma unroll
            for (int r=0;r<4;r++)
                #pragma unroll
                for (int c=0;c<8;c++) acc[r][c] = fmaf(xr[r], wv[c], acc[r][c]);
        }
        __syncthreads();
    }
    #pragma unroll
    for (int r=0;r<4;r++){
        int gr = row0 + (tr<<2) + r;
        if (gr < N){
            uint4 o;
            o.x = f2bf(acc[r][0]) | (f2bf(acc[r][1])<<16);
            o.y = f2bf(acc[r][2]) | (f2bf(acc[r][3])<<16);
            o.z = f2bf(acc[r][4]) | (f2bf(acc[r][5])<<16);
            o.w = f2bf(acc[r][6]) | (f2bf(acc[r][7])<<16);
            *(uint4*)&hb2[(size_t)gr*64 + (jb>>1)] = o;
        }
    }
}

// ---------------- alpha1 from bf16 h (wave per node, 16-lane head groups) ----------------
__global__ __launch_bounds__(256) void k_alpha1(const uint* __restrict__ hb2,
        const float* __restrict__ at_s, const float* __restrict__ at_d,
        float* __restrict__ as1, float* __restrict__ ad1, int N)
{
    int wid = (blockIdx.x << 2) + (threadIdx.x >> 6);
    int lane = threadIdx.x & 63;
    if (wid >= N) return;
    uint hv = hb2[(size_t)wid*64 + lane];      // channels 2*lane, 2*lane+1
    float f0 = bf_lo(hv), f1 = bf_hi(hv);
    float2 asv = *(const float2*)&at_s[2*lane];
    float2 adv = *(const float2*)&at_d[2*lane];
    float sa = f0*asv.x + f1*asv.y;
    float da = f0*adv.x + f1*adv.y;
    #pragma unroll
    for (int d=8; d>=1; d>>=1){ sa += __shfl_xor(sa,d); da += __shfl_xor(da,d); }
    if ((lane & 15) == 0){
        int head = lane >> 4;
        as1[(size_t)wid*4 + head] = sa;
        ad1[(size_t)wid*4 + head] = da;
    }
}

// ---------------- CSR build: count + rank (single atomic pass) ----------------
__global__ void k_count(const int* __restrict__ ei, int* __restrict__ counts,
                        int* __restrict__ erank, int E, int Etot){
    int eid = blockIdx.x*256 + threadIdx.x;
    if (eid >= Etot) return;
    int dst = (eid < E) ? ei[E + eid] : (eid - E);
    erank[eid] = atomicAdd(&counts[dst], 1);
}

__global__ __launch_bounds__(256) void k_scan1(const int* __restrict__ counts, int* __restrict__ offs,
                                               int* __restrict__ partials, int N){
    __shared__ int sm[256];
    int tid = threadIdx.x;
    int i = blockIdx.x*256 + tid;
    int v = (i < N) ? counts[i] : 0;
    sm[tid] = v;
    __syncthreads();
    for (int d=1; d<256; d<<=1){
        int t = (tid >= d) ? sm[tid-d] : 0;
        __syncthreads();
        sm[tid] += t;
        __syncthreads();
    }
    if (i < N) offs[i] = sm[tid] - v;
    if (tid == 255) partials[blockIdx.x] = sm[255];
}

__global__ __launch_bounds__(256) void k_scan2(int* partials, int nb){
    if (nb > 256){
        if (threadIdx.x == 0){
            int run = 0;
            for (int b=0;b<nb;b++){ int v = partials[b]; partials[b] = run; run += v; }
        }
        return;
    }
    __shared__ int sm[256];
    int tid = threadIdx.x;
    int v = (tid < nb) ? partials[tid] : 0;
    sm[tid] = v;
    __syncthreads();
    for (int d=1; d<256; d<<=1){
        int t = (tid >= d) ? sm[tid-d] : 0;
        __syncthreads();
        sm[tid] += t;
        __syncthreads();
    }
    if (tid < nb) partials[tid] = sm[tid] - v;
}

__global__ void k_scan3(int* __restrict__ offs, const int* __restrict__ partials, int N, int Etot){
    int i = blockIdx.x*256 + threadIdx.x;
    if (i < N) offs[i] += partials[blockIdx.x];
    if (i == 0) offs[N] = Etot;
}

__global__ void k_fill(const int* __restrict__ ei, const int* __restrict__ offs,
                       const int* __restrict__ erank, int* __restrict__ bsrc, int E, int Etot){
    int eid = blockIdx.x*256 + threadIdx.x;
    if (eid >= Etot) return;
    int s, d;
    if (eid < E){ s = ei[eid]; d = ei[E+eid]; }
    else        { s = eid - E; d = eid - E; }
    bsrc[offs[d] + erank[eid]] = s;
}

// ---------------- layer-1 softmax + aggregate + bias + ELU ----------------
// deg<=64: one edge/lane, single alpha gather, softmax in registers,
// weights+src staged in wave-private LDS (no exb traffic). Fallback: R3 path.
__global__ __launch_bounds__(256) void k_agg1(const uint* __restrict__ hb2,
    const float4* __restrict__ as1v, const float4* __restrict__ ad1v,
    const int* __restrict__ offs, const int* __restrict__ bsrc,
    const float* __restrict__ b1, float* __restrict__ exb,
    float* __restrict__ h1, int N)
{
    __shared__ float wsh[4][64][4];   // [wave][edge][head]
    __shared__ int   ssh[4][64];      // [wave][edge] src
    int wv   = threadIdx.x >> 6;
    int wid  = (blockIdx.x << 2) + wv;
    int lane = threadIdx.x & 63;
    if (wid >= N) return;
    int base = offs[wid];
    int deg  = offs[wid+1] - base;
    float4 adv = ad1v[wid];
    const int comp = lane >> 4;              // head of channels 2*lane, 2*lane+1
    float acc0=0.f, acc1=0.f;

    if (deg <= 64){
        const bool act = lane < deg;
        int sreg = 0;
        float l0=-1e30f,l1=-1e30f,l2=-1e30f,l3=-1e30f;
        if (act){
            sreg = bsrc[base+lane];
            float4 av = as1v[sreg];
            l0=lrelu(av.x+adv.x); l1=lrelu(av.y+adv.y);
            l2=lrelu(av.z+adv.z); l3=lrelu(av.w+adv.w);
        }
        float m0=l0,m1=l1,m2=l2,m3=l3;
        #pragma unroll
        for (int d=32; d>=1; d>>=1){
            m0=fmaxf(m0,__shfl_xor(m0,d)); m1=fmaxf(m1,__shfl_xor(m1,d));
            m2=fmaxf(m2,__shfl_xor(m2,d)); m3=fmaxf(m3,__shfl_xor(m3,d));
        }
        float e0=0.f,e1=0.f,e2=0.f,e3=0.f;
        if (act){
            e0=__expf(l0-m0); e1=__expf(l1-m1); e2=__expf(l2-m2); e3=__expf(l3-m3);
        }
        float s0=e0,s1=e1,s2=e2,s3=e3;
        #pragma unroll
        for (int d=32; d>=1; d>>=1){
            s0+=__shfl_xor(s0,d); s1+=__shfl_xor(s1,d);
            s2+=__shfl_xor(s2,d); s3+=__shfl_xor(s3,d);
        }
        if (act){
            ssh[wv][lane]    = sreg;
            wsh[wv][lane][0] = e0/s0;
            wsh[wv][lane][1] = e1/s1;
            wsh[wv][lane][2] = e2/s2;
            wsh[wv][lane][3] = e3/s3;
        }
        int j=0;
        for (; j+3 < deg; j+=4){
            int sA=ssh[wv][j],   sB=ssh[wv][j+1], sC=ssh[wv][j+2], sD=ssh[wv][j+3];
            float wA=wsh[wv][j][comp],   wB=wsh[wv][j+1][comp];
            float wC=wsh[wv][j+2][comp], wD=wsh[wv][j+3][comp];
            uint hA=hb2[(size_t)sA*64+lane], hB=hb2[(size_t)sB*64+lane];
            uint hC=hb2[(size_t)sC*64+lane], hD=hb2[(size_t)sD*64+lane];
            acc0 = fmaf(bf_lo(hA), wA, acc0); acc1 = fmaf(bf_hi(hA), wA, acc1);
            acc0 = fmaf(bf_lo(hB), wB, acc0); acc1 = fmaf(bf_hi(hB), wB, acc1);
            acc0 = fmaf(bf_lo(hC), wC, acc0); acc1 = fmaf(bf_hi(hC), wC, acc1);
            acc0 = fmaf(bf_lo(hD), wD, acc0); acc1 = fmaf(bf_hi(hD), wD, acc1);
        }
        for (; j < deg; j++){
            int sA = ssh[wv][j];
            float wA = wsh[wv][j][comp];
            uint hA = hb2[(size_t)sA*64+lane];
            acc0 = fmaf(bf_lo(hA), wA, acc0);
            acc1 = fmaf(bf_hi(hA), wA, acc1);
        }
    } else {
        // ---- fallback: R3 3-pass with exb cache ----
        float m0=-1e30f,m1=-1e30f,m2=-1e30f,m3=-1e30f;
        for (int j=lane; j<deg; j+=64){
            int s = bsrc[base+j];
            float4 av = as1v[s];
            m0=fmaxf(m0,lrelu(av.x+adv.x)); m1=fmaxf(m1,lrelu(av.y+adv.y));
            m2=fmaxf(m2,lrelu(av.z+adv.z)); m3=fmaxf(m3,lrelu(av.w+adv.w));
        }
        #pragma unroll
        for (int d=32; d>=1; d>>=1){
            m0=fmaxf(m0,__shfl_xor(m0,d)); m1=fmaxf(m1,__shfl_xor(m1,d));
            m2=fmaxf(m2,__shfl_xor(m2,d)); m3=fmaxf(m3,__shfl_xor(m3,d));
        }
        float s0=0,s1=0,s2=0,s3=0;
        for (int j=lane; j<deg; j+=64){
            int s = bsrc[base+j];
            float4 av = as1v[s];
            float e0=__expf(lrelu(av.x+adv.x)-m0);
            float e1=__expf(lrelu(av.y+adv.y)-m1);
            float e2=__expf(lrelu(av.z+adv.z)-m2);
            float e3=__expf(lrelu(av.w+adv.w)-m3);
            s0+=e0; s1+=e1; s2+=e2; s3+=e3;
            *(float4*)&exb[(size_t)(base+j)*4] = make_float4(e0,e1,e2,e3);
        }
        #pragma unroll
        for (int d=32; d>=1; d>>=1){
            s0+=__shfl_xor(s0,d); s1+=__shfl_xor(s1,d);
            s2+=__shfl_xor(s2,d); s3+=__shfl_xor(s3,d);
        }
        float invc = 1.0f / sel4(s0,s1,s2,s3,comp);
        for (int j=0;j<deg;j++){
            int s = bsrc[base+j];
            float w = exb[(size_t)(base+j)*4 + comp]*invc;
            uint hv = hb2[(size_t)s*64 + lane];
            acc0 = fmaf(bf_lo(hv), w, acc0);
            acc1 = fmaf(bf_hi(hv), w, acc1);
        }
    }
    float2 bv = *(const float2*)&b1[2*lane];
    float r0 = acc0 + bv.x;
    float r1 = acc1 + bv.y;
    r0 = r0 > 0.f ? r0 : (__expf(r0) - 1.f);
    r1 = r1 > 0.f ? r1 : (__expf(r1) - 1.f);
    *(float2*)&h1[(size_t)wid*128 + 2*lane] = make_float2(r0, r1);
}

// ---------------- GEMM2 (h2 = h1 @ W2) + alpha2 (half-wave per node) ----------------
__global__ __launch_bounds__(256) void k_l2pre(const float* __restrict__ h1,
    const float* __restrict__ W2, const float* __restrict__ asrc2,
    const float* __restrict__ adst2, float* __restrict__ h2,
    float* __restrict__ as2, float* __restrict__ ad2, int N)
{
    __shared__ __align__(16) float w2s[4096];
    __shared__ float a2s[32], a2d[32];
    int tid = threadIdx.x;
    #pragma unroll
    for (int q=0;q<4;q++){
        int idx = q*1024 + tid*4;
        *(float4*)&w2s[idx] = *(const float4*)&W2[idx];
    }
    if (tid < 32){ a2s[tid] = asrc2[tid]; a2d[tid] = adst2[tid]; }
    __syncthreads();
    int node = blockIdx.x*8 + (tid>>5);
    if (node >= N) return;
    int c = tid & 31;
    float acc = 0.f;
    #pragma unroll 8
    for (int k=0;k<128;k+=4){
        float4 hv = *(const float4*)&h1[(size_t)node*128 + k];
        acc = fmaf(hv.x, w2s[(k+0)*32+c], acc);
        acc = fmaf(hv.y, w2s[(k+1)*32+c], acc);
        acc = fmaf(hv.z, w2s[(k+2)*32+c], acc);
        acc = fmaf(hv.w, w2s[(k+3)*32+c], acc);
    }
    h2[(size_t)node*32 + c] = acc;
    float ps = acc * a2s[c], pd = acc * a2d[c];
    #pragma unroll
    for (int d=16; d>=1; d>>=1){ ps += __shfl_xor(ps,d); pd += __shfl_xor(pd,d); }
    if (c == 0){ as2[node] = ps; ad2[node] = pd; }
}

// ---------------- layer-2 softmax + aggregate + bias -> output ----------------
__global__ __launch_bounds__(256) void k_agg2(const float* __restrict__ h2,
    const float* __restrict__ as2, const float* __restrict__ ad2,
    const int* __restrict__ offs, const int* __restrict__ bsrc,
    const float* __restrict__ b2, float* __restrict__ exb,
    float* __restrict__ outp, int N)
{
    __shared__ float w2sh[4][64];
    __shared__ int   s2sh[4][64];
    int wv   = threadIdx.x >> 6;
    int wid  = (blockIdx.x << 2) + wv;
    int lane = threadIdx.x & 63;
    if (wid >= N) return;
    int base = offs[wid], deg = offs[wid+1] - base;
    float adn = ad2[wid];
    int half = lane >> 5, c = lane & 31;
    float acc = 0.f;

    if (deg <= 64){
        const bool act = lane < deg;
        int sreg = 0; float l = -1e30f;
        if (act){ sreg = bsrc[base+lane]; l = lrelu(as2[sreg] + adn); }
        float m = l;
        #pragma unroll
        for (int d=32; d>=1; d>>=1) m = fmaxf(m, __shfl_xor(m,d));
        float e = act ? __expf(l - m) : 0.f;
        float sum = e;
        #pragma unroll
        for (int d=32; d>=1; d>>=1) sum += __shfl_xor(sum,d);
        if (act){ s2sh[wv][lane] = sreg; w2sh[wv][lane] = e/sum; }
        int j = half;
        for (; j+2 < deg; j += 4){
            int sA = s2sh[wv][j], sB = s2sh[wv][j+2];
            float wA = w2sh[wv][j], wB = w2sh[wv][j+2];
            acc = fmaf(h2[(size_t)sA*32 + c], wA, acc);
            acc = fmaf(h2[(size_t)sB*32 + c], wB, acc);
        }
        for (; j < deg; j += 2){
            acc = fmaf(h2[(size_t)s2sh[wv][j]*32 + c], w2sh[wv][j], acc);
        }
    } else {
        float m = -1e30f;
        for (int j=lane; j<deg; j+=64){
            int s = bsrc[base+j];
            m = fmaxf(m, lrelu(as2[s] + adn));
        }
        #pragma unroll
        for (int d=32; d>=1; d>>=1) m = fmaxf(m, __shfl_xor(m,d));
        float sum = 0.f;
        for (int j=lane; j<deg; j+=64){
            int s = bsrc[base+j];
            float ex = __expf(lrelu(as2[s] + adn) - m);
            sum += ex;
            exb[base+j] = ex;
        }
        #pragma unroll
        for (int d=32; d>=1; d>>=1) sum += __shfl_xor(sum,d);
        float inv = 1.f/sum;
        for (int j=half; j<deg; j+=2){
            int s = bsrc[base+j];
            acc = fmaf(h2[(size_t)s*32 + c], exb[base+j]*inv, acc);
        }
    }
    acc += __shfl_xor(acc, 32);
    if (lane < 32) outp[(size_t)wid*32 + c] = acc + b2[c];
}

extern "C" void kernel_launch(void* const* d_in, const int* in_sizes, int n_in,
                              void* d_out, int out_size, void* d_ws, size_t ws_size,
                              hipStream_t stream)
{
    const float* x     = (const float*)d_in[0];
    const int*   ei    = (const int*)d_in[1];
    const float* W1    = (const float*)d_in[2];
    const float* at_s1 = (const float*)d_in[3];
    const float* at_d1 = (const float*)d_in[4];
    const float* b1    = (const float*)d_in[5];
    const float* W2    = (const float*)d_in[6];
    const float* at_s2 = (const float*)d_in[7];
    const float* at_d2 = (const float*)d_in[8];
    const float* b2    = (const float*)d_in[9];
    float* outp = (float*)d_out;

    const int N = in_sizes[0] / 128;
    const int E = in_sizes[1] / 2;
    const int Etot = E + N;

    float* f = (float*)d_ws;
    size_t off = 0;
    uint*  hb2 = (uint*)(f + off); off += (size_t)N*64;
    float* h1  = f + off; off += (size_t)N*128;
    float* exb = f + off; off += (size_t)Etot*4;
    float* as1 = f + off; off += (size_t)N*4;
    float* ad1 = f + off; off += (size_t)N*4;
    float* h2  = f + off; off += (size_t)N*32;
    float* as2 = f + off; off += (size_t)N;
    float* ad2 = f + off; off += (size_t)N;
    int* ib      = (int*)(f + off);
    int* counts  = ib;                   // N
    int* offs    = ib + N;               // N+1 (+pad)
    int* partials= ib + 2*N + 8;         // 256
    int* erank   = ib + 2*N + 8 + 256;   // Etot
    int* bsrc    = erank + Etot;         // Etot

    hipMemsetAsync(counts, 0, sizeof(int)*(size_t)N, stream);
    k_gemm1 <<<(N+63)/64,   256, 0, stream>>>(x, W1, hb2, N);
    k_alpha1<<<(N+3)/4,     256, 0, stream>>>(hb2, at_s1, at_d1, as1, ad1, N);
    k_count <<<(Etot+255)/256, 256, 0, stream>>>(ei, counts, erank, E, Etot);
    int nb = (N+255)/256;
    k_scan1 <<<nb, 256, 0, stream>>>(counts, offs, partials, N);
    k_scan2 <<<1, 256, 0, stream>>>(partials, nb);
    k_scan3 <<<nb, 256, 0, stream>>>(offs, partials, N, Etot);
    k_fill  <<<(Etot+255)/256, 256, 0, stream>>>(ei, offs, erank, bsrc, E, Etot);
    k_agg1  <<<(N+3)/4, 256, 0, stream>>>(hb2, (const float4*)as1, (const float4*)ad1,
                                          offs, bsrc, b1, exb, h1, N);
    k_l2pre <<<(N+7)/8, 256, 0, stream>>>(h1, W2, at_s2, at_d2, h2, as2, ad2, N);
    k_agg2  <<<(N+3)/4, 256, 0, stream>>>(h2, as2, ad2, offs, bsrc, b2, exb, outp, N);
}

// Round 5
// 208.199 us; speedup vs baseline: 1.6808x; 1.0055x over previous
//
#include <hip/hip_runtime.h>
#include <math.h>

#define NEG_SLOPE 0.2f
typedef unsigned int uint;

__device__ __forceinline__ float lrelu(float x){ return x > 0.f ? x : NEG_SLOPE*x; }
__device__ __forceinline__ float sel4(float a,float b,float c,float d,int comp){
    return comp==0 ? a : (comp==1 ? b : (comp==2 ? c : d));
}
__device__ __forceinline__ uint f2bf(float f){
    uint u = __float_as_uint(f);
    return (u + 0x7FFFu + ((u>>16)&1u)) >> 16;
}
__device__ __forceinline__ float bf_lo(uint u){ return __uint_as_float(u<<16); }
__device__ __forceinline__ float bf_hi(uint u){ return __uint_as_float(u & 0xFFFF0000u); }

// ---------------- GEMM1: hb2[N,64] (bf16 pairs) = pack(x[N,128] @ W1[128,128]) ----------------
__global__ __launch_bounds__(256) void k_gemm1(const float* __restrict__ x,
                                               const float* __restrict__ W,
                                               uint* __restrict__ hb2, int N)
{
    __shared__ __align__(16) float xs[32][68];   // [k][row]
    __shared__ __align__(16) float wl[32][140];  // [k][skewed col]
    const int tid = threadIdx.x;
    const int tr = tid >> 4, tc = tid & 15;
    const int row0 = blockIdx.x * 64;
    const int rr  = tid & 63;
    const int kk0 = (tid >> 6) << 3;
    const int kw  = tid >> 3;
    const int jc  = (tid & 7) << 4;
    const int jb  = tc << 3;
    const int pb  = jb + ((jb >> 5) << 2);
    float acc[4][8];
    #pragma unroll
    for (int r=0;r<4;r++)
        #pragma unroll
        for (int c=0;c<8;c++) acc[r][c]=0.f;

    for (int kc = 0; kc < 128; kc += 32) {
        int gr = row0 + rr;
        float4 a0 = make_float4(0,0,0,0), a1 = a0;
        if (gr < N) {
            const float* xp = &x[(size_t)gr*128 + kc + kk0];
            a0 = *(const float4*)xp;
            a1 = *(const float4*)(xp+4);
        }
        xs[kk0+0][rr]=a0.x; xs[kk0+1][rr]=a0.y; xs[kk0+2][rr]=a0.z; xs[kk0+3][rr]=a0.w;
        xs[kk0+4][rr]=a1.x; xs[kk0+5][rr]=a1.y; xs[kk0+6][rr]=a1.z; xs[kk0+7][rr]=a1.w;
        const float* wsrc = &W[(size_t)(kc+kw)*128 + jc];
        #pragma unroll
        for (int q=0;q<4;q++){
            float4 wv = *(const float4*)(wsrc + q*4);
            int j = jc + q*4;
            int p = j + ((j>>5)<<2);
            *(float4*)&wl[kw][p] = wv;
        }
        __syncthreads();
        #pragma unroll
        for (int k=0;k<32;k++){
            float4 xv = *(float4*)&xs[k][tr<<2];
            float4 w0 = *(float4*)&wl[k][pb];
            float4 w1 = *(float4*)&wl[k][pb+4];
            float xr[4]={xv.x,xv.y,xv.z,xv.w};
            float wv[8]={w0.x,w0.y,w0.z,w0.w,w1.x,w1.y,w1.z,w1.w};
            #pragma unroll
            for (int r=0;r<4;r++)
                #pragma unroll
                for (int c=0;c<8;c++) acc[r][c] = fmaf(xr[r], wv[c], acc[r][c]);
        }
        __syncthreads();
    }
    #pragma unroll
    for (int r=0;r<4;r++){
        int gr = row0 + (tr<<2) + r;
        if (gr < N){
            uint4 o;
            o.x = f2bf(acc[r][0]) | (f2bf(acc[r][1])<<16);
            o.y = f2bf(acc[r][2]) | (f2bf(acc[r][3])<<16);
            o.z = f2bf(acc[r][4]) | (f2bf(acc[r][5])<<16);
            o.w = f2bf(acc[r][6]) | (f2bf(acc[r][7])<<16);
            *(uint4*)&hb2[(size_t)gr*64 + (jb>>1)] = o;
        }
    }
}

// ---------------- alpha1 from bf16 h (wave per node, 16-lane head groups) ----------------
__global__ __launch_bounds__(256) void k_alpha1(const uint* __restrict__ hb2,
        const float* __restrict__ at_s, const float* __restrict__ at_d,
        float* __restrict__ as1, float* __restrict__ ad1, int N)
{
    int wid = (blockIdx.x << 2) + (threadIdx.x >> 6);
    int lane = threadIdx.x & 63;
    if (wid >= N) return;
    uint hv = hb2[(size_t)wid*64 + lane];      // channels 2*lane, 2*lane+1
    float f0 = bf_lo(hv), f1 = bf_hi(hv);
    float2 asv = *(const float2*)&at_s[2*lane];
    float2 adv = *(const float2*)&at_d[2*lane];
    float sa = f0*asv.x + f1*asv.y;
    float da = f0*adv.x + f1*adv.y;
    #pragma unroll
    for (int d=8; d>=1; d>>=1){ sa += __shfl_xor(sa,d); da += __shfl_xor(da,d); }
    if ((lane & 15) == 0){
        int head = lane >> 4;
        as1[(size_t)wid*4 + head] = sa;
        ad1[(size_t)wid*4 + head] = da;
    }
}

// ---------------- CSR build: count + rank (single atomic pass) ----------------
__global__ void k_count(const int* __restrict__ ei, int* __restrict__ counts,
                        int* __restrict__ erank, int E, int Etot){
    int eid = blockIdx.x*256 + threadIdx.x;
    if (eid >= Etot) return;
    int dst = (eid < E) ? ei[E + eid] : (eid - E);
    erank[eid] = atomicAdd(&counts[dst], 1);
}

__global__ __launch_bounds__(256) void k_scan1(const int* __restrict__ counts, int* __restrict__ offs,
                                               int* __restrict__ partials, int N){
    __shared__ int sm[256];
    int tid = threadIdx.x;
    int i = blockIdx.x*256 + tid;
    int v = (i < N) ? counts[i] : 0;
    sm[tid] = v;
    __syncthreads();
    for (int d=1; d<256; d<<=1){
        int t = (tid >= d) ? sm[tid-d] : 0;
        __syncthreads();
        sm[tid] += t;
        __syncthreads();
    }
    if (i < N) offs[i] = sm[tid] - v;
    if (tid == 255) partials[blockIdx.x] = sm[255];
}

__global__ __launch_bounds__(256) void k_scan2(int* partials, int nb){
    if (nb > 256){
        if (threadIdx.x == 0){
            int run = 0;
            for (int b=0;b<nb;b++){ int v = partials[b]; partials[b] = run; run += v; }
        }
        return;
    }
    __shared__ int sm[256];
    int tid = threadIdx.x;
    int v = (tid < nb) ? partials[tid] : 0;
    sm[tid] = v;
    __syncthreads();
    for (int d=1; d<256; d<<=1){
        int t = (tid >= d) ? sm[tid-d] : 0;
        __syncthreads();
        sm[tid] += t;
        __syncthreads();
    }
    if (tid < nb) partials[tid] = sm[tid] - v;
}

__global__ void k_scan3(int* __restrict__ offs, const int* __restrict__ partials, int N, int Etot){
    int i = blockIdx.x*256 + threadIdx.x;
    if (i < N) offs[i] += partials[blockIdx.x];
    if (i == 0) offs[N] = Etot;
}

__global__ void k_fill(const int* __restrict__ ei, const int* __restrict__ offs,
                       const int* __restrict__ erank, int* __restrict__ bsrc, int E, int Etot){
    int eid = blockIdx.x*256 + threadIdx.x;
    if (eid >= Etot) return;
    int s, d;
    if (eid < E){ s = ei[eid]; d = ei[E+eid]; }
    else        { s = eid - E; d = eid - E; }
    bsrc[offs[d] + erank[eid]] = s;
}

// ---------------- layer-1 agg + bias + ELU + FUSED layer-2 GEMM + alpha2 ----------------
// deg<=64 fast path identical to R4; epilogue computes h2 = h1 @ W2 in-block
// (W2 staged in LDS once per block) plus as2/ad2, so h1 never hits global.
__global__ __launch_bounds__(256) void k_agg1(const uint* __restrict__ hb2,
    const float4* __restrict__ as1v, const float4* __restrict__ ad1v,
    const int* __restrict__ offs, const int* __restrict__ bsrc,
    const float* __restrict__ b1, float* __restrict__ exb,
    const float* __restrict__ W2, const float* __restrict__ asrc2,
    const float* __restrict__ adst2, float* __restrict__ h2,
    float* __restrict__ as2, float* __restrict__ ad2, int N)
{
    __shared__ __align__(16) float w2s[4096];   // W2 [128][32]
    __shared__ float a2sL[32], a2dL[32];
    __shared__ float wsh[4][64][4];   // [wave][edge][head]
    __shared__ int   ssh[4][64];      // [wave][edge] src
    __shared__ float hsh[4][128];     // [wave][channel] h1 row
    const int tid = threadIdx.x;
    #pragma unroll
    for (int q=0;q<4;q++){
        int idx = q*1024 + tid*4;
        *(float4*)&w2s[idx] = *(const float4*)&W2[idx];
    }
    if (tid < 32){ a2sL[tid] = asrc2[tid]; a2dL[tid] = adst2[tid]; }
    __syncthreads();                  // before any divergence/early-return

    int wv   = tid >> 6;
    int wid  = (blockIdx.x << 2) + wv;
    int lane = tid & 63;
    if (wid >= N) return;
    int base = offs[wid];
    int deg  = offs[wid+1] - base;
    float4 adv = ad1v[wid];
    const int comp = lane >> 4;              // head of channels 2*lane, 2*lane+1
    float acc0=0.f, acc1=0.f;

    if (deg <= 64){
        const bool act = lane < deg;
        int sreg = 0;
        float l0=-1e30f,l1=-1e30f,l2=-1e30f,l3=-1e30f;
        if (act){
            sreg = bsrc[base+lane];
            float4 av = as1v[sreg];
            l0=lrelu(av.x+adv.x); l1=lrelu(av.y+adv.y);
            l2=lrelu(av.z+adv.z); l3=lrelu(av.w+adv.w);
        }
        float m0=l0,m1=l1,m2=l2,m3=l3;
        #pragma unroll
        for (int d=32; d>=1; d>>=1){
            m0=fmaxf(m0,__shfl_xor(m0,d)); m1=fmaxf(m1,__shfl_xor(m1,d));
            m2=fmaxf(m2,__shfl_xor(m2,d)); m3=fmaxf(m3,__shfl_xor(m3,d));
        }
        float e0=0.f,e1=0.f,e2=0.f,e3=0.f;
        if (act){
            e0=__expf(l0-m0); e1=__expf(l1-m1); e2=__expf(l2-m2); e3=__expf(l3-m3);
        }
        float s0=e0,s1=e1,s2=e2,s3=e3;
        #pragma unroll
        for (int d=32; d>=1; d>>=1){
            s0+=__shfl_xor(s0,d); s1+=__shfl_xor(s1,d);
            s2+=__shfl_xor(s2,d); s3+=__shfl_xor(s3,d);
        }
        if (act){
            ssh[wv][lane]    = sreg;
            wsh[wv][lane][0] = e0/s0;
            wsh[wv][lane][1] = e1/s1;
            wsh[wv][lane][2] = e2/s2;
            wsh[wv][lane][3] = e3/s3;
        }
        int j=0;
        for (; j+3 < deg; j+=4){
            int sA=ssh[wv][j],   sB=ssh[wv][j+1], sC=ssh[wv][j+2], sD=ssh[wv][j+3];
            float wA=wsh[wv][j][comp],   wB=wsh[wv][j+1][comp];
            float wC=wsh[wv][j+2][comp], wD=wsh[wv][j+3][comp];
            uint hA=hb2[(size_t)sA*64+lane], hB=hb2[(size_t)sB*64+lane];
            uint hC=hb2[(size_t)sC*64+lane], hD=hb2[(size_t)sD*64+lane];
            acc0 = fmaf(bf_lo(hA), wA, acc0); acc1 = fmaf(bf_hi(hA), wA, acc1);
            acc0 = fmaf(bf_lo(hB), wB, acc0); acc1 = fmaf(bf_hi(hB), wB, acc1);
            acc0 = fmaf(bf_lo(hC), wC, acc0); acc1 = fmaf(bf_hi(hC), wC, acc1);
            acc0 = fmaf(bf_lo(hD), wD, acc0); acc1 = fmaf(bf_hi(hD), wD, acc1);
        }
        for (; j < deg; j++){
            int sA = ssh[wv][j];
            float wA = wsh[wv][j][comp];
            uint hA = hb2[(size_t)sA*64+lane];
            acc0 = fmaf(bf_lo(hA), wA, acc0);
            acc1 = fmaf(bf_hi(hA), wA, acc1);
        }
    } else {
        // ---- fallback: 3-pass with exb cache (deg > 64) ----
        float m0=-1e30f,m1=-1e30f,m2=-1e30f,m3=-1e30f;
        for (int j=lane; j<deg; j+=64){
            int s = bsrc[base+j];
            float4 av = as1v[s];
            m0=fmaxf(m0,lrelu(av.x+adv.x)); m1=fmaxf(m1,lrelu(av.y+adv.y));
            m2=fmaxf(m2,lrelu(av.z+adv.z)); m3=fmaxf(m3,lrelu(av.w+adv.w));
        }
        #pragma unroll
        for (int d=32; d>=1; d>>=1){
            m0=fmaxf(m0,__shfl_xor(m0,d)); m1=fmaxf(m1,__shfl_xor(m1,d));
            m2=fmaxf(m2,__shfl_xor(m2,d)); m3=fmaxf(m3,__shfl_xor(m3,d));
        }
        float s0=0,s1=0,s2=0,s3=0;
        for (int j=lane; j<deg; j+=64){
            int s = bsrc[base+j];
            float4 av = as1v[s];
            float e0=__expf(lrelu(av.x+adv.x)-m0);
            float e1=__expf(lrelu(av.y+adv.y)-m1);
            float e2=__expf(lrelu(av.z+adv.z)-m2);
            float e3=__expf(lrelu(av.w+adv.w)-m3);
            s0+=e0; s1+=e1; s2+=e2; s3+=e3;
            *(float4*)&exb[(size_t)(base+j)*4] = make_float4(e0,e1,e2,e3);
        }
        #pragma unroll
        for (int d=32; d>=1; d>>=1){
            s0+=__shfl_xor(s0,d); s1+=__shfl_xor(s1,d);
            s2+=__shfl_xor(s2,d); s3+=__shfl_xor(s3,d);
        }
        float invc = 1.0f / sel4(s0,s1,s2,s3,comp);
        for (int j=0;j<deg;j++){
            int s = bsrc[base+j];
            float w = exb[(size_t)(base+j)*4 + comp]*invc;
            uint hv = hb2[(size_t)s*64 + lane];
            acc0 = fmaf(bf_lo(hv), w, acc0);
            acc1 = fmaf(bf_hi(hv), w, acc1);
        }
    }
    float2 bv = *(const float2*)&b1[2*lane];
    float r0 = acc0 + bv.x;
    float r1 = acc1 + bv.y;
    r0 = r0 > 0.f ? r0 : (__expf(r0) - 1.f);
    r1 = r1 > 0.f ? r1 : (__expf(r1) - 1.f);

    // ---- fused layer-2: h2 = h1 @ W2, alpha2 dots (wave-private LDS stage) ----
    hsh[wv][2*lane]   = r0;
    hsh[wv][2*lane+1] = r1;
    __threadfence_block();   // wave-internal LDS ordering (hsh is wave-private)
    const int c = lane & 31, half = lane >> 5;
    const float* hrow = &hsh[wv][half << 6];
    const float* wrow = &w2s[(half << 6)*32 + c];
    float a2 = 0.f;
    #pragma unroll 8
    for (int k=0;k<64;k++) a2 = fmaf(hrow[k], wrow[k*32], a2);
    a2 += __shfl_xor(a2, 32);          // full 128-dot; all lanes hold h2[c]
    float ps = a2 * a2sL[c], pd = a2 * a2dL[c];
    #pragma unroll
    for (int d=16; d>=1; d>>=1){ ps += __shfl_xor(ps,d); pd += __shfl_xor(pd,d); }
    if (lane == 0){ as2[wid] = ps; ad2[wid] = pd; }
    if (lane < 32) h2[(size_t)wid*32 + c] = a2;
}

// ---------------- layer-2 softmax + aggregate + bias -> output ----------------
__global__ __launch_bounds__(256) void k_agg2(const float* __restrict__ h2,
    const float* __restrict__ as2, const float* __restrict__ ad2,
    const int* __restrict__ offs, const int* __restrict__ bsrc,
    const float* __restrict__ b2, float* __restrict__ exb,
    float* __restrict__ outp, int N)
{
    __shared__ float w2sh[4][64];
    __shared__ int   s2sh[4][64];
    int wv   = threadIdx.x >> 6;
    int wid  = (blockIdx.x << 2) + wv;
    int lane = threadIdx.x & 63;
    if (wid >= N) return;
    int base = offs[wid], deg = offs[wid+1] - base;
    float adn = ad2[wid];
    int half = lane >> 5, c = lane & 31;
    float acc = 0.f;

    if (deg <= 64){
        const bool act = lane < deg;
        int sreg = 0; float l = -1e30f;
        if (act){ sreg = bsrc[base+lane]; l = lrelu(as2[sreg] + adn); }
        float m = l;
        #pragma unroll
        for (int d=32; d>=1; d>>=1) m = fmaxf(m, __shfl_xor(m,d));
        float e = act ? __expf(l - m) : 0.f;
        float sum = e;
        #pragma unroll
        for (int d=32; d>=1; d>>=1) sum += __shfl_xor(sum,d);
        if (act){ s2sh[wv][lane] = sreg; w2sh[wv][lane] = e/sum; }
        int j = half;
        for (; j+2 < deg; j += 4){
            int sA = s2sh[wv][j], sB = s2sh[wv][j+2];
            float wA = w2sh[wv][j], wB = w2sh[wv][j+2];
            acc = fmaf(h2[(size_t)sA*32 + c], wA, acc);
            acc = fmaf(h2[(size_t)sB*32 + c], wB, acc);
        }
        for (; j < deg; j += 2){
            acc = fmaf(h2[(size_t)s2sh[wv][j]*32 + c], w2sh[wv][j], acc);
        }
    } else {
        float m = -1e30f;
        for (int j=lane; j<deg; j+=64){
            int s = bsrc[base+j];
            m = fmaxf(m, lrelu(as2[s] + adn));
        }
        #pragma unroll
        for (int d=32; d>=1; d>>=1) m = fmaxf(m, __shfl_xor(m,d));
        float sum = 0.f;
        for (int j=lane; j<deg; j+=64){
            int s = bsrc[base+j];
            float ex = __expf(lrelu(as2[s] + adn) - m);
            sum += ex;
            exb[base+j] = ex;
        }
        #pragma unroll
        for (int d=32; d>=1; d>>=1) sum += __shfl_xor(sum,d);
        float inv = 1.f/sum;
        for (int j=half; j<deg; j+=2){
            int s = bsrc[base+j];
            acc = fmaf(h2[(size_t)s*32 + c], exb[base+j]*inv, acc);
        }
    }
    acc += __shfl_xor(acc, 32);
    if (lane < 32) outp[(size_t)wid*32 + c] = acc + b2[c];
}

extern "C" void kernel_launch(void* const* d_in, const int* in_sizes, int n_in,
                              void* d_out, int out_size, void* d_ws, size_t ws_size,
                              hipStream_t stream)
{
    const float* x     = (const float*)d_in[0];
    const int*   ei    = (const int*)d_in[1];
    const float* W1    = (const float*)d_in[2];
    const float* at_s1 = (const float*)d_in[3];
    const float* at_d1 = (const float*)d_in[4];
    const float* b1    = (const float*)d_in[5];
    const float* W2    = (const float*)d_in[6];
    const float* at_s2 = (const float*)d_in[7];
    const float* at_d2 = (const float*)d_in[8];
    const float* b2    = (const float*)d_in[9];
    float* outp = (float*)d_out;

    const int N = in_sizes[0] / 128;
    const int E = in_sizes[1] / 2;
    const int Etot = E + N;

    float* f = (float*)d_ws;
    size_t off = 0;
    uint*  hb2 = (uint*)(f + off); off += (size_t)N*64;
    float* exb = f + off; off += (size_t)Etot*4;
    float* as1 = f + off; off += (size_t)N*4;
    float* ad1 = f + off; off += (size_t)N*4;
    float* h2  = f + off; off += (size_t)N*32;
    float* as2 = f + off; off += (size_t)N;
    float* ad2 = f + off; off += (size_t)N;
    int* ib      = (int*)(f + off);
    int* counts  = ib;                   // N
    int* offs    = ib + N;               // N+1 (+pad)
    int* partials= ib + 2*N + 8;         // 256
    int* erank   = ib + 2*N + 8 + 256;   // Etot
    int* bsrc    = erank + Etot;         // Etot

    hipMemsetAsync(counts, 0, sizeof(int)*(size_t)N, stream);
    k_gemm1 <<<(N+63)/64,   256, 0, stream>>>(x, W1, hb2, N);
    k_alpha1<<<(N+3)/4,     256, 0, stream>>>(hb2, at_s1, at_d1, as1, ad1, N);
    k_count <<<(Etot+255)/256, 256, 0, stream>>>(ei, counts, erank, E, Etot);
    int nb = (N+255)/256;
    k_scan1 <<<nb, 256, 0, stream>>>(counts, offs, partials, N);
    k_scan2 <<<1, 256, 0, stream>>>(partials, nb);
    k_scan3 <<<nb, 256, 0, stream>>>(offs, partials, N, Etot);
    k_fill  <<<(Etot+255)/256, 256, 0, stream>>>(ei, offs, erank, bsrc, E, Etot);
    k_agg1  <<<(N+3)/4, 256, 0, stream>>>(hb2, (const float4*)as1, (const float4*)ad1,
                                          offs, bsrc, b1, exb,
                                          W2, at_s2, at_d2, h2, as2, ad2, N);
    k_agg2  <<<(N+3)/4, 256, 0, stream>>>(h2, as2, ad2, offs, bsrc, b2, exb, outp, N);
}

// Round 6
// 205.726 us; speedup vs baseline: 1.7010x; 1.0120x over previous
//
#include <hip/hip_runtime.h>
#include <math.h>

#define NEG_SLOPE 0.2f
typedef unsigned int uint;

__device__ __forceinline__ float lrelu(float x){ return x > 0.f ? x : NEG_SLOPE*x; }
__device__ __forceinline__ float sel4(float a,float b,float c,float d,int comp){
    return comp==0 ? a : (comp==1 ? b : (comp==2 ? c : d));
}
__device__ __forceinline__ uint f2bf(float f){
    uint u = __float_as_uint(f);
    return (u + 0x7FFFu + ((u>>16)&1u)) >> 16;
}
__device__ __forceinline__ float bf_lo(uint u){ return __uint_as_float(u<<16); }
__device__ __forceinline__ float bf_hi(uint u){ return __uint_as_float(u & 0xFFFF0000u); }

// ---------------- GEMM1: hb2[N,64] (bf16 pairs) = pack(x[N,128] @ W1[128,128]) ----------------
__global__ __launch_bounds__(256) void k_gemm1(const float* __restrict__ x,
                                               const float* __restrict__ W,
                                               uint* __restrict__ hb2, int N)
{
    __shared__ __align__(16) float xs[32][68];   // [k][row]
    __shared__ __align__(16) float wl[32][140];  // [k][skewed col]
    const int tid = threadIdx.x;
    const int tr = tid >> 4, tc = tid & 15;
    const int row0 = blockIdx.x * 64;
    const int rr  = tid & 63;
    const int kk0 = (tid >> 6) << 3;
    const int kw  = tid >> 3;
    const int jc  = (tid & 7) << 4;
    const int jb  = tc << 3;
    const int pb  = jb + ((jb >> 5) << 2);
    float acc[4][8];
    #pragma unroll
    for (int r=0;r<4;r++)
        #pragma unroll
        for (int c=0;c<8;c++) acc[r][c]=0.f;

    for (int kc = 0; kc < 128; kc += 32) {
        int gr = row0 + rr;
        float4 a0 = make_float4(0,0,0,0), a1 = a0;
        if (gr < N) {
            const float* xp = &x[(size_t)gr*128 + kc + kk0];
            a0 = *(const float4*)xp;
            a1 = *(const float4*)(xp+4);
        }
        xs[kk0+0][rr]=a0.x; xs[kk0+1][rr]=a0.y; xs[kk0+2][rr]=a0.z; xs[kk0+3][rr]=a0.w;
        xs[kk0+4][rr]=a1.x; xs[kk0+5][rr]=a1.y; xs[kk0+6][rr]=a1.z; xs[kk0+7][rr]=a1.w;
        const float* wsrc = &W[(size_t)(kc+kw)*128 + jc];
        #pragma unroll
        for (int q=0;q<4;q++){
            float4 wv = *(const float4*)(wsrc + q*4);
            int j = jc + q*4;
            int p = j + ((j>>5)<<2);
            *(float4*)&wl[kw][p] = wv;
        }
        __syncthreads();
        #pragma unroll
        for (int k=0;k<32;k++){
            float4 xv = *(float4*)&xs[k][tr<<2];
            float4 w0 = *(float4*)&wl[k][pb];
            float4 w1 = *(float4*)&wl[k][pb+4];
            float xr[4]={xv.x,xv.y,xv.z,xv.w};
            float wv[8]={w0.x,w0.y,w0.z,w0.w,w1.x,w1.y,w1.z,w1.w};
            #pragma unroll
            for (int r=0;r<4;r++)
                #pragma unroll
                for (int c=0;c<8;c++) acc[r][c] = fmaf(xr[r], wv[c], acc[r][c]);
        }
        __syncthreads();
    }
    #pragma unroll
    for (int r=0;r<4;r++){
        int gr = row0 + (tr<<2) + r;
        if (gr < N){
            uint4 o;
            o.x = f2bf(acc[r][0]) | (f2bf(acc[r][1])<<16);
            o.y = f2bf(acc[r][2]) | (f2bf(acc[r][3])<<16);
            o.z = f2bf(acc[r][4]) | (f2bf(acc[r][5])<<16);
            o.w = f2bf(acc[r][6]) | (f2bf(acc[r][7])<<16);
            *(uint4*)&hb2[(size_t)gr*64 + (jb>>1)] = o;
        }
    }
}

// ---------------- alpha1 from bf16 h (wave per node, 16-lane head groups) ----------------
__global__ __launch_bounds__(256) void k_alpha1(const uint* __restrict__ hb2,
        const float* __restrict__ at_s, const float* __restrict__ at_d,
        float* __restrict__ as1, float* __restrict__ ad1, int N)
{
    int wid = (blockIdx.x << 2) + (threadIdx.x >> 6);
    int lane = threadIdx.x & 63;
    if (wid >= N) return;
    uint hv = hb2[(size_t)wid*64 + lane];      // channels 2*lane, 2*lane+1
    float f0 = bf_lo(hv), f1 = bf_hi(hv);
    float2 asv = *(const float2*)&at_s[2*lane];
    float2 adv = *(const float2*)&at_d[2*lane];
    float sa = f0*asv.x + f1*asv.y;
    float da = f0*adv.x + f1*adv.y;
    #pragma unroll
    for (int d=8; d>=1; d>>=1){ sa += __shfl_xor(sa,d); da += __shfl_xor(da,d); }
    if ((lane & 15) == 0){
        int head = lane >> 4;
        as1[(size_t)wid*4 + head] = sa;
        ad1[(size_t)wid*4 + head] = da;
    }
}

// ---------------- CSR build: count + rank (single atomic pass) ----------------
__global__ void k_count(const int* __restrict__ ei, int* __restrict__ counts,
                        int* __restrict__ erank, int E, int Etot){
    int eid = blockIdx.x*256 + threadIdx.x;
    if (eid >= Etot) return;
    int dst = (eid < E) ? ei[E + eid] : (eid - E);
    erank[eid] = atomicAdd(&counts[dst], 1);
}

__global__ __launch_bounds__(256) void k_scan1(const int* __restrict__ counts, int* __restrict__ offs,
                                               int* __restrict__ partials, int N){
    __shared__ int sm[256];
    int tid = threadIdx.x;
    int i = blockIdx.x*256 + tid;
    int v = (i < N) ? counts[i] : 0;
    sm[tid] = v;
    __syncthreads();
    for (int d=1; d<256; d<<=1){
        int t = (tid >= d) ? sm[tid-d] : 0;
        __syncthreads();
        sm[tid] += t;
        __syncthreads();
    }
    if (i < N) offs[i] = sm[tid] - v;
    if (tid == 255) partials[blockIdx.x] = sm[255];
}

// fused scan2+scan3: each block redundantly scans the (<=256) partials in LDS,
// then adds its block's exclusive prefix to its offs slice.
__global__ __launch_bounds__(256) void k_scan23(int* __restrict__ offs, const int* __restrict__ partials,
                                                int nb, int N, int Etot){
    __shared__ int sm[256];
    int tid = threadIdx.x;
    int v = (tid < nb) ? partials[tid] : 0;
    sm[tid] = v;
    __syncthreads();
    for (int d=1; d<256; d<<=1){
        int t = (tid >= d) ? sm[tid-d] : 0;
        __syncthreads();
        sm[tid] += t;
        __syncthreads();
    }
    int boff = (blockIdx.x == 0) ? 0 : sm[blockIdx.x - 1];  // inclusive prefix up to b-1
    int i = blockIdx.x*256 + tid;
    if (i < N) offs[i] += boff;
    if (i == 0) offs[N] = Etot;
}

// fallback pair for nb > 256 (not hit at N=50000)
__global__ void k_scan2s(int* partials, int nb){
    if (threadIdx.x == 0){
        int run = 0;
        for (int b=0;b<nb;b++){ int v = partials[b]; partials[b] = run; run += v; }
    }
}
__global__ void k_scan3s(int* __restrict__ offs, const int* __restrict__ partials, int N, int Etot){
    int i = blockIdx.x*256 + threadIdx.x;
    if (i < N) offs[i] += partials[blockIdx.x];
    if (i == 0) offs[N] = Etot;
}

__global__ void k_fill(const int* __restrict__ ei, const int* __restrict__ offs,
                       const int* __restrict__ erank, int* __restrict__ bsrc, int E, int Etot){
    int eid = blockIdx.x*256 + threadIdx.x;
    if (eid >= Etot) return;
    int s, d;
    if (eid < E){ s = ei[eid]; d = ei[E+eid]; }
    else        { s = eid - E; d = eid - E; }
    bsrc[offs[d] + erank[eid]] = s;
}

// ---------------- layer-1 softmax + aggregate + bias + ELU (R4-proven) ----------------
__global__ __launch_bounds__(256) void k_agg1(const uint* __restrict__ hb2,
    const float4* __restrict__ as1v, const float4* __restrict__ ad1v,
    const int* __restrict__ offs, const int* __restrict__ bsrc,
    const float* __restrict__ b1, float* __restrict__ exb,
    float* __restrict__ h1, int N)
{
    __shared__ float wsh[4][64][4];   // [wave][edge][head]
    __shared__ int   ssh[4][64];      // [wave][edge] src
    int wv   = threadIdx.x >> 6;
    int wid  = (blockIdx.x << 2) + wv;
    int lane = threadIdx.x & 63;
    if (wid >= N) return;
    int base = offs[wid];
    int deg  = offs[wid+1] - base;
    float4 adv = ad1v[wid];
    const int comp = lane >> 4;              // head of channels 2*lane, 2*lane+1
    float acc0=0.f, acc1=0.f;

    if (deg <= 64){
        const bool act = lane < deg;
        int sreg = 0;
        float l0=-1e30f,l1=-1e30f,l2=-1e30f,l3=-1e30f;
        if (act){
            sreg = bsrc[base+lane];
            float4 av = as1v[sreg];
            l0=lrelu(av.x+adv.x); l1=lrelu(av.y+adv.y);
            l2=lrelu(av.z+adv.z); l3=lrelu(av.w+adv.w);
        }
        float m0=l0,m1=l1,m2=l2,m3=l3;
        #pragma unroll
        for (int d=32; d>=1; d>>=1){
            m0=fmaxf(m0,__shfl_xor(m0,d)); m1=fmaxf(m1,__shfl_xor(m1,d));
            m2=fmaxf(m2,__shfl_xor(m2,d)); m3=fmaxf(m3,__shfl_xor(m3,d));
        }
        float e0=0.f,e1=0.f,e2=0.f,e3=0.f;
        if (act){
            e0=__expf(l0-m0); e1=__expf(l1-m1); e2=__expf(l2-m2); e3=__expf(l3-m3);
        }
        float s0=e0,s1=e1,s2=e2,s3=e3;
        #pragma unroll
        for (int d=32; d>=1; d>>=1){
            s0+=__shfl_xor(s0,d); s1+=__shfl_xor(s1,d);
            s2+=__shfl_xor(s2,d); s3+=__shfl_xor(s3,d);
        }
        if (act){
            ssh[wv][lane]    = sreg;
            wsh[wv][lane][0] = e0/s0;
            wsh[wv][lane][1] = e1/s1;
            wsh[wv][lane][2] = e2/s2;
            wsh[wv][lane][3] = e3/s3;
        }
        int j=0;
        for (; j+3 < deg; j+=4){
            int sA=ssh[wv][j],   sB=ssh[wv][j+1], sC=ssh[wv][j+2], sD=ssh[wv][j+3];
            float wA=wsh[wv][j][comp],   wB=wsh[wv][j+1][comp];
            float wC=wsh[wv][j+2][comp], wD=wsh[wv][j+3][comp];
            uint hA=hb2[(size_t)sA*64+lane], hB=hb2[(size_t)sB*64+lane];
            uint hC=hb2[(size_t)sC*64+lane], hD=hb2[(size_t)sD*64+lane];
            acc0 = fmaf(bf_lo(hA), wA, acc0); acc1 = fmaf(bf_hi(hA), wA, acc1);
            acc0 = fmaf(bf_lo(hB), wB, acc0); acc1 = fmaf(bf_hi(hB), wB, acc1);
            acc0 = fmaf(bf_lo(hC), wC, acc0); acc1 = fmaf(bf_hi(hC), wC, acc1);
            acc0 = fmaf(bf_lo(hD), wD, acc0); acc1 = fmaf(bf_hi(hD), wD, acc1);
        }
        for (; j < deg; j++){
            int sA = ssh[wv][j];
            float wA = wsh[wv][j][comp];
            uint hA = hb2[(size_t)sA*64+lane];
            acc0 = fmaf(bf_lo(hA), wA, acc0);
            acc1 = fmaf(bf_hi(hA), wA, acc1);
        }
    } else {
        // ---- fallback: 3-pass with exb cache (deg > 64) ----
        float m0=-1e30f,m1=-1e30f,m2=-1e30f,m3=-1e30f;
        for (int j=lane; j<deg; j+=64){
            int s = bsrc[base+j];
            float4 av = as1v[s];
            m0=fmaxf(m0,lrelu(av.x+adv.x)); m1=fmaxf(m1,lrelu(av.y+adv.y));
            m2=fmaxf(m2,lrelu(av.z+adv.z)); m3=fmaxf(m3,lrelu(av.w+adv.w));
        }
        #pragma unroll
        for (int d=32; d>=1; d>>=1){
            m0=fmaxf(m0,__shfl_xor(m0,d)); m1=fmaxf(m1,__shfl_xor(m1,d));
            m2=fmaxf(m2,__shfl_xor(m2,d)); m3=fmaxf(m3,__shfl_xor(m3,d));
        }
        float s0=0,s1=0,s2=0,s3=0;
        for (int j=lane; j<deg; j+=64){
            int s = bsrc[base+j];
            float4 av = as1v[s];
            float e0=__expf(lrelu(av.x+adv.x)-m0);
            float e1=__expf(lrelu(av.y+adv.y)-m1);
            float e2=__expf(lrelu(av.z+adv.z)-m2);
            float e3=__expf(lrelu(av.w+adv.w)-m3);
            s0+=e0; s1+=e1; s2+=e2; s3+=e3;
            *(float4*)&exb[(size_t)(base+j)*4] = make_float4(e0,e1,e2,e3);
        }
        #pragma unroll
        for (int d=32; d>=1; d>>=1){
            s0+=__shfl_xor(s0,d); s1+=__shfl_xor(s1,d);
            s2+=__shfl_xor(s2,d); s3+=__shfl_xor(s3,d);
        }
        float invc = 1.0f / sel4(s0,s1,s2,s3,comp);
        for (int j=0;j<deg;j++){
            int s = bsrc[base+j];
            float w = exb[(size_t)(base+j)*4 + comp]*invc;
            uint hv = hb2[(size_t)s*64 + lane];
            acc0 = fmaf(bf_lo(hv), w, acc0);
            acc1 = fmaf(bf_hi(hv), w, acc1);
        }
    }
    float2 bv = *(const float2*)&b1[2*lane];
    float r0 = acc0 + bv.x;
    float r1 = acc1 + bv.y;
    r0 = r0 > 0.f ? r0 : (__expf(r0) - 1.f);
    r1 = r1 > 0.f ? r1 : (__expf(r1) - 1.f);
    *(float2*)&h1[(size_t)wid*128 + 2*lane] = make_float2(r0, r1);
}

// ---------------- GEMM2 (h2 = h1 @ W2, bf16-packed out) + alpha2 ----------------
__global__ __launch_bounds__(256) void k_l2pre(const float* __restrict__ h1,
    const float* __restrict__ W2, const float* __restrict__ asrc2,
    const float* __restrict__ adst2, uint* __restrict__ h2b,
    float* __restrict__ as2, float* __restrict__ ad2, int N)
{
    __shared__ __align__(16) float w2s[4096];
    __shared__ float a2s[32], a2d[32];
    int tid = threadIdx.x;
    #pragma unroll
    for (int q=0;q<4;q++){
        int idx = q*1024 + tid*4;
        *(float4*)&w2s[idx] = *(const float4*)&W2[idx];
    }
    if (tid < 32){ a2s[tid] = asrc2[tid]; a2d[tid] = adst2[tid]; }
    __syncthreads();
    int node = blockIdx.x*8 + (tid>>5);
    if (node >= N) return;
    int c = tid & 31;
    float acc = 0.f;
    #pragma unroll 8
    for (int k=0;k<128;k+=4){
        float4 hv = *(const float4*)&h1[(size_t)node*128 + k];
        acc = fmaf(hv.x, w2s[(k+0)*32+c], acc);
        acc = fmaf(hv.y, w2s[(k+1)*32+c], acc);
        acc = fmaf(hv.z, w2s[(k+2)*32+c], acc);
        acc = fmaf(hv.w, w2s[(k+3)*32+c], acc);
    }
    float pr = __shfl_xor(acc, 1);           // partner channel's value
    if ((c & 1) == 0)
        h2b[(size_t)node*16 + (c>>1)] = f2bf(acc) | (f2bf(pr)<<16);
    float ps = acc * a2s[c], pd = acc * a2d[c];
    #pragma unroll
    for (int d=16; d>=1; d>>=1){ ps += __shfl_xor(ps,d); pd += __shfl_xor(pd,d); }
    if (c == 0){ as2[node] = ps; ad2[node] = pd; }
}

// ---------------- layer-2 softmax + aggregate + bias -> output (bf16 gather, 4 edge-slots) ----------------
__global__ __launch_bounds__(256) void k_agg2(const uint* __restrict__ h2b,
    const float* __restrict__ as2, const float* __restrict__ ad2,
    const int* __restrict__ offs, const int* __restrict__ bsrc,
    const float* __restrict__ b2, float* __restrict__ exb,
    float* __restrict__ outp, int N)
{
    __shared__ float w2sh[4][64];
    __shared__ int   s2sh[4][64];
    int wv   = threadIdx.x >> 6;
    int wid  = (blockIdx.x << 2) + wv;
    int lane = threadIdx.x & 63;
    if (wid >= N) return;
    int base = offs[wid], deg = offs[wid+1] - base;
    float adn = ad2[wid];
    const int c2 = lane & 15, slot = lane >> 4;   // channels 2*c2,2*c2+1 ; 4 edges in flight
    float acc0 = 0.f, acc1 = 0.f;

    if (deg <= 64){
        const bool act = lane < deg;
        int sreg = 0; float l = -1e30f;
        if (act){ sreg = bsrc[base+lane]; l = lrelu(as2[sreg] + adn); }
        float m = l;
        #pragma unroll
        for (int d=32; d>=1; d>>=1) m = fmaxf(m, __shfl_xor(m,d));
        float e = act ? __expf(l - m) : 0.f;
        float sum = e;
        #pragma unroll
        for (int d=32; d>=1; d>>=1) sum += __shfl_xor(sum,d);
        if (act){ s2sh[wv][lane] = sreg; w2sh[wv][lane] = e/sum; }
        for (int j=slot; j<deg; j+=4){
            int s  = s2sh[wv][j];
            float w = w2sh[wv][j];
            uint u = h2b[(size_t)s*16 + c2];
            acc0 = fmaf(bf_lo(u), w, acc0);
            acc1 = fmaf(bf_hi(u), w, acc1);
        }
    } else {
        float m = -1e30f;
        for (int j=lane; j<deg; j+=64){
            int s = bsrc[base+j];
            m = fmaxf(m, lrelu(as2[s] + adn));
        }
        #pragma unroll
        for (int d=32; d>=1; d>>=1) m = fmaxf(m, __shfl_xor(m,d));
        float sum = 0.f;
        for (int j=lane; j<deg; j+=64){
            int s = bsrc[base+j];
            float ex = __expf(lrelu(as2[s] + adn) - m);
            sum += ex;
            exb[base+j] = ex;
        }
        #pragma unroll
        for (int d=32; d>=1; d>>=1) sum += __shfl_xor(sum,d);
        float inv = 1.f/sum;
        for (int j=slot; j<deg; j+=4){
            int s  = bsrc[base+j];
            float w = exb[base+j]*inv;
            uint u = h2b[(size_t)s*16 + c2];
            acc0 = fmaf(bf_lo(u), w, acc0);
            acc1 = fmaf(bf_hi(u), w, acc1);
        }
    }
    acc0 += __shfl_xor(acc0, 16); acc0 += __shfl_xor(acc0, 32);
    acc1 += __shfl_xor(acc1, 16); acc1 += __shfl_xor(acc1, 32);
    if (lane < 16){
        float2 bv = *(const float2*)&b2[2*c2];
        *(float2*)&outp[(size_t)wid*32 + 2*c2] = make_float2(acc0 + bv.x, acc1 + bv.y);
    }
}

extern "C" void kernel_launch(void* const* d_in, const int* in_sizes, int n_in,
                              void* d_out, int out_size, void* d_ws, size_t ws_size,
                              hipStream_t stream)
{
    const float* x     = (const float*)d_in[0];
    const int*   ei    = (const int*)d_in[1];
    const float* W1    = (const float*)d_in[2];
    const float* at_s1 = (const float*)d_in[3];
    const float* at_d1 = (const float*)d_in[4];
    const float* b1    = (const float*)d_in[5];
    const float* W2    = (const float*)d_in[6];
    const float* at_s2 = (const float*)d_in[7];
    const float* at_d2 = (const float*)d_in[8];
    const float* b2    = (const float*)d_in[9];
    float* outp = (float*)d_out;

    const int N = in_sizes[0] / 128;
    const int E = in_sizes[1] / 2;
    const int Etot = E + N;

    float* f = (float*)d_ws;
    size_t off = 0;
    uint*  hb2 = (uint*)(f + off); off += (size_t)N*64;   // bf16-packed h
    float* h1  = f + off; off += (size_t)N*128;
    float* exb = f + off; off += (size_t)Etot*4;
    float* as1 = f + off; off += (size_t)N*4;
    float* ad1 = f + off; off += (size_t)N*4;
    uint*  h2b = (uint*)(f + off); off += (size_t)N*16;   // bf16-packed h2
    float* as2 = f + off; off += (size_t)N;
    float* ad2 = f + off; off += (size_t)N;
    int* ib      = (int*)(f + off);
    int* counts  = ib;                   // N
    int* offs    = ib + N;               // N+1 (+pad)
    int* partials= ib + 2*N + 8;         // 256
    int* erank   = ib + 2*N + 8 + 256;   // Etot
    int* bsrc    = erank + Etot;         // Etot

    hipMemsetAsync(counts, 0, sizeof(int)*(size_t)N, stream);
    k_gemm1 <<<(N+63)/64,   256, 0, stream>>>(x, W1, hb2, N);
    k_alpha1<<<(N+3)/4,     256, 0, stream>>>(hb2, at_s1, at_d1, as1, ad1, N);
    k_count <<<(Etot+255)/256, 256, 0, stream>>>(ei, counts, erank, E, Etot);
    int nb = (N+255)/256;
    k_scan1 <<<nb, 256, 0, stream>>>(counts, offs, partials, N);
    if (nb <= 256){
        k_scan23<<<nb, 256, 0, stream>>>(offs, partials, nb, N, Etot);
    } else {
        k_scan2s<<<1, 1, 0, stream>>>(partials, nb);
        k_scan3s<<<nb, 256, 0, stream>>>(offs, partials, N, Etot);
    }
    k_fill  <<<(Etot+255)/256, 256, 0, stream>>>(ei, offs, erank, bsrc, E, Etot);
    k_agg1  <<<(N+3)/4, 256, 0, stream>>>(hb2, (const float4*)as1, (const float4*)ad1,
                                          offs, bsrc, b1, exb, h1, N);
    k_l2pre <<<(N+7)/8, 256, 0, stream>>>(h1, W2, at_s2, at_d2, h2b, as2, ad2, N);
    k_agg2  <<<(N+3)/4, 256, 0, stream>>>(h2b, as2, ad2, offs, bsrc, b2, exb, outp, N);
}

// Round 7
// 185.129 us; speedup vs baseline: 1.8902x; 1.1113x over previous
//
#include <hip/hip_runtime.h>
#include <math.h>

#define NEG_SLOPE 0.2f
typedef unsigned int uint;
typedef __attribute__((ext_vector_type(8))) short short8;
typedef __attribute__((ext_vector_type(4))) float floatx4;

__device__ __forceinline__ float lrelu(float x){ return x > 0.f ? x : NEG_SLOPE*x; }
__device__ __forceinline__ float sel4(float a,float b,float c,float d,int comp){
    return comp==0 ? a : (comp==1 ? b : (comp==2 ? c : d));
}
__device__ __forceinline__ uint f2bf(float f){
    uint u = __float_as_uint(f);
    return (u + 0x7FFFu + ((u>>16)&1u)) >> 16;
}
__device__ __forceinline__ float bf_lo(uint u){ return __uint_as_float(u<<16); }
__device__ __forceinline__ float bf_hi(uint u){ return __uint_as_float(u & 0xFFFF0000u); }

// ---------------- MERGED: MFMA GEMM1 (blocks < GB) + edge count (blocks >= GB) ----------------
// gemm: hb2[N,64] (bf16 pairs) = pack(x[N,128] @ W1[128,128]) via mfma_f32_16x16x32_bf16.
// LDS tiles padded to 136 shorts/row: rows 16B-aligned (272=17*16), 2-way bank alias (free).
__global__ __launch_bounds__(256) void k_g1c(const float* __restrict__ x,
    const float* __restrict__ W, uint* __restrict__ hb2, int N, int GB,
    const int* __restrict__ ei, int* __restrict__ counts, int* __restrict__ erank,
    int E, int Etot)
{
    if (blockIdx.x >= GB){
        int eid = (blockIdx.x - GB)*256 + threadIdx.x;
        if (eid >= Etot) return;
        int dst = (eid < E) ? ei[E + eid] : (eid - E);
        erank[eid] = atomicAdd(&counts[dst], 1);
        return;
    }
    __shared__ __align__(16) ushort xt[64][136];   // x tile, bf16 [row][k]
    __shared__ __align__(16) ushort wt[128][136];  // W^T,    bf16 [col][k]
    const int tid = threadIdx.x;
    const int row0 = blockIdx.x * 64;
    // stage W^T (bf16): 16384 f32, 64/thread, coalesced reads, strided b16 writes (one-time)
    #pragma unroll
    for (int j=0;j<16;j++){
        int flat = j*1024 + tid*4;
        int k = flat >> 7, c = flat & 127;
        float4 wv = *(const float4*)&W[flat];
        wt[c+0][k] = (ushort)f2bf(wv.x);
        wt[c+1][k] = (ushort)f2bf(wv.y);
        wt[c+2][k] = (ushort)f2bf(wv.z);
        wt[c+3][k] = (ushort)f2bf(wv.w);
    }
    // stage x tile (bf16): coalesced float4 reads, uint2 LDS writes
    #pragma unroll
    for (int j=0;j<8;j++){
        int flat = j*1024 + tid*4;
        int r = flat >> 7, c = flat & 127;
        int gr = row0 + r;
        float4 xv = (gr < N) ? *(const float4*)&x[(size_t)gr*128 + c]
                             : make_float4(0.f,0.f,0.f,0.f);
        uint2 p;
        p.x = f2bf(xv.x) | (f2bf(xv.y)<<16);
        p.y = f2bf(xv.z) | (f2bf(xv.w)<<16);
        *(uint2*)&xt[r][c] = p;
    }
    __syncthreads();
    const int wv_ = tid >> 6, lane = tid & 63;
    const int l15 = lane & 15, hi = lane >> 4;
    const int arow = wv_*16 + l15;                 // A: row = lane&15
    floatx4 acc[8];
    #pragma unroll
    for (int t=0;t<8;t++) acc[t] = (floatx4){0.f,0.f,0.f,0.f};
    #pragma unroll
    for (int ks=0; ks<4; ks++){
        short8 a = *(short8*)&xt[arow][ks*32 + hi*8];      // k contiguous per lane
        #pragma unroll
        for (int ct=0; ct<8; ct++){
            short8 b = *(short8*)&wt[ct*16 + l15][ks*32 + hi*8];  // B^T convention
            acc[ct] = __builtin_amdgcn_mfma_f32_16x16x32_bf16(a, b, acc[ct], 0, 0, 0);
        }
    }
    // epilogue: D layout col=lane&15, row=(lane>>4)*4+reg (m89/m91); pack channel pairs
    #pragma unroll
    for (int ct=0; ct<8; ct++){
        #pragma unroll
        for (int r=0;r<4;r++){
            float v  = acc[ct][r];
            float pr = __shfl_xor(v, 1);               // partner channel c^1
            int gr = row0 + wv_*16 + (hi<<2) + r;
            if (((lane & 1) == 0) && gr < N)
                hb2[(size_t)gr*64 + ct*8 + (l15>>1)] = f2bf(v) | (f2bf(pr)<<16);
        }
    }
}

// ---------------- MERGED: alpha1 (blocks < AB) + scan1 (blocks >= AB) ----------------
__global__ __launch_bounds__(256) void k_a1s(const uint* __restrict__ hb2,
        const float* __restrict__ at_s, const float* __restrict__ at_d,
        float* __restrict__ as1, float* __restrict__ ad1, int N, int AB,
        const int* __restrict__ counts, int* __restrict__ offs, int* __restrict__ partials)
{
    __shared__ int sm[256];
    if (blockIdx.x >= AB){
        int bid = blockIdx.x - AB;
        int tid = threadIdx.x;
        int i = bid*256 + tid;
        int v = (i < N) ? counts[i] : 0;
        sm[tid] = v;
        __syncthreads();
        for (int d=1; d<256; d<<=1){
            int t = (tid >= d) ? sm[tid-d] : 0;
            __syncthreads();
            sm[tid] += t;
            __syncthreads();
        }
        if (i < N) offs[i] = sm[tid] - v;
        if (tid == 255) partials[bid] = sm[255];
        return;
    }
    int wid = (blockIdx.x << 2) + (threadIdx.x >> 6);
    int lane = threadIdx.x & 63;
    if (wid >= N) return;
    uint hv = hb2[(size_t)wid*64 + lane];      // channels 2*lane, 2*lane+1
    float f0 = bf_lo(hv), f1 = bf_hi(hv);
    float2 asv = *(const float2*)&at_s[2*lane];
    float2 adv = *(const float2*)&at_d[2*lane];
    float sa = f0*asv.x + f1*asv.y;
    float da = f0*adv.x + f1*adv.y;
    #pragma unroll
    for (int d=8; d>=1; d>>=1){ sa += __shfl_xor(sa,d); da += __shfl_xor(da,d); }
    if ((lane & 15) == 0){
        int head = lane >> 4;
        as1[(size_t)wid*4 + head] = sa;
        ad1[(size_t)wid*4 + head] = da;
    }
}

// fused scan2+scan3 (nb <= 256)
__global__ __launch_bounds__(256) void k_scan23(int* __restrict__ offs, const int* __restrict__ partials,
                                                int nb, int N, int Etot){
    __shared__ int sm[256];
    int tid = threadIdx.x;
    int v = (tid < nb) ? partials[tid] : 0;
    sm[tid] = v;
    __syncthreads();
    for (int d=1; d<256; d<<=1){
        int t = (tid >= d) ? sm[tid-d] : 0;
        __syncthreads();
        sm[tid] += t;
        __syncthreads();
    }
    int boff = (blockIdx.x == 0) ? 0 : sm[blockIdx.x - 1];
    int i = blockIdx.x*256 + tid;
    if (i < N) offs[i] += boff;
    if (i == 0) offs[N] = Etot;
}

// fallback pair for nb > 256 (not hit at N=50000)
__global__ void k_scan2s(int* partials, int nb){
    if (threadIdx.x == 0){
        int run = 0;
        for (int b=0;b<nb;b++){ int v = partials[b]; partials[b] = run; run += v; }
    }
}
__global__ void k_scan3s(int* __restrict__ offs, const int* __restrict__ partials, int N, int Etot){
    int i = blockIdx.x*256 + threadIdx.x;
    if (i < N) offs[i] += partials[blockIdx.x];
    if (i == 0) offs[N] = Etot;
}

__global__ void k_fill(const int* __restrict__ ei, const int* __restrict__ offs,
                       const int* __restrict__ erank, int* __restrict__ bsrc, int E, int Etot){
    int eid = blockIdx.x*256 + threadIdx.x;
    if (eid >= Etot) return;
    int s, d;
    if (eid < E){ s = ei[eid]; d = ei[E+eid]; }
    else        { s = eid - E; d = eid - E; }
    bsrc[offs[d] + erank[eid]] = s;
}

// ---------------- layer-1 softmax + aggregate + bias + ELU (R4-proven) ----------------
__global__ __launch_bounds__(256) void k_agg1(const uint* __restrict__ hb2,
    const float4* __restrict__ as1v, const float4* __restrict__ ad1v,
    const int* __restrict__ offs, const int* __restrict__ bsrc,
    const float* __restrict__ b1, float* __restrict__ exb,
    float* __restrict__ h1, int N)
{
    __shared__ float wsh[4][64][4];
    __shared__ int   ssh[4][64];
    int wv   = threadIdx.x >> 6;
    int wid  = (blockIdx.x << 2) + wv;
    int lane = threadIdx.x & 63;
    if (wid >= N) return;
    int base = offs[wid];
    int deg  = offs[wid+1] - base;
    float4 adv = ad1v[wid];
    const int comp = lane >> 4;
    float acc0=0.f, acc1=0.f;

    if (deg <= 64){
        const bool act = lane < deg;
        int sreg = 0;
        float l0=-1e30f,l1=-1e30f,l2=-1e30f,l3=-1e30f;
        if (act){
            sreg = bsrc[base+lane];
            float4 av = as1v[sreg];
            l0=lrelu(av.x+adv.x); l1=lrelu(av.y+adv.y);
            l2=lrelu(av.z+adv.z); l3=lrelu(av.w+adv.w);
        }
        float m0=l0,m1=l1,m2=l2,m3=l3;
        #pragma unroll
        for (int d=32; d>=1; d>>=1){
            m0=fmaxf(m0,__shfl_xor(m0,d)); m1=fmaxf(m1,__shfl_xor(m1,d));
            m2=fmaxf(m2,__shfl_xor(m2,d)); m3=fmaxf(m3,__shfl_xor(m3,d));
        }
        float e0=0.f,e1=0.f,e2=0.f,e3=0.f;
        if (act){
            e0=__expf(l0-m0); e1=__expf(l1-m1); e2=__expf(l2-m2); e3=__expf(l3-m3);
        }
        float s0=e0,s1=e1,s2=e2,s3=e3;
        #pragma unroll
        for (int d=32; d>=1; d>>=1){
            s0+=__shfl_xor(s0,d); s1+=__shfl_xor(s1,d);
            s2+=__shfl_xor(s2,d); s3+=__shfl_xor(s3,d);
        }
        if (act){
            ssh[wv][lane]    = sreg;
            wsh[wv][lane][0] = e0/s0;
            wsh[wv][lane][1] = e1/s1;
            wsh[wv][lane][2] = e2/s2;
            wsh[wv][lane][3] = e3/s3;
        }
        int j=0;
        for (; j+3 < deg; j+=4){
            int sA=ssh[wv][j],   sB=ssh[wv][j+1], sC=ssh[wv][j+2], sD=ssh[wv][j+3];
            float wA=wsh[wv][j][comp],   wB=wsh[wv][j+1][comp];
            float wC=wsh[wv][j+2][comp], wD=wsh[wv][j+3][comp];
            uint hA=hb2[(size_t)sA*64+lane], hB=hb2[(size_t)sB*64+lane];
            uint hC=hb2[(size_t)sC*64+lane], hD=hb2[(size_t)sD*64+lane];
            acc0 = fmaf(bf_lo(hA), wA, acc0); acc1 = fmaf(bf_hi(hA), wA, acc1);
            acc0 = fmaf(bf_lo(hB), wB, acc0); acc1 = fmaf(bf_hi(hB), wB, acc1);
            acc0 = fmaf(bf_lo(hC), wC, acc0); acc1 = fmaf(bf_hi(hC), wC, acc1);
            acc0 = fmaf(bf_lo(hD), wD, acc0); acc1 = fmaf(bf_hi(hD), wD, acc1);
        }
        for (; j < deg; j++){
            int sA = ssh[wv][j];
            float wA = wsh[wv][j][comp];
            uint hA = hb2[(size_t)sA*64+lane];
            acc0 = fmaf(bf_lo(hA), wA, acc0);
            acc1 = fmaf(bf_hi(hA), wA, acc1);
        }
    } else {
        float m0=-1e30f,m1=-1e30f,m2=-1e30f,m3=-1e30f;
        for (int j=lane; j<deg; j+=64){
            int s = bsrc[base+j];
            float4 av = as1v[s];
            m0=fmaxf(m0,lrelu(av.x+adv.x)); m1=fmaxf(m1,lrelu(av.y+adv.y));
            m2=fmaxf(m2,lrelu(av.z+adv.z)); m3=fmaxf(m3,lrelu(av.w+adv.w));
        }
        #pragma unroll
        for (int d=32; d>=1; d>>=1){
            m0=fmaxf(m0,__shfl_xor(m0,d)); m1=fmaxf(m1,__shfl_xor(m1,d));
            m2=fmaxf(m2,__shfl_xor(m2,d)); m3=fmaxf(m3,__shfl_xor(m3,d));
        }
        float s0=0,s1=0,s2=0,s3=0;
        for (int j=lane; j<deg; j+=64){
            int s = bsrc[base+j];
            float4 av = as1v[s];
            float e0=__expf(lrelu(av.x+adv.x)-m0);
            float e1=__expf(lrelu(av.y+adv.y)-m1);
            float e2=__expf(lrelu(av.z+adv.z)-m2);
            float e3=__expf(lrelu(av.w+adv.w)-m3);
            s0+=e0; s1+=e1; s2+=e2; s3+=e3;
            *(float4*)&exb[(size_t)(base+j)*4] = make_float4(e0,e1,e2,e3);
        }
        #pragma unroll
        for (int d=32; d>=1; d>>=1){
            s0+=__shfl_xor(s0,d); s1+=__shfl_xor(s1,d);
            s2+=__shfl_xor(s2,d); s3+=__shfl_xor(s3,d);
        }
        float invc = 1.0f / sel4(s0,s1,s2,s3,comp);
        for (int j=0;j<deg;j++){
            int s = bsrc[base+j];
            float w = exb[(size_t)(base+j)*4 + comp]*invc;
            uint hv = hb2[(size_t)s*64 + lane];
            acc0 = fmaf(bf_lo(hv), w, acc0);
            acc1 = fmaf(bf_hi(hv), w, acc1);
        }
    }
    float2 bv = *(const float2*)&b1[2*lane];
    float r0 = acc0 + bv.x;
    float r1 = acc1 + bv.y;
    r0 = r0 > 0.f ? r0 : (__expf(r0) - 1.f);
    r1 = r1 > 0.f ? r1 : (__expf(r1) - 1.f);
    *(float2*)&h1[(size_t)wid*128 + 2*lane] = make_float2(r0, r1);
}

// ---------------- GEMM2 (h2 = h1 @ W2, bf16-packed out) + alpha2 ----------------
__global__ __launch_bounds__(256) void k_l2pre(const float* __restrict__ h1,
    const float* __restrict__ W2, const float* __restrict__ asrc2,
    const float* __restrict__ adst2, uint* __restrict__ h2b,
    float* __restrict__ as2, float* __restrict__ ad2, int N)
{
    __shared__ __align__(16) float w2s[4096];
    __shared__ float a2s[32], a2d[32];
    int tid = threadIdx.x;
    #pragma unroll
    for (int q=0;q<4;q++){
        int idx = q*1024 + tid*4;
        *(float4*)&w2s[idx] = *(const float4*)&W2[idx];
    }
    if (tid < 32){ a2s[tid] = asrc2[tid]; a2d[tid] = adst2[tid]; }
    __syncthreads();
    int node = blockIdx.x*8 + (tid>>5);
    if (node >= N) return;
    int c = tid & 31;
    float acc = 0.f;
    #pragma unroll 8
    for (int k=0;k<128;k+=4){
        float4 hv = *(const float4*)&h1[(size_t)node*128 + k];
        acc = fmaf(hv.x, w2s[(k+0)*32+c], acc);
        acc = fmaf(hv.y, w2s[(k+1)*32+c], acc);
        acc = fmaf(hv.z, w2s[(k+2)*32+c], acc);
        acc = fmaf(hv.w, w2s[(k+3)*32+c], acc);
    }
    float pr = __shfl_xor(acc, 1);
    if ((c & 1) == 0)
        h2b[(size_t)node*16 + (c>>1)] = f2bf(acc) | (f2bf(pr)<<16);
    float ps = acc * a2s[c], pd = acc * a2d[c];
    #pragma unroll
    for (int d=16; d>=1; d>>=1){ ps += __shfl_xor(ps,d); pd += __shfl_xor(pd,d); }
    if (c == 0){ as2[node] = ps; ad2[node] = pd; }
}

// ---------------- layer-2 softmax + aggregate + bias -> output ----------------
__global__ __launch_bounds__(256) void k_agg2(const uint* __restrict__ h2b,
    const float* __restrict__ as2, const float* __restrict__ ad2,
    const int* __restrict__ offs, const int* __restrict__ bsrc,
    const float* __restrict__ b2, float* __restrict__ exb,
    float* __restrict__ outp, int N)
{
    __shared__ float w2sh[4][64];
    __shared__ int   s2sh[4][64];
    int wv   = threadIdx.x >> 6;
    int wid  = (blockIdx.x << 2) + wv;
    int lane = threadIdx.x & 63;
    if (wid >= N) return;
    int base = offs[wid], deg = offs[wid+1] - base;
    float adn = ad2[wid];
    const int c2 = lane & 15, slot = lane >> 4;
    float acc0 = 0.f, acc1 = 0.f;

    if (deg <= 64){
        const bool act = lane < deg;
        int sreg = 0; float l = -1e30f;
        if (act){ sreg = bsrc[base+lane]; l = lrelu(as2[sreg] + adn); }
        float m = l;
        #pragma unroll
        for (int d=32; d>=1; d>>=1) m = fmaxf(m, __shfl_xor(m,d));
        float e = act ? __expf(l - m) : 0.f;
        float sum = e;
        #pragma unroll
        for (int d=32; d>=1; d>>=1) sum += __shfl_xor(sum,d);
        if (act){ s2sh[wv][lane] = sreg; w2sh[wv][lane] = e/sum; }
        for (int j=slot; j<deg; j+=4){
            int s  = s2sh[wv][j];
            float w = w2sh[wv][j];
            uint u = h2b[(size_t)s*16 + c2];
            acc0 = fmaf(bf_lo(u), w, acc0);
            acc1 = fmaf(bf_hi(u), w, acc1);
        }
    } else {
        float m = -1e30f;
        for (int j=lane; j<deg; j+=64){
            int s = bsrc[base+j];
            m = fmaxf(m, lrelu(as2[s] + adn));
        }
        #pragma unroll
        for (int d=32; d>=1; d>>=1) m = fmaxf(m, __shfl_xor(m,d));
        float sum = 0.f;
        for (int j=lane; j<deg; j+=64){
            int s = bsrc[base+j];
            float ex = __expf(lrelu(as2[s] + adn) - m);
            sum += ex;
            exb[base+j] = ex;
        }
        #pragma unroll
        for (int d=32; d>=1; d>>=1) sum += __shfl_xor(sum,d);
        float inv = 1.f/sum;
        for (int j=slot; j<deg; j+=4){
            int s  = bsrc[base+j];
            float w = exb[base+j]*inv;
            uint u = h2b[(size_t)s*16 + c2];
            acc0 = fmaf(bf_lo(u), w, acc0);
            acc1 = fmaf(bf_hi(u), w, acc1);
        }
    }
    acc0 += __shfl_xor(acc0, 16); acc0 += __shfl_xor(acc0, 32);
    acc1 += __shfl_xor(acc1, 16); acc1 += __shfl_xor(acc1, 32);
    if (lane < 16){
        float2 bv = *(const float2*)&b2[2*c2];
        *(float2*)&outp[(size_t)wid*32 + 2*c2] = make_float2(acc0 + bv.x, acc1 + bv.y);
    }
}

extern "C" void kernel_launch(void* const* d_in, const int* in_sizes, int n_in,
                              void* d_out, int out_size, void* d_ws, size_t ws_size,
                              hipStream_t stream)
{
    const float* x     = (const float*)d_in[0];
    const int*   ei    = (const int*)d_in[1];
    const float* W1    = (const float*)d_in[2];
    const float* at_s1 = (const float*)d_in[3];
    const float* at_d1 = (const float*)d_in[4];
    const float* b1    = (const float*)d_in[5];
    const float* W2    = (const float*)d_in[6];
    const float* at_s2 = (const float*)d_in[7];
    const float* at_d2 = (const float*)d_in[8];
    const float* b2    = (const float*)d_in[9];
    float* outp = (float*)d_out;

    const int N = in_sizes[0] / 128;
    const int E = in_sizes[1] / 2;
    const int Etot = E + N;

    float* f = (float*)d_ws;
    size_t off = 0;
    uint*  hb2 = (uint*)(f + off); off += (size_t)N*64;   // bf16-packed h
    float* h1  = f + off; off += (size_t)N*128;
    float* exb = f + off; off += (size_t)Etot*4;
    float* as1 = f + off; off += (size_t)N*4;
    float* ad1 = f + off; off += (size_t)N*4;
    uint*  h2b = (uint*)(f + off); off += (size_t)N*16;   // bf16-packed h2
    float* as2 = f + off; off += (size_t)N;
    float* ad2 = f + off; off += (size_t)N;
    int* ib      = (int*)(f + off);
    int* counts  = ib;                   // N
    int* offs    = ib + N;               // N+1 (+pad)
    int* partials= ib + 2*N + 8;         // 256
    int* erank   = ib + 2*N + 8 + 256;   // Etot
    int* bsrc    = erank + Etot;         // Etot

    const int GB = (N+63)/64, CB = (Etot+255)/256;
    const int AB = (N+3)/4,   nb = (N+255)/256;

    hipMemsetAsync(counts, 0, sizeof(int)*(size_t)N, stream);
    k_g1c <<<GB+CB, 256, 0, stream>>>(x, W1, hb2, N, GB, ei, counts, erank, E, Etot);
    k_a1s <<<AB+nb, 256, 0, stream>>>(hb2, at_s1, at_d1, as1, ad1, N, AB, counts, offs, partials);
    if (nb <= 256){
        k_scan23<<<nb, 256, 0, stream>>>(offs, partials, nb, N, Etot);
    } else {
        k_scan2s<<<1, 1, 0, stream>>>(partials, nb);
        k_scan3s<<<nb, 256, 0, stream>>>(offs, partials, N, Etot);
    }
    k_fill  <<<(Etot+255)/256, 256, 0, stream>>>(ei, offs, erank, bsrc, E, Etot);
    k_agg1  <<<(N+3)/4, 256, 0, stream>>>(hb2, (const float4*)as1, (const float4*)ad1,
                                          offs, bsrc, b1, exb, h1, N);
    k_l2pre <<<(N+7)/8, 256, 0, stream>>>(h1, W2, at_s2, at_d2, h2b, as2, ad2, N);
    k_agg2  <<<(N+3)/4, 256, 0, stream>>>(h2b, as2, ad2, offs, bsrc, b2, exb, outp, N);
}

// Round 8
// 176.806 us; speedup vs baseline: 1.9792x; 1.0471x over previous
//
#include <hip/hip_runtime.h>
#include <math.h>

#define NEG_SLOPE 0.2f
typedef unsigned int uint;
typedef __attribute__((ext_vector_type(8))) short short8;
typedef __attribute__((ext_vector_type(4))) float floatx4;

__device__ __forceinline__ float lrelu(float x){ return x > 0.f ? x : NEG_SLOPE*x; }
__device__ __forceinline__ float sel4(float a,float b,float c,float d,int comp){
    return comp==0 ? a : (comp==1 ? b : (comp==2 ? c : d));
}
__device__ __forceinline__ uint f2bf(float f){
    uint u = __float_as_uint(f);
    return (u + 0x7FFFu + ((u>>16)&1u)) >> 16;
}
__device__ __forceinline__ float bf_lo(uint u){ return __uint_as_float(u<<16); }
__device__ __forceinline__ float bf_hi(uint u){ return __uint_as_float(u & 0xFFFF0000u); }

// ---------------- prep: zero counts (all blocks) + W1^T -> bf16 (blocks < 16) ----------------
__global__ __launch_bounds__(256) void k_prep(const float* __restrict__ W,
                                              ushort* __restrict__ wtb,
                                              int* __restrict__ counts, int N)
{
    int i = blockIdx.x*256 + threadIdx.x;
    if (i < N) counts[i] = 0;
    if (blockIdx.x < 16){
        int flat = blockIdx.x*1024 + threadIdx.x*4;       // 16 blocks x 1024 = 16384
        int k = flat >> 7, c = flat & 127;
        float4 wv = *(const float4*)&W[flat];             // coalesced read
        wtb[(size_t)(c+0)*128 + k] = (ushort)f2bf(wv.x);  // scattered 2B writes (L2)
        wtb[(size_t)(c+1)*128 + k] = (ushort)f2bf(wv.y);
        wtb[(size_t)(c+2)*128 + k] = (ushort)f2bf(wv.z);
        wtb[(size_t)(c+3)*128 + k] = (ushort)f2bf(wv.w);
    }
}

// ---------------- MERGED: MFMA GEMM1 (blocks < GB) + edge count (blocks >= GB) ----------------
// hb2[N,64] (bf16 pairs) = pack(x[N,128] @ W1) via mfma_f32_16x16x32_bf16.
// B-fragments straight from global wtb (L2-resident); only x tile staged in LDS.
__global__ __launch_bounds__(256) void k_g1c(const float* __restrict__ x,
    const ushort* __restrict__ wtb, uint* __restrict__ hb2, int N, int GB,
    const int* __restrict__ ei, int* __restrict__ counts, int* __restrict__ erank,
    int E, int Etot)
{
    if (blockIdx.x >= GB){
        int eid = (blockIdx.x - GB)*256 + threadIdx.x;
        if (eid >= Etot) return;
        int dst = (eid < E) ? ei[E + eid] : (eid - E);
        erank[eid] = atomicAdd(&counts[dst], 1);
        return;
    }
    __shared__ __align__(16) ushort xt[64][136];   // x tile, bf16 [row][k]; 2-way alias = free
    const int tid = threadIdx.x;
    const int row0 = blockIdx.x * 64;
    #pragma unroll
    for (int j=0;j<8;j++){
        int flat = j*1024 + tid*4;
        int r = flat >> 7, c = flat & 127;
        int gr = row0 + r;
        float4 xv = (gr < N) ? *(const float4*)&x[(size_t)gr*128 + c]
                             : make_float4(0.f,0.f,0.f,0.f);
        uint2 p;
        p.x = f2bf(xv.x) | (f2bf(xv.y)<<16);
        p.y = f2bf(xv.z) | (f2bf(xv.w)<<16);
        *(uint2*)&xt[r][c] = p;
    }
    __syncthreads();
    const int wv_ = tid >> 6, lane = tid & 63;
    const int l15 = lane & 15, hi = lane >> 4;
    const int arow = wv_*16 + l15;                 // A: row = lane&15
    floatx4 acc[8];
    #pragma unroll
    for (int t=0;t<8;t++) acc[t] = (floatx4){0.f,0.f,0.f,0.f};
    #pragma unroll
    for (int ks=0; ks<4; ks++){
        short8 a = *(short8*)&xt[arow][ks*32 + hi*8];      // k contiguous per lane
        #pragma unroll
        for (int ct=0; ct<8; ct++){
            short8 b = *(const short8*)&wtb[(size_t)(ct*16 + l15)*128 + ks*32 + hi*8];
            acc[ct] = __builtin_amdgcn_mfma_f32_16x16x32_bf16(a, b, acc[ct], 0, 0, 0);
        }
    }
    // epilogue: D layout col=lane&15, row=(lane>>4)*4+reg (m89/m91); pack channel pairs
    #pragma unroll
    for (int ct=0; ct<8; ct++){
        #pragma unroll
        for (int r=0;r<4;r++){
            float v  = acc[ct][r];
            float pr = __shfl_xor(v, 1);               // partner channel c^1
            int gr = row0 + wv_*16 + (hi<<2) + r;
            if (((lane & 1) == 0) && gr < N)
                hb2[(size_t)gr*64 + ct*8 + (l15>>1)] = f2bf(v) | (f2bf(pr)<<16);
        }
    }
}

// ---------------- MERGED: alpha1 (blocks < AB) + scan1 (blocks >= AB) ----------------
__global__ __launch_bounds__(256) void k_a1s(const uint* __restrict__ hb2,
        const float* __restrict__ at_s, const float* __restrict__ at_d,
        float* __restrict__ as1, float* __restrict__ ad1, int N, int AB,
        const int* __restrict__ counts, int* __restrict__ offs, int* __restrict__ partials)
{
    __shared__ int sm[256];
    if (blockIdx.x >= AB){
        int bid = blockIdx.x - AB;
        int tid = threadIdx.x;
        int i = bid*256 + tid;
        int v = (i < N) ? counts[i] : 0;
        sm[tid] = v;
        __syncthreads();
        for (int d=1; d<256; d<<=1){
            int t = (tid >= d) ? sm[tid-d] : 0;
            __syncthreads();
            sm[tid] += t;
            __syncthreads();
        }
        if (i < N) offs[i] = sm[tid] - v;
        if (tid == 255) partials[bid] = sm[255];
        return;
    }
    int wid = (blockIdx.x << 2) + (threadIdx.x >> 6);
    int lane = threadIdx.x & 63;
    if (wid >= N) return;
    uint hv = hb2[(size_t)wid*64 + lane];      // channels 2*lane, 2*lane+1
    float f0 = bf_lo(hv), f1 = bf_hi(hv);
    float2 asv = *(const float2*)&at_s[2*lane];
    float2 adv = *(const float2*)&at_d[2*lane];
    float sa = f0*asv.x + f1*asv.y;
    float da = f0*adv.x + f1*adv.y;
    #pragma unroll
    for (int d=8; d>=1; d>>=1){ sa += __shfl_xor(sa,d); da += __shfl_xor(da,d); }
    if ((lane & 15) == 0){
        int head = lane >> 4;
        as1[(size_t)wid*4 + head] = sa;
        ad1[(size_t)wid*4 + head] = da;
    }
}

// fused scan2+scan3 (nb <= 256)
__global__ __launch_bounds__(256) void k_scan23(int* __restrict__ offs, const int* __restrict__ partials,
                                                int nb, int N, int Etot){
    __shared__ int sm[256];
    int tid = threadIdx.x;
    int v = (tid < nb) ? partials[tid] : 0;
    sm[tid] = v;
    __syncthreads();
    for (int d=1; d<256; d<<=1){
        int t = (tid >= d) ? sm[tid-d] : 0;
        __syncthreads();
        sm[tid] += t;
        __syncthreads();
    }
    int boff = (blockIdx.x == 0) ? 0 : sm[blockIdx.x - 1];
    int i = blockIdx.x*256 + tid;
    if (i < N) offs[i] += boff;
    if (i == 0) offs[N] = Etot;
}

// fallback pair for nb > 256 (not hit at N=50000)
__global__ void k_scan2s(int* partials, int nb){
    if (threadIdx.x == 0){
        int run = 0;
        for (int b=0;b<nb;b++){ int v = partials[b]; partials[b] = run; run += v; }
    }
}
__global__ void k_scan3s(int* __restrict__ offs, const int* __restrict__ partials, int N, int Etot){
    int i = blockIdx.x*256 + threadIdx.x;
    if (i < N) offs[i] += partials[blockIdx.x];
    if (i == 0) offs[N] = Etot;
}

__global__ void k_fill(const int* __restrict__ ei, const int* __restrict__ offs,
                       const int* __restrict__ erank, int* __restrict__ bsrc, int E, int Etot){
    int eid = blockIdx.x*256 + threadIdx.x;
    if (eid >= Etot) return;
    int s, d;
    if (eid < E){ s = ei[eid]; d = ei[E+eid]; }
    else        { s = eid - E; d = eid - E; }
    bsrc[offs[d] + erank[eid]] = s;
}

// ---------------- layer-1 softmax + aggregate + bias + ELU (R4-proven) ----------------
__global__ __launch_bounds__(256) void k_agg1(const uint* __restrict__ hb2,
    const float4* __restrict__ as1v, const float4* __restrict__ ad1v,
    const int* __restrict__ offs, const int* __restrict__ bsrc,
    const float* __restrict__ b1, float* __restrict__ exb,
    float* __restrict__ h1, int N)
{
    __shared__ float wsh[4][64][4];
    __shared__ int   ssh[4][64];
    int wv   = threadIdx.x >> 6;
    int wid  = (blockIdx.x << 2) + wv;
    int lane = threadIdx.x & 63;
    if (wid >= N) return;
    int base = offs[wid];
    int deg  = offs[wid+1] - base;
    float4 adv = ad1v[wid];
    const int comp = lane >> 4;
    float acc0=0.f, acc1=0.f;

    if (deg <= 64){
        const bool act = lane < deg;
        int sreg = 0;
        float l0=-1e30f,l1=-1e30f,l2=-1e30f,l3=-1e30f;
        if (act){
            sreg = bsrc[base+lane];
            float4 av = as1v[sreg];
            l0=lrelu(av.x+adv.x); l1=lrelu(av.y+adv.y);
            l2=lrelu(av.z+adv.z); l3=lrelu(av.w+adv.w);
        }
        float m0=l0,m1=l1,m2=l2,m3=l3;
        #pragma unroll
        for (int d=32; d>=1; d>>=1){
            m0=fmaxf(m0,__shfl_xor(m0,d)); m1=fmaxf(m1,__shfl_xor(m1,d));
            m2=fmaxf(m2,__shfl_xor(m2,d)); m3=fmaxf(m3,__shfl_xor(m3,d));
        }
        float e0=0.f,e1=0.f,e2=0.f,e3=0.f;
        if (act){
            e0=__expf(l0-m0); e1=__expf(l1-m1); e2=__expf(l2-m2); e3=__expf(l3-m3);
        }
        float s0=e0,s1=e1,s2=e2,s3=e3;
        #pragma unroll
        for (int d=32; d>=1; d>>=1){
            s0+=__shfl_xor(s0,d); s1+=__shfl_xor(s1,d);
            s2+=__shfl_xor(s2,d); s3+=__shfl_xor(s3,d);
        }
        if (act){
            ssh[wv][lane]    = sreg;
            wsh[wv][lane][0] = e0/s0;
            wsh[wv][lane][1] = e1/s1;
            wsh[wv][lane][2] = e2/s2;
            wsh[wv][lane][3] = e3/s3;
        }
        int j=0;
        for (; j+3 < deg; j+=4){
            int sA=ssh[wv][j],   sB=ssh[wv][j+1], sC=ssh[wv][j+2], sD=ssh[wv][j+3];
            float wA=wsh[wv][j][comp],   wB=wsh[wv][j+1][comp];
            float wC=wsh[wv][j+2][comp], wD=wsh[wv][j+3][comp];
            uint hA=hb2[(size_t)sA*64+lane], hB=hb2[(size_t)sB*64+lane];
            uint hC=hb2[(size_t)sC*64+lane], hD=hb2[(size_t)sD*64+lane];
            acc0 = fmaf(bf_lo(hA), wA, acc0); acc1 = fmaf(bf_hi(hA), wA, acc1);
            acc0 = fmaf(bf_lo(hB), wB, acc0); acc1 = fmaf(bf_hi(hB), wB, acc1);
            acc0 = fmaf(bf_lo(hC), wC, acc0); acc1 = fmaf(bf_hi(hC), wC, acc1);
            acc0 = fmaf(bf_lo(hD), wD, acc0); acc1 = fmaf(bf_hi(hD), wD, acc1);
        }
        for (; j < deg; j++){
            int sA = ssh[wv][j];
            float wA = wsh[wv][j][comp];
            uint hA = hb2[(size_t)sA*64+lane];
            acc0 = fmaf(bf_lo(hA), wA, acc0);
            acc1 = fmaf(bf_hi(hA), wA, acc1);
        }
    } else {
        float m0=-1e30f,m1=-1e30f,m2=-1e30f,m3=-1e30f;
        for (int j=lane; j<deg; j+=64){
            int s = bsrc[base+j];
            float4 av = as1v[s];
            m0=fmaxf(m0,lrelu(av.x+adv.x)); m1=fmaxf(m1,lrelu(av.y+adv.y));
            m2=fmaxf(m2,lrelu(av.z+adv.z)); m3=fmaxf(m3,lrelu(av.w+adv.w));
        }
        #pragma unroll
        for (int d=32; d>=1; d>>=1){
            m0=fmaxf(m0,__shfl_xor(m0,d)); m1=fmaxf(m1,__shfl_xor(m1,d));
            m2=fmaxf(m2,__shfl_xor(m2,d)); m3=fmaxf(m3,__shfl_xor(m3,d));
        }
        float s0=0,s1=0,s2=0,s3=0;
        for (int j=lane; j<deg; j+=64){
            int s = bsrc[base+j];
            float4 av = as1v[s];
            float e0=__expf(lrelu(av.x+adv.x)-m0);
            float e1=__expf(lrelu(av.y+adv.y)-m1);
            float e2=__expf(lrelu(av.z+adv.z)-m2);
            float e3=__expf(lrelu(av.w+adv.w)-m3);
            s0+=e0; s1+=e1; s2+=e2; s3+=e3;
            *(float4*)&exb[(size_t)(base+j)*4] = make_float4(e0,e1,e2,e3);
        }
        #pragma unroll
        for (int d=32; d>=1; d>>=1){
            s0+=__shfl_xor(s0,d); s1+=__shfl_xor(s1,d);
            s2+=__shfl_xor(s2,d); s3+=__shfl_xor(s3,d);
        }
        float invc = 1.0f / sel4(s0,s1,s2,s3,comp);
        for (int j=0;j<deg;j++){
            int s = bsrc[base+j];
            float w = exb[(size_t)(base+j)*4 + comp]*invc;
            uint hv = hb2[(size_t)s*64 + lane];
            acc0 = fmaf(bf_lo(hv), w, acc0);
            acc1 = fmaf(bf_hi(hv), w, acc1);
        }
    }
    float2 bv = *(const float2*)&b1[2*lane];
    float r0 = acc0 + bv.x;
    float r1 = acc1 + bv.y;
    r0 = r0 > 0.f ? r0 : (__expf(r0) - 1.f);
    r1 = r1 > 0.f ? r1 : (__expf(r1) - 1.f);
    *(float2*)&h1[(size_t)wid*128 + 2*lane] = make_float2(r0, r1);
}

// ---------------- GEMM2 (h2 = h1 @ W2, bf16-packed out) + alpha2 ----------------
__global__ __launch_bounds__(256) void k_l2pre(const float* __restrict__ h1,
    const float* __restrict__ W2, const float* __restrict__ asrc2,
    const float* __restrict__ adst2, uint* __restrict__ h2b,
    float* __restrict__ as2, float* __restrict__ ad2, int N)
{
    __shared__ __align__(16) float w2s[4096];
    __shared__ float a2s[32], a2d[32];
    int tid = threadIdx.x;
    #pragma unroll
    for (int q=0;q<4;q++){
        int idx = q*1024 + tid*4;
        *(float4*)&w2s[idx] = *(const float4*)&W2[idx];
    }
    if (tid < 32){ a2s[tid] = asrc2[tid]; a2d[tid] = adst2[tid]; }
    __syncthreads();
    int node = blockIdx.x*8 + (tid>>5);
    if (node >= N) return;
    int c = tid & 31;
    float acc = 0.f;
    #pragma unroll 8
    for (int k=0;k<128;k+=4){
        float4 hv = *(const float4*)&h1[(size_t)node*128 + k];
        acc = fmaf(hv.x, w2s[(k+0)*32+c], acc);
        acc = fmaf(hv.y, w2s[(k+1)*32+c], acc);
        acc = fmaf(hv.z, w2s[(k+2)*32+c], acc);
        acc = fmaf(hv.w, w2s[(k+3)*32+c], acc);
    }
    float pr = __shfl_xor(acc, 1);
    if ((c & 1) == 0)
        h2b[(size_t)node*16 + (c>>1)] = f2bf(acc) | (f2bf(pr)<<16);
    float ps = acc * a2s[c], pd = acc * a2d[c];
    #pragma unroll
    for (int d=16; d>=1; d>>=1){ ps += __shfl_xor(ps,d); pd += __shfl_xor(pd,d); }
    if (c == 0){ as2[node] = ps; ad2[node] = pd; }
}

// ---------------- layer-2 softmax + aggregate + bias -> output ----------------
__global__ __launch_bounds__(256) void k_agg2(const uint* __restrict__ h2b,
    const float* __restrict__ as2, const float* __restrict__ ad2,
    const int* __restrict__ offs, const int* __restrict__ bsrc,
    const float* __restrict__ b2, float* __restrict__ exb,
    float* __restrict__ outp, int N)
{
    __shared__ float w2sh[4][64];
    __shared__ int   s2sh[4][64];
    int wv   = threadIdx.x >> 6;
    int wid  = (blockIdx.x << 2) + wv;
    int lane = threadIdx.x & 63;
    if (wid >= N) return;
    int base = offs[wid], deg = offs[wid+1] - base;
    float adn = ad2[wid];
    const int c2 = lane & 15, slot = lane >> 4;
    float acc0 = 0.f, acc1 = 0.f;

    if (deg <= 64){
        const bool act = lane < deg;
        int sreg = 0; float l = -1e30f;
        if (act){ sreg = bsrc[base+lane]; l = lrelu(as2[sreg] + adn); }
        float m = l;
        #pragma unroll
        for (int d=32; d>=1; d>>=1) m = fmaxf(m, __shfl_xor(m,d));
        float e = act ? __expf(l - m) : 0.f;
        float sum = e;
        #pragma unroll
        for (int d=32; d>=1; d>>=1) sum += __shfl_xor(sum,d);
        if (act){ s2sh[wv][lane] = sreg; w2sh[wv][lane] = e/sum; }
        for (int j=slot; j<deg; j+=4){
            int s  = s2sh[wv][j];
            float w = w2sh[wv][j];
            uint u = h2b[(size_t)s*16 + c2];
            acc0 = fmaf(bf_lo(u), w, acc0);
            acc1 = fmaf(bf_hi(u), w, acc1);
        }
    } else {
        float m = -1e30f;
        for (int j=lane; j<deg; j+=64){
            int s = bsrc[base+j];
            m = fmaxf(m, lrelu(as2[s] + adn));
        }
        #pragma unroll
        for (int d=32; d>=1; d>>=1) m = fmaxf(m, __shfl_xor(m,d));
        float sum = 0.f;
        for (int j=lane; j<deg; j+=64){
            int s = bsrc[base+j];
            float ex = __expf(lrelu(as2[s] + adn) - m);
            sum += ex;
            exb[base+j] = ex;
        }
        #pragma unroll
        for (int d=32; d>=1; d>>=1) sum += __shfl_xor(sum,d);
        float inv = 1.f/sum;
        for (int j=slot; j<deg; j+=4){
            int s  = bsrc[base+j];
            float w = exb[base+j]*inv;
            uint u = h2b[(size_t)s*16 + c2];
            acc0 = fmaf(bf_lo(u), w, acc0);
            acc1 = fmaf(bf_hi(u), w, acc1);
        }
    }
    acc0 += __shfl_xor(acc0, 16); acc0 += __shfl_xor(acc0, 32);
    acc1 += __shfl_xor(acc1, 16); acc1 += __shfl_xor(acc1, 32);
    if (lane < 16){
        float2 bv = *(const float2*)&b2[2*c2];
        *(float2*)&outp[(size_t)wid*32 + 2*c2] = make_float2(acc0 + bv.x, acc1 + bv.y);
    }
}

extern "C" void kernel_launch(void* const* d_in, const int* in_sizes, int n_in,
                              void* d_out, int out_size, void* d_ws, size_t ws_size,
                              hipStream_t stream)
{
    const float* x     = (const float*)d_in[0];
    const int*   ei    = (const int*)d_in[1];
    const float* W1    = (const float*)d_in[2];
    const float* at_s1 = (const float*)d_in[3];
    const float* at_d1 = (const float*)d_in[4];
    const float* b1    = (const float*)d_in[5];
    const float* W2    = (const float*)d_in[6];
    const float* at_s2 = (const float*)d_in[7];
    const float* at_d2 = (const float*)d_in[8];
    const float* b2    = (const float*)d_in[9];
    float* outp = (float*)d_out;

    const int N = in_sizes[0] / 128;
    const int E = in_sizes[1] / 2;
    const int Etot = E + N;

    float* f = (float*)d_ws;
    size_t off = 0;
    uint*  hb2 = (uint*)(f + off); off += (size_t)N*64;   // bf16-packed h
    float* h1  = f + off; off += (size_t)N*128;
    float* exb = f + off; off += (size_t)Etot*4;
    float* as1 = f + off; off += (size_t)N*4;
    float* ad1 = f + off; off += (size_t)N*4;
    uint*  h2b = (uint*)(f + off); off += (size_t)N*16;   // bf16-packed h2
    float* as2 = f + off; off += (size_t)N;
    float* ad2 = f + off; off += (size_t)N;
    ushort* wtb = (ushort*)(f + off); off += 8192;        // W1^T bf16 [128][128] (32KB)
    int* ib      = (int*)(f + off);
    int* counts  = ib;                   // N
    int* offs    = ib + N;               // N+1 (+pad)
    int* partials= ib + 2*N + 8;         // 256
    int* erank   = ib + 2*N + 8 + 256;   // Etot
    int* bsrc    = erank + Etot;         // Etot

    const int GB = (N+63)/64, CB = (Etot+255)/256;
    const int AB = (N+3)/4,   nb = (N+255)/256;

    k_prep <<<nb, 256, 0, stream>>>(W1, wtb, counts, N);
    k_g1c  <<<GB+CB, 256, 0, stream>>>(x, wtb, hb2, N, GB, ei, counts, erank, E, Etot);
    k_a1s  <<<AB+nb, 256, 0, stream>>>(hb2, at_s1, at_d1, as1, ad1, N, AB, counts, offs, partials);
    if (nb <= 256){
        k_scan23<<<nb, 256, 0, stream>>>(offs, partials, nb, N, Etot);
    } else {
        k_scan2s<<<1, 1, 0, stream>>>(partials, nb);
        k_scan3s<<<nb, 256, 0, stream>>>(offs, partials, N, Etot);
    }
    k_fill  <<<(Etot+255)/256, 256, 0, stream>>>(ei, offs, erank, bsrc, E, Etot);
    k_agg1  <<<(N+3)/4, 256, 0, stream>>>(hb2, (const float4*)as1, (const float4*)ad1,
                                          offs, bsrc, b1, exb, h1, N);
    k_l2pre <<<(N+7)/8, 256, 0, stream>>>(h1, W2, at_s2, at_d2, h2b, as2, ad2, N);
    k_agg2  <<<(N+3)/4, 256, 0, stream>>>(h2b, as2, ad2, offs, bsrc, b2, exb, outp, N);
}

// Round 9
// 167.482 us; speedup vs baseline: 2.0894x; 1.0557x over previous
//
#include <hip/hip_runtime.h>
#include <math.h>

#define NEG_SLOPE 0.2f
typedef unsigned int uint;
typedef __attribute__((ext_vector_type(8))) short short8;
typedef __attribute__((ext_vector_type(4))) float floatx4;

__device__ __forceinline__ float lrelu(float x){ return x > 0.f ? x : NEG_SLOPE*x; }
__device__ __forceinline__ float sel4(float a,float b,float c,float d,int comp){
    return comp==0 ? a : (comp==1 ? b : (comp==2 ? c : d));
}
__device__ __forceinline__ uint f2bf(float f){
    uint u = __float_as_uint(f);
    return (u + 0x7FFFu + ((u>>16)&1u)) >> 16;
}
__device__ __forceinline__ float bf_lo(uint u){ return __uint_as_float(u<<16); }
__device__ __forceinline__ float bf_hi(uint u){ return __uint_as_float(u & 0xFFFF0000u); }

// ---------------- prep: W1^T -> bf16 (16 blocks) ----------------
__global__ __launch_bounds__(256) void k_prep(const float* __restrict__ W,
                                              ushort* __restrict__ wtb)
{
    int flat = blockIdx.x*1024 + threadIdx.x*4;       // 16 blocks x 1024 = 16384
    int k = flat >> 7, c = flat & 127;
    float4 wv = *(const float4*)&W[flat];
    wtb[(size_t)(c+0)*128 + k] = (ushort)f2bf(wv.x);
    wtb[(size_t)(c+1)*128 + k] = (ushort)f2bf(wv.y);
    wtb[(size_t)(c+2)*128 + k] = (ushort)f2bf(wv.z);
    wtb[(size_t)(c+3)*128 + k] = (ushort)f2bf(wv.w);
}

// ---------------- MERGED: MFMA GEMM1 (blocks < GB) + bucket histogram (blocks >= GB) ----------------
__global__ __launch_bounds__(256) void k_g1b(const float* __restrict__ x,
    const ushort* __restrict__ wtb, uint* __restrict__ hb2, int N, int GB,
    const int* __restrict__ ei, int* __restrict__ bh, int E, int Etot, int NC, int NB)
{
    if (blockIdx.x >= GB){
        __shared__ uint hist[256];
        int c = blockIdx.x - GB;
        hist[threadIdx.x] = 0;
        __syncthreads();
        int e0 = c*4096;
        #pragma unroll
        for (int r=0;r<16;r++){
            int e = e0 + r*256 + threadIdx.x;
            if (e < Etot){
                int d = (e < E) ? ei[E+e] : (e-E);
                atomicAdd(&hist[d>>8], 1u);     // LDS atomic
            }
        }
        __syncthreads();
        int b = threadIdx.x;
        if (b < NB) bh[(size_t)b*NC + c] = (int)hist[b];
        return;
    }
    __shared__ __align__(16) ushort xt[64][136];   // x tile, bf16 [row][k]; 2-way alias = free
    const int tid = threadIdx.x;
    const int row0 = blockIdx.x * 64;
    #pragma unroll
    for (int j=0;j<8;j++){
        int flat = j*1024 + tid*4;
        int r = flat >> 7, c = flat & 127;
        int gr = row0 + r;
        float4 xv = (gr < N) ? *(const float4*)&x[(size_t)gr*128 + c]
                             : make_float4(0.f,0.f,0.f,0.f);
        uint2 p;
        p.x = f2bf(xv.x) | (f2bf(xv.y)<<16);
        p.y = f2bf(xv.z) | (f2bf(xv.w)<<16);
        *(uint2*)&xt[r][c] = p;
    }
    __syncthreads();
    const int wv_ = tid >> 6, lane = tid & 63;
    const int l15 = lane & 15, hi = lane >> 4;
    const int arow = wv_*16 + l15;
    floatx4 acc[8];
    #pragma unroll
    for (int t=0;t<8;t++) acc[t] = (floatx4){0.f,0.f,0.f,0.f};
    #pragma unroll
    for (int ks=0; ks<4; ks++){
        short8 a = *(short8*)&xt[arow][ks*32 + hi*8];
        #pragma unroll
        for (int ct=0; ct<8; ct++){
            short8 b = *(const short8*)&wtb[(size_t)(ct*16 + l15)*128 + ks*32 + hi*8];
            acc[ct] = __builtin_amdgcn_mfma_f32_16x16x32_bf16(a, b, acc[ct], 0, 0, 0);
        }
    }
    #pragma unroll
    for (int ct=0; ct<8; ct++){
        #pragma unroll
        for (int r=0;r<4;r++){
            float v  = acc[ct][r];
            float pr = __shfl_xor(v, 1);
            int gr = row0 + wv_*16 + (hi<<2) + r;
            if (((lane & 1) == 0) && gr < N)
                hb2[(size_t)gr*64 + ct*8 + (l15>>1)] = f2bf(v) | (f2bf(pr)<<16);
        }
    }
}

// ---------------- MERGED: alpha1 (blocks < AB) + bucket-scan level1 (blocks >= AB) ----------------
__global__ __launch_bounds__(256) void k_a1sc(const uint* __restrict__ hb2,
        const float* __restrict__ at_s, const float* __restrict__ at_d,
        float* __restrict__ as1, float* __restrict__ ad1, int N, int AB,
        const int* __restrict__ bh, int* __restrict__ bhs, int* __restrict__ partials2, int T)
{
    __shared__ int sm[256];
    if (blockIdx.x >= AB){
        int bid = blockIdx.x - AB;
        int tid = threadIdx.x;
        int i = bid*256 + tid;
        int v = (i < T) ? bh[i] : 0;
        sm[tid] = v;
        __syncthreads();
        for (int d=1; d<256; d<<=1){
            int t = (tid >= d) ? sm[tid-d] : 0;
            __syncthreads();
            sm[tid] += t;
            __syncthreads();
        }
        if (i < T) bhs[i] = sm[tid] - v;
        if (tid == 255) partials2[bid] = sm[255];
        return;
    }
    int wid = (blockIdx.x << 2) + (threadIdx.x >> 6);
    int lane = threadIdx.x & 63;
    if (wid >= N) return;
    uint hv = hb2[(size_t)wid*64 + lane];
    float f0 = bf_lo(hv), f1 = bf_hi(hv);
    float2 asv = *(const float2*)&at_s[2*lane];
    float2 adv = *(const float2*)&at_d[2*lane];
    float sa = f0*asv.x + f1*asv.y;
    float da = f0*adv.x + f1*adv.y;
    #pragma unroll
    for (int d=8; d>=1; d>>=1){ sa += __shfl_xor(sa,d); da += __shfl_xor(da,d); }
    if ((lane & 15) == 0){
        int head = lane >> 4;
        as1[(size_t)wid*4 + head] = sa;
        ad1[(size_t)wid*4 + head] = da;
    }
}

// ---------------- bucket-scan level2+add (L1 <= 256 blocks) ----------------
__global__ __launch_bounds__(256) void k_bscan23(int* __restrict__ bhs,
        const int* __restrict__ partials2, int nb2, int T)
{
    __shared__ int sm[256];
    int tid = threadIdx.x;
    int v = (tid < nb2) ? partials2[tid] : 0;
    sm[tid] = v;
    __syncthreads();
    for (int d=1; d<256; d<<=1){
        int t = (tid >= d) ? sm[tid-d] : 0;
        __syncthreads();
        sm[tid] += t;
        __syncthreads();
    }
    int boff = (blockIdx.x == 0) ? 0 : sm[blockIdx.x - 1];
    int i = blockIdx.x*256 + tid;
    if (i < T) bhs[i] += boff;
}

// serial fallback (T > 65536; not hit here)
__global__ void k_bscan2s(int* __restrict__ bhs, const int* __restrict__ bh, int T){
    if (threadIdx.x == 0){
        int run = 0;
        for (int i=0;i<T;i++){ bhs[i] = run; run += bh[i]; }
    }
}

// ---------------- scatter edges to bucket-major order (NC blocks) ----------------
__global__ __launch_bounds__(256) void k_bscat(const int* __restrict__ ei,
        const int* __restrict__ bhs, uint* __restrict__ epack,
        int E, int Etot, int NC)
{
    __shared__ uint cnt[256];
    int c = blockIdx.x, tid = threadIdx.x;
    cnt[tid] = 0;
    __syncthreads();
    int e0 = c*4096;
    #pragma unroll
    for (int r=0;r<16;r++){
        int e = e0 + r*256 + tid;
        if (e < Etot){
            int d, s;
            if (e < E){ s = ei[e]; d = ei[E+e]; }
            else      { s = e - E; d = e - E; }
            int b = d >> 8;
            uint lr = atomicAdd(&cnt[b], 1u);       // LDS atomic rank within (bucket,chunk)
            int pos = bhs[(size_t)b*NC + c] + (int)lr;
            epack[pos] = (uint)s | ((uint)(d & 255) << 16);
        }
    }
}

// ---------------- finalize: per-bucket node offsets + bsrc (NB blocks) ----------------
__global__ __launch_bounds__(256) void k_bfin(const uint* __restrict__ epack,
        const int* __restrict__ bhs, int* __restrict__ bsrc,
        int* __restrict__ offs, int N, int NB, int NC, int Etot)
{
    __shared__ int cnt[256], lofs[256], cnt2[256], sm[256];
    int b = blockIdx.x, tid = threadIdx.x;
    int start = bhs[(size_t)b*NC];
    int end   = (b+1 < NB) ? bhs[(size_t)(b+1)*NC] : Etot;
    cnt[tid] = 0; cnt2[tid] = 0;
    __syncthreads();
    for (int e = start + tid; e < end; e += 256)
        atomicAdd((uint*)&cnt[(epack[e] >> 16) & 255], 1u);
    __syncthreads();
    int v = cnt[tid];
    sm[tid] = v;
    __syncthreads();
    for (int d=1; d<256; d<<=1){
        int t = (tid >= d) ? sm[tid-d] : 0;
        __syncthreads();
        sm[tid] += t;
        __syncthreads();
    }
    lofs[tid] = sm[tid] - v;                  // exclusive within bucket
    int nd = b*256 + tid;
    if (nd <= N) offs[nd] = start + sm[tid] - v;
    __syncthreads();
    for (int e = start + tid; e < end; e += 256){
        uint u = epack[e];
        int dl = (u >> 16) & 255;
        int r = (int)atomicAdd((uint*)&cnt2[dl], 1u);   // LDS atomic
        bsrc[start + lofs[dl] + r] = (int)(u & 0xFFFFu);
    }
}

// ---------------- layer-1 softmax + aggregate + bias + ELU (R4-proven) ----------------
__global__ __launch_bounds__(256) void k_agg1(const uint* __restrict__ hb2,
    const float4* __restrict__ as1v, const float4* __restrict__ ad1v,
    const int* __restrict__ offs, const int* __restrict__ bsrc,
    const float* __restrict__ b1, float* __restrict__ exb,
    float* __restrict__ h1, int N)
{
    __shared__ float wsh[4][64][4];
    __shared__ int   ssh[4][64];
    int wv   = threadIdx.x >> 6;
    int wid  = (blockIdx.x << 2) + wv;
    int lane = threadIdx.x & 63;
    if (wid >= N) return;
    int base = offs[wid];
    int deg  = offs[wid+1] - base;
    float4 adv = ad1v[wid];
    const int comp = lane >> 4;
    float acc0=0.f, acc1=0.f;

    if (deg <= 64){
        const bool act = lane < deg;
        int sreg = 0;
        float l0=-1e30f,l1=-1e30f,l2=-1e30f,l3=-1e30f;
        if (act){
            sreg = bsrc[base+lane];
            float4 av = as1v[sreg];
            l0=lrelu(av.x+adv.x); l1=lrelu(av.y+adv.y);
            l2=lrelu(av.z+adv.z); l3=lrelu(av.w+adv.w);
        }
        float m0=l0,m1=l1,m2=l2,m3=l3;
        #pragma unroll
        for (int d=32; d>=1; d>>=1){
            m0=fmaxf(m0,__shfl_xor(m0,d)); m1=fmaxf(m1,__shfl_xor(m1,d));
            m2=fmaxf(m2,__shfl_xor(m2,d)); m3=fmaxf(m3,__shfl_xor(m3,d));
        }
        float e0=0.f,e1=0.f,e2=0.f,e3=0.f;
        if (act){
            e0=__expf(l0-m0); e1=__expf(l1-m1); e2=__expf(l2-m2); e3=__expf(l3-m3);
        }
        float s0=e0,s1=e1,s2=e2,s3=e3;
        #pragma unroll
        for (int d=32; d>=1; d>>=1){
            s0+=__shfl_xor(s0,d); s1+=__shfl_xor(s1,d);
            s2+=__shfl_xor(s2,d); s3+=__shfl_xor(s3,d);
        }
        if (act){
            ssh[wv][lane]    = sreg;
            wsh[wv][lane][0] = e0/s0;
            wsh[wv][lane][1] = e1/s1;
            wsh[wv][lane][2] = e2/s2;
            wsh[wv][lane][3] = e3/s3;
        }
        int j=0;
        for (; j+3 < deg; j+=4){
            int sA=ssh[wv][j],   sB=ssh[wv][j+1], sC=ssh[wv][j+2], sD=ssh[wv][j+3];
            float wA=wsh[wv][j][comp],   wB=wsh[wv][j+1][comp];
            float wC=wsh[wv][j+2][comp], wD=wsh[wv][j+3][comp];
            uint hA=hb2[(size_t)sA*64+lane], hB=hb2[(size_t)sB*64+lane];
            uint hC=hb2[(size_t)sC*64+lane], hD=hb2[(size_t)sD*64+lane];
            acc0 = fmaf(bf_lo(hA), wA, acc0); acc1 = fmaf(bf_hi(hA), wA, acc1);
            acc0 = fmaf(bf_lo(hB), wB, acc0); acc1 = fmaf(bf_hi(hB), wB, acc1);
            acc0 = fmaf(bf_lo(hC), wC, acc0); acc1 = fmaf(bf_hi(hC), wC, acc1);
            acc0 = fmaf(bf_lo(hD), wD, acc0); acc1 = fmaf(bf_hi(hD), wD, acc1);
        }
        for (; j < deg; j++){
            int sA = ssh[wv][j];
            float wA = wsh[wv][j][comp];
            uint hA = hb2[(size_t)sA*64+lane];
            acc0 = fmaf(bf_lo(hA), wA, acc0);
            acc1 = fmaf(bf_hi(hA), wA, acc1);
        }
    } else {
        float m0=-1e30f,m1=-1e30f,m2=-1e30f,m3=-1e30f;
        for (int j=lane; j<deg; j+=64){
            int s = bsrc[base+j];
            float4 av = as1v[s];
            m0=fmaxf(m0,lrelu(av.x+adv.x)); m1=fmaxf(m1,lrelu(av.y+adv.y));
            m2=fmaxf(m2,lrelu(av.z+adv.z)); m3=fmaxf(m3,lrelu(av.w+adv.w));
        }
        #pragma unroll
        for (int d=32; d>=1; d>>=1){
            m0=fmaxf(m0,__shfl_xor(m0,d)); m1=fmaxf(m1,__shfl_xor(m1,d));
            m2=fmaxf(m2,__shfl_xor(m2,d)); m3=fmaxf(m3,__shfl_xor(m3,d));
        }
        float s0=0,s1=0,s2=0,s3=0;
        for (int j=lane; j<deg; j+=64){
            int s = bsrc[base+j];
            float4 av = as1v[s];
            float e0=__expf(lrelu(av.x+adv.x)-m0);
            float e1=__expf(lrelu(av.y+adv.y)-m1);
            float e2=__expf(lrelu(av.z+adv.z)-m2);
            float e3=__expf(lrelu(av.w+adv.w)-m3);
            s0+=e0; s1+=e1; s2+=e2; s3+=e3;
            *(float4*)&exb[(size_t)(base+j)*4] = make_float4(e0,e1,e2,e3);
        }
        #pragma unroll
        for (int d=32; d>=1; d>>=1){
            s0+=__shfl_xor(s0,d); s1+=__shfl_xor(s1,d);
            s2+=__shfl_xor(s2,d); s3+=__shfl_xor(s3,d);
        }
        float invc = 1.0f / sel4(s0,s1,s2,s3,comp);
        for (int j=0;j<deg;j++){
            int s = bsrc[base+j];
            float w = exb[(size_t)(base+j)*4 + comp]*invc;
            uint hv = hb2[(size_t)s*64 + lane];
            acc0 = fmaf(bf_lo(hv), w, acc0);
            acc1 = fmaf(bf_hi(hv), w, acc1);
        }
    }
    float2 bv = *(const float2*)&b1[2*lane];
    float r0 = acc0 + bv.x;
    float r1 = acc1 + bv.y;
    r0 = r0 > 0.f ? r0 : (__expf(r0) - 1.f);
    r1 = r1 > 0.f ? r1 : (__expf(r1) - 1.f);
    *(float2*)&h1[(size_t)wid*128 + 2*lane] = make_float2(r0, r1);
}

// ---------------- GEMM2 (h2 = h1 @ W2, bf16-packed out) + alpha2 ----------------
__global__ __launch_bounds__(256) void k_l2pre(const float* __restrict__ h1,
    const float* __restrict__ W2, const float* __restrict__ asrc2,
    const float* __restrict__ adst2, uint* __restrict__ h2b,
    float* __restrict__ as2, float* __restrict__ ad2, int N)
{
    __shared__ __align__(16) float w2s[4096];
    __shared__ float a2s[32], a2d[32];
    int tid = threadIdx.x;
    #pragma unroll
    for (int q=0;q<4;q++){
        int idx = q*1024 + tid*4;
        *(float4*)&w2s[idx] = *(const float4*)&W2[idx];
    }
    if (tid < 32){ a2s[tid] = asrc2[tid]; a2d[tid] = adst2[tid]; }
    __syncthreads();
    int node = blockIdx.x*8 + (tid>>5);
    if (node >= N) return;
    int c = tid & 31;
    float acc = 0.f;
    #pragma unroll 8
    for (int k=0;k<128;k+=4){
        float4 hv = *(const float4*)&h1[(size_t)node*128 + k];
        acc = fmaf(hv.x, w2s[(k+0)*32+c], acc);
        acc = fmaf(hv.y, w2s[(k+1)*32+c], acc);
        acc = fmaf(hv.z, w2s[(k+2)*32+c], acc);
        acc = fmaf(hv.w, w2s[(k+3)*32+c], acc);
    }
    float pr = __shfl_xor(acc, 1);
    if ((c & 1) == 0)
        h2b[(size_t)node*16 + (c>>1)] = f2bf(acc) | (f2bf(pr)<<16);
    float ps = acc * a2s[c], pd = acc * a2d[c];
    #pragma unroll
    for (int d=16; d>=1; d>>=1){ ps += __shfl_xor(ps,d); pd += __shfl_xor(pd,d); }
    if (c == 0){ as2[node] = ps; ad2[node] = pd; }
}

// ---------------- layer-2 softmax + aggregate + bias -> output ----------------
__global__ __launch_bounds__(256) void k_agg2(const uint* __restrict__ h2b,
    const float* __restrict__ as2, const float* __restrict__ ad2,
    const int* __restrict__ offs, const int* __restrict__ bsrc,
    const float* __restrict__ b2, float* __restrict__ exb,
    float* __restrict__ outp, int N)
{
    __shared__ float w2sh[4][64];
    __shared__ int   s2sh[4][64];
    int wv   = threadIdx.x >> 6;
    int wid  = (blockIdx.x << 2) + wv;
    int lane = threadIdx.x & 63;
    if (wid >= N) return;
    int base = offs[wid], deg = offs[wid+1] - base;
    float adn = ad2[wid];
    const int c2 = lane & 15, slot = lane >> 4;
    float acc0 = 0.f, acc1 = 0.f;

    if (deg <= 64){
        const bool act = lane < deg;
        int sreg = 0; float l = -1e30f;
        if (act){ sreg = bsrc[base+lane]; l = lrelu(as2[sreg] + adn); }
        float m = l;
        #pragma unroll
        for (int d=32; d>=1; d>>=1) m = fmaxf(m, __shfl_xor(m,d));
        float e = act ? __expf(l - m) : 0.f;
        float sum = e;
        #pragma unroll
        for (int d=32; d>=1; d>>=1) sum += __shfl_xor(sum,d);
        if (act){ s2sh[wv][lane] = sreg; w2sh[wv][lane] = e/sum; }
        for (int j=slot; j<deg; j+=4){
            int s  = s2sh[wv][j];
            float w = w2sh[wv][j];
            uint u = h2b[(size_t)s*16 + c2];
            acc0 = fmaf(bf_lo(u), w, acc0);
            acc1 = fmaf(bf_hi(u), w, acc1);
        }
    } else {
        float m = -1e30f;
        for (int j=lane; j<deg; j+=64){
            int s = bsrc[base+j];
            m = fmaxf(m, lrelu(as2[s] + adn));
        }
        #pragma unroll
        for (int d=32; d>=1; d>>=1) m = fmaxf(m, __shfl_xor(m,d));
        float sum = 0.f;
        for (int j=lane; j<deg; j+=64){
            int s = bsrc[base+j];
            float ex = __expf(lrelu(as2[s] + adn) - m);
            sum += ex;
            exb[base+j] = ex;
        }
        #pragma unroll
        for (int d=32; d>=1; d>>=1) sum += __shfl_xor(sum,d);
        float inv = 1.f/sum;
        for (int j=slot; j<deg; j+=4){
            int s  = bsrc[base+j];
            float w = exb[base+j]*inv;
            uint u = h2b[(size_t)s*16 + c2];
            acc0 = fmaf(bf_lo(u), w, acc0);
            acc1 = fmaf(bf_hi(u), w, acc1);
        }
    }
    acc0 += __shfl_xor(acc0, 16); acc0 += __shfl_xor(acc0, 32);
    acc1 += __shfl_xor(acc1, 16); acc1 += __shfl_xor(acc1, 32);
    if (lane < 16){
        float2 bv = *(const float2*)&b2[2*c2];
        *(float2*)&outp[(size_t)wid*32 + 2*c2] = make_float2(acc0 + bv.x, acc1 + bv.y);
    }
}

extern "C" void kernel_launch(void* const* d_in, const int* in_sizes, int n_in,
                              void* d_out, int out_size, void* d_ws, size_t ws_size,
                              hipStream_t stream)
{
    const float* x     = (const float*)d_in[0];
    const int*   ei    = (const int*)d_in[1];
    const float* W1    = (const float*)d_in[2];
    const float* at_s1 = (const float*)d_in[3];
    const float* at_d1 = (const float*)d_in[4];
    const float* b1    = (const float*)d_in[5];
    const float* W2    = (const float*)d_in[6];
    const float* at_s2 = (const float*)d_in[7];
    const float* at_d2 = (const float*)d_in[8];
    const float* b2    = (const float*)d_in[9];
    float* outp = (float*)d_out;

    const int N = in_sizes[0] / 128;
    const int E = in_sizes[1] / 2;
    const int Etot = E + N;

    const int NB = (N + 255) >> 8;             // dst buckets (dst>>8)
    const int NC = (Etot + 4095) / 4096;       // edge chunks
    const int T  = NB * NC;                    // (bucket,chunk) cells
    const int L1 = (T + 255) / 256;            // level-1 scan blocks

    float* f = (float*)d_ws;
    size_t off = 0;
    uint*  hb2 = (uint*)(f + off); off += (size_t)N*64;   // bf16-packed h
    float* h1  = f + off; off += (size_t)N*128;
    float* exb = f + off; off += (size_t)Etot*4;
    float* as1 = f + off; off += (size_t)N*4;
    float* ad1 = f + off; off += (size_t)N*4;
    uint*  h2b = (uint*)(f + off); off += (size_t)N*16;   // bf16-packed h2
    float* as2 = f + off; off += (size_t)N;
    float* ad2 = f + off; off += (size_t)N;
    ushort* wtb = (ushort*)(f + off); off += 8192;        // W1^T bf16 (32KB)
    int* ib       = (int*)(f + off);
    int* offs     = ib;                        // N+1 (+pad)
    int* bh       = ib + N + 8;                // T
    int* bhs      = bh + T;                    // T
    int* partials2= bhs + T;                   // 256
    uint* epack   = (uint*)(partials2 + 256);  // Etot
    int* bsrc     = (int*)(epack + Etot);      // Etot

    const int GB = (N+63)/64;                  // gemm blocks
    const int AB = (N+3)/4;                    // alpha blocks

    k_prep <<<16, 256, 0, stream>>>(W1, wtb);
    k_g1b  <<<GB+NC, 256, 0, stream>>>(x, wtb, hb2, N, GB, ei, bh, E, Etot, NC, NB);
    k_a1sc <<<AB+L1, 256, 0, stream>>>(hb2, at_s1, at_d1, as1, ad1, N, AB,
                                       bh, bhs, partials2, T);
    if (L1 <= 256){
        k_bscan23<<<L1, 256, 0, stream>>>(bhs, partials2, L1, T);
    } else {
        k_bscan2s<<<1, 1, 0, stream>>>(bhs, bh, T);
    }
    k_bscat<<<NC, 256, 0, stream>>>(ei, bhs, epack, E, Etot, NC);
    k_bfin <<<NB, 256, 0, stream>>>(epack, bhs, bsrc, offs, N, NB, NC, Etot);
    k_agg1 <<<(N+3)/4, 256, 0, stream>>>(hb2, (const float4*)as1, (const float4*)ad1,
                                         offs, bsrc, b1, exb, h1, N);
    k_l2pre<<<(N+7)/8, 256, 0, stream>>>(h1, W2, at_s2, at_d2, h2b, as2, ad2, N);
    k_agg2 <<<(N+3)/4, 256, 0, stream>>>(h2b, as2, ad2, offs, bsrc, b2, exb, outp, N);
}

// Round 10
// 162.111 us; speedup vs baseline: 2.1586x; 1.0331x over previous
//
#include <hip/hip_runtime.h>
#include <math.h>

#define NEG_SLOPE 0.2f
typedef unsigned int uint;
typedef __attribute__((ext_vector_type(8))) short short8;
typedef __attribute__((ext_vector_type(4))) float floatx4;

__device__ __forceinline__ float lrelu(float x){ return x > 0.f ? x : NEG_SLOPE*x; }
__device__ __forceinline__ float sel4(float a,float b,float c,float d,int comp){
    return comp==0 ? a : (comp==1 ? b : (comp==2 ? c : d));
}
__device__ __forceinline__ uint f2bf(float f){
    uint u = __float_as_uint(f);
    return (u + 0x7FFFu + ((u>>16)&1u)) >> 16;
}
__device__ __forceinline__ float bf_lo(uint u){ return __uint_as_float(u<<16); }
__device__ __forceinline__ float bf_hi(uint u){ return __uint_as_float(u & 0xFFFF0000u); }
__device__ __forceinline__ float cexp(float x){ return __expf(fminf(x, 60.f)); }

// ---------------- prep: W1^T -> bf16 (16 blocks) ----------------
__global__ __launch_bounds__(256) void k_prep(const float* __restrict__ W,
                                              ushort* __restrict__ wtb)
{
    int flat = blockIdx.x*1024 + threadIdx.x*4;
    int k = flat >> 7, c = flat & 127;
    float4 wv = *(const float4*)&W[flat];
    wtb[(size_t)(c+0)*128 + k] = (ushort)f2bf(wv.x);
    wtb[(size_t)(c+1)*128 + k] = (ushort)f2bf(wv.y);
    wtb[(size_t)(c+2)*128 + k] = (ushort)f2bf(wv.z);
    wtb[(size_t)(c+3)*128 + k] = (ushort)f2bf(wv.w);
}

// ---------------- MERGED: MFMA GEMM1 (blocks < GB, 8 waves) + bucket histogram ----------------
__global__ __launch_bounds__(512) void k_g1b(const float* __restrict__ x,
    const ushort* __restrict__ wtb, uint* __restrict__ hb2, int N, int GB,
    const int* __restrict__ ei, int* __restrict__ bh, int E, int Etot, int NC, int NB)
{
    if (blockIdx.x >= GB){
        __shared__ uint hist[256];
        int c = blockIdx.x - GB;
        if (threadIdx.x < 256) hist[threadIdx.x] = 0;
        __syncthreads();
        int e0 = c*4096;
        #pragma unroll
        for (int r=0;r<8;r++){
            int e = e0 + r*512 + threadIdx.x;
            if (e < Etot){
                int d = (e < E) ? ei[E+e] : (e-E);
                atomicAdd(&hist[d>>8], 1u);     // LDS atomic
            }
        }
        __syncthreads();
        int b = threadIdx.x;
        if (b < NB) bh[(size_t)b*NC + c] = (int)hist[b];
        return;
    }
    __shared__ __align__(16) ushort xt[64][136];   // x tile, bf16 [row][k]; 2-way alias = free
    const int tid = threadIdx.x;
    const int row0 = blockIdx.x * 64;
    #pragma unroll
    for (int j=0;j<4;j++){
        int flat = j*2048 + tid*4;
        int r = flat >> 7, c = flat & 127;
        int gr = row0 + r;
        float4 xv = (gr < N) ? *(const float4*)&x[(size_t)gr*128 + c]
                             : make_float4(0.f,0.f,0.f,0.f);
        uint2 p;
        p.x = f2bf(xv.x) | (f2bf(xv.y)<<16);
        p.y = f2bf(xv.z) | (f2bf(xv.w)<<16);
        *(uint2*)&xt[r][c] = p;
    }
    __syncthreads();
    const int wv_ = tid >> 6, lane = tid & 63;
    const int l15 = lane & 15, hi = lane >> 4;
    const int rw = wv_ & 3, ch = wv_ >> 2;         // row strip, col half
    const int arow = rw*16 + l15;
    floatx4 acc[4];
    #pragma unroll
    for (int t=0;t<4;t++) acc[t] = (floatx4){0.f,0.f,0.f,0.f};
    #pragma unroll
    for (int ks=0; ks<4; ks++){
        short8 a = *(short8*)&xt[arow][ks*32 + hi*8];
        #pragma unroll
        for (int c4=0; c4<4; c4++){
            int ct = ch*4 + c4;
            short8 b = *(const short8*)&wtb[(size_t)(ct*16 + l15)*128 + ks*32 + hi*8];
            acc[c4] = __builtin_amdgcn_mfma_f32_16x16x32_bf16(a, b, acc[c4], 0, 0, 0);
        }
    }
    // D layout: col=lane&15, row=(lane>>4)*4+reg (m89/m91); pack channel pairs
    #pragma unroll
    for (int c4=0; c4<4; c4++){
        int ct = ch*4 + c4;
        #pragma unroll
        for (int r=0;r<4;r++){
            float v  = acc[c4][r];
            float pr = __shfl_xor(v, 1);
            int gr = row0 + rw*16 + (hi<<2) + r;
            if (((lane & 1) == 0) && gr < N)
                hb2[(size_t)gr*64 + ct*8 + (l15>>1)] = f2bf(v) | (f2bf(pr)<<16);
        }
    }
}

// ---------------- MERGED: alpha1 (blocks < AB) + bucket-scan level1 ----------------
__global__ __launch_bounds__(256) void k_a1sc(const uint* __restrict__ hb2,
        const float* __restrict__ at_s, const float* __restrict__ at_d,
        float* __restrict__ as1, float* __restrict__ ad1, int N, int AB,
        const int* __restrict__ bh, int* __restrict__ bhs, int* __restrict__ partials2, int T)
{
    __shared__ int sm[256];
    if (blockIdx.x >= AB){
        int bid = blockIdx.x - AB;
        int tid = threadIdx.x;
        int i = bid*256 + tid;
        int v = (i < T) ? bh[i] : 0;
        sm[tid] = v;
        __syncthreads();
        for (int d=1; d<256; d<<=1){
            int t = (tid >= d) ? sm[tid-d] : 0;
            __syncthreads();
            sm[tid] += t;
            __syncthreads();
        }
        if (i < T) bhs[i] = sm[tid] - v;
        if (tid == 255) partials2[bid] = sm[255];
        return;
    }
    int wid = (blockIdx.x << 2) + (threadIdx.x >> 6);
    int lane = threadIdx.x & 63;
    if (wid >= N) return;
    uint hv = hb2[(size_t)wid*64 + lane];
    float f0 = bf_lo(hv), f1 = bf_hi(hv);
    float2 asv = *(const float2*)&at_s[2*lane];
    float2 adv = *(const float2*)&at_d[2*lane];
    float sa = f0*asv.x + f1*asv.y;
    float da = f0*adv.x + f1*adv.y;
    #pragma unroll
    for (int d=8; d>=1; d>>=1){ sa += __shfl_xor(sa,d); da += __shfl_xor(da,d); }
    if ((lane & 15) == 0){
        int head = lane >> 4;
        as1[(size_t)wid*4 + head] = sa;
        ad1[(size_t)wid*4 + head] = da;
    }
}

// ---------------- bucket-scan level2+add ----------------
__global__ __launch_bounds__(256) void k_bscan23(int* __restrict__ bhs,
        const int* __restrict__ partials2, int nb2, int T)
{
    __shared__ int sm[256];
    int tid = threadIdx.x;
    int v = (tid < nb2) ? partials2[tid] : 0;
    sm[tid] = v;
    __syncthreads();
    for (int d=1; d<256; d<<=1){
        int t = (tid >= d) ? sm[tid-d] : 0;
        __syncthreads();
        sm[tid] += t;
        __syncthreads();
    }
    int boff = (blockIdx.x == 0) ? 0 : sm[blockIdx.x - 1];
    int i = blockIdx.x*256 + tid;
    if (i < T) bhs[i] += boff;
}

__global__ void k_bscan2s(int* __restrict__ bhs, const int* __restrict__ bh, int T){
    if (threadIdx.x == 0){
        int run = 0;
        for (int i=0;i<T;i++){ bhs[i] = run; run += bh[i]; }
    }
}

// ---------------- scatter edges to bucket-major order ----------------
__global__ __launch_bounds__(256) void k_bscat(const int* __restrict__ ei,
        const int* __restrict__ bhs, uint* __restrict__ epack,
        int E, int Etot, int NC)
{
    __shared__ uint cnt[256];
    int c = blockIdx.x, tid = threadIdx.x;
    cnt[tid] = 0;
    __syncthreads();
    int e0 = c*4096;
    #pragma unroll
    for (int r=0;r<16;r++){
        int e = e0 + r*256 + tid;
        if (e < Etot){
            int d, s;
            if (e < E){ s = ei[e]; d = ei[E+e]; }
            else      { s = e - E; d = e - E; }
            int b = d >> 8;
            uint lr = atomicAdd(&cnt[b], 1u);
            int pos = bhs[(size_t)b*NC + c] + (int)lr;
            epack[pos] = (uint)s | ((uint)(d & 255) << 16);
        }
    }
}

// ---------------- finalize: per-bucket node offsets + bsrc ----------------
__global__ __launch_bounds__(256) void k_bfin(const uint* __restrict__ epack,
        const int* __restrict__ bhs, int* __restrict__ bsrc,
        int* __restrict__ offs, int N, int NB, int NC, int Etot)
{
    __shared__ int cnt[256], lofs[256], cnt2[256], sm[256];
    int b = blockIdx.x, tid = threadIdx.x;
    int start = bhs[(size_t)b*NC];
    int end   = (b+1 < NB) ? bhs[(size_t)(b+1)*NC] : Etot;
    cnt[tid] = 0; cnt2[tid] = 0;
    __syncthreads();
    for (int e = start + tid; e < end; e += 256)
        atomicAdd((uint*)&cnt[(epack[e] >> 16) & 255], 1u);
    __syncthreads();
    int v = cnt[tid];
    sm[tid] = v;
    __syncthreads();
    for (int d=1; d<256; d<<=1){
        int t = (tid >= d) ? sm[tid-d] : 0;
        __syncthreads();
        sm[tid] += t;
        __syncthreads();
    }
    lofs[tid] = sm[tid] - v;
    int nd = b*256 + tid;
    if (nd <= N) offs[nd] = start + sm[tid] - v;
    __syncthreads();
    for (int e = start + tid; e < end; e += 256){
        uint u = epack[e];
        int dl = (u >> 16) & 255;
        int r = (int)atomicAdd((uint*)&cnt2[dl], 1u);
        bsrc[start + lofs[dl] + r] = (int)(u & 0xFFFFu);
    }
}

// ---------------- layer-1 softmax (max-free) + aggregate + bias + ELU ----------------
__global__ __launch_bounds__(256) void k_agg1(const uint* __restrict__ hb2,
    const float4* __restrict__ as1v, const float4* __restrict__ ad1v,
    const int* __restrict__ offs, const int* __restrict__ bsrc,
    const float* __restrict__ b1, float* __restrict__ exb,
    float* __restrict__ h1, int N)
{
    __shared__ float wsh[4][64][4];   // [wave][edge][head]
    __shared__ int   ssh[4][64];      // [wave][edge] src<<6
    int wv   = threadIdx.x >> 6;
    int wid  = (blockIdx.x << 2) + wv;
    int lane = threadIdx.x & 63;
    if (wid >= N) return;
    int base = offs[wid];
    int deg  = offs[wid+1] - base;
    float4 adv = ad1v[wid];
    const int comp = lane >> 4;
    float acc0=0.f, acc1=0.f;

    if (deg <= 64){
        const bool act = lane < deg;
        int sreg = 0;
        float e0=0.f,e1=0.f,e2=0.f,e3=0.f;
        if (act){
            sreg = bsrc[base+lane];
            float4 av = as1v[sreg];
            e0=cexp(lrelu(av.x+adv.x)); e1=cexp(lrelu(av.y+adv.y));
            e2=cexp(lrelu(av.z+adv.z)); e3=cexp(lrelu(av.w+adv.w));
        }
        float s0=e0,s1=e1,s2=e2,s3=e3;
        #pragma unroll
        for (int d=32; d>=1; d>>=1){
            s0+=__shfl_xor(s0,d); s1+=__shfl_xor(s1,d);
            s2+=__shfl_xor(s2,d); s3+=__shfl_xor(s3,d);
        }
        if (act){
            ssh[wv][lane]    = sreg << 6;
            wsh[wv][lane][0] = e0/s0;
            wsh[wv][lane][1] = e1/s1;
            wsh[wv][lane][2] = e2/s2;
            wsh[wv][lane][3] = e3/s3;
        }
        int j=0;
        for (; j+3 < deg; j+=4){
            uint oA=ssh[wv][j]+lane,   oB=ssh[wv][j+1]+lane;
            uint oC=ssh[wv][j+2]+lane, oD=ssh[wv][j+3]+lane;
            float wA=wsh[wv][j][comp],   wB=wsh[wv][j+1][comp];
            float wC=wsh[wv][j+2][comp], wD=wsh[wv][j+3][comp];
            uint hA=hb2[oA], hB=hb2[oB], hC=hb2[oC], hD=hb2[oD];
            acc0 = fmaf(bf_lo(hA), wA, acc0); acc1 = fmaf(bf_hi(hA), wA, acc1);
            acc0 = fmaf(bf_lo(hB), wB, acc0); acc1 = fmaf(bf_hi(hB), wB, acc1);
            acc0 = fmaf(bf_lo(hC), wC, acc0); acc1 = fmaf(bf_hi(hC), wC, acc1);
            acc0 = fmaf(bf_lo(hD), wD, acc0); acc1 = fmaf(bf_hi(hD), wD, acc1);
        }
        for (; j < deg; j++){
            uint oA = ssh[wv][j]+lane;
            float wA = wsh[wv][j][comp];
            uint hA = hb2[oA];
            acc0 = fmaf(bf_lo(hA), wA, acc0);
            acc1 = fmaf(bf_hi(hA), wA, acc1);
        }
    } else {
        // fallback (deg > 64): 2-pass, max-free
        float s0=0,s1=0,s2=0,s3=0;
        for (int j=lane; j<deg; j+=64){
            int s = bsrc[base+j];
            float4 av = as1v[s];
            float e0=cexp(lrelu(av.x+adv.x));
            float e1=cexp(lrelu(av.y+adv.y));
            float e2=cexp(lrelu(av.z+adv.z));
            float e3=cexp(lrelu(av.w+adv.w));
            s0+=e0; s1+=e1; s2+=e2; s3+=e3;
            *(float4*)&exb[(size_t)(base+j)*4] = make_float4(e0,e1,e2,e3);
        }
        #pragma unroll
        for (int d=32; d>=1; d>>=1){
            s0+=__shfl_xor(s0,d); s1+=__shfl_xor(s1,d);
            s2+=__shfl_xor(s2,d); s3+=__shfl_xor(s3,d);
        }
        float invc = 1.0f / sel4(s0,s1,s2,s3,comp);
        for (int j=0;j<deg;j++){
            int s = bsrc[base+j];
            float w = exb[(size_t)(base+j)*4 + comp]*invc;
            uint hv = hb2[((uint)s<<6)+lane];
            acc0 = fmaf(bf_lo(hv), w, acc0);
            acc1 = fmaf(bf_hi(hv), w, acc1);
        }
    }
    float2 bv = *(const float2*)&b1[2*lane];
    float r0 = acc0 + bv.x;
    float r1 = acc1 + bv.y;
    r0 = r0 > 0.f ? r0 : (__expf(r0) - 1.f);
    r1 = r1 > 0.f ? r1 : (__expf(r1) - 1.f);
    *(float2*)&h1[(size_t)wid*128 + 2*lane] = make_float2(r0, r1);
}

// ---------------- GEMM2 (h2 = h1 @ W2, bf16-packed out) + alpha2 ----------------
__global__ __launch_bounds__(256) void k_l2pre(const float* __restrict__ h1,
    const float* __restrict__ W2, const float* __restrict__ asrc2,
    const float* __restrict__ adst2, uint* __restrict__ h2b,
    float* __restrict__ as2, float* __restrict__ ad2, int N)
{
    __shared__ __align__(16) float w2s[4096];
    __shared__ float a2s[32], a2d[32];
    int tid = threadIdx.x;
    #pragma unroll
    for (int q=0;q<4;q++){
        int idx = q*1024 + tid*4;
        *(float4*)&w2s[idx] = *(const float4*)&W2[idx];
    }
    if (tid < 32){ a2s[tid] = asrc2[tid]; a2d[tid] = adst2[tid]; }
    __syncthreads();
    int node = blockIdx.x*8 + (tid>>5);
    if (node >= N) return;
    int c = tid & 31;
    float acc = 0.f;
    #pragma unroll 8
    for (int k=0;k<128;k+=4){
        float4 hv = *(const float4*)&h1[(size_t)node*128 + k];
        acc = fmaf(hv.x, w2s[(k+0)*32+c], acc);
        acc = fmaf(hv.y, w2s[(k+1)*32+c], acc);
        acc = fmaf(hv.z, w2s[(k+2)*32+c], acc);
        acc = fmaf(hv.w, w2s[(k+3)*32+c], acc);
    }
    float pr = __shfl_xor(acc, 1);
    if ((c & 1) == 0)
        h2b[(size_t)node*16 + (c>>1)] = f2bf(acc) | (f2bf(pr)<<16);
    float ps = acc * a2s[c], pd = acc * a2d[c];
    #pragma unroll
    for (int d=16; d>=1; d>>=1){ ps += __shfl_xor(ps,d); pd += __shfl_xor(pd,d); }
    if (c == 0){ as2[node] = ps; ad2[node] = pd; }
}

// ---------------- layer-2 softmax (max-free) + aggregate + bias -> output ----------------
__global__ __launch_bounds__(256) void k_agg2(const uint* __restrict__ h2b,
    const float* __restrict__ as2, const float* __restrict__ ad2,
    const int* __restrict__ offs, const int* __restrict__ bsrc,
    const float* __restrict__ b2, float* __restrict__ exb,
    float* __restrict__ outp, int N)
{
    __shared__ float w2sh[4][64];
    __shared__ int   s2sh[4][64];     // src<<4
    int wv   = threadIdx.x >> 6;
    int wid  = (blockIdx.x << 2) + wv;
    int lane = threadIdx.x & 63;
    if (wid >= N) return;
    int base = offs[wid], deg = offs[wid+1] - base;
    float adn = ad2[wid];
    const int c2 = lane & 15, slot = lane >> 4;
    float acc0 = 0.f, acc1 = 0.f;

    if (deg <= 64){
        const bool act = lane < deg;
        int sreg = 0; float e = 0.f;
        if (act){ sreg = bsrc[base+lane]; e = cexp(lrelu(as2[sreg] + adn)); }
        float sum = e;
        #pragma unroll
        for (int d=32; d>=1; d>>=1) sum += __shfl_xor(sum,d);
        if (act){ s2sh[wv][lane] = sreg << 4; w2sh[wv][lane] = e/sum; }
        for (int j=slot; j<deg; j+=4){
            uint o  = (uint)(s2sh[wv][j] + c2);
            float w = w2sh[wv][j];
            uint u = h2b[o];
            acc0 = fmaf(bf_lo(u), w, acc0);
            acc1 = fmaf(bf_hi(u), w, acc1);
        }
    } else {
        float sum = 0.f;
        for (int j=lane; j<deg; j+=64){
            int s = bsrc[base+j];
            float ex = cexp(lrelu(as2[s] + adn));
            sum += ex;
            exb[base+j] = ex;
        }
        #pragma unroll
        for (int d=32; d>=1; d>>=1) sum += __shfl_xor(sum,d);
        float inv = 1.f/sum;
        for (int j=slot; j<deg; j+=4){
            int s  = bsrc[base+j];
            float w = exb[base+j]*inv;
            uint u = h2b[((uint)s<<4) + c2];
            acc0 = fmaf(bf_lo(u), w, acc0);
            acc1 = fmaf(bf_hi(u), w, acc1);
        }
    }
    acc0 += __shfl_xor(acc0, 16); acc0 += __shfl_xor(acc0, 32);
    acc1 += __shfl_xor(acc1, 16); acc1 += __shfl_xor(acc1, 32);
    if (lane < 16){
        float2 bv = *(const float2*)&b2[2*c2];
        *(float2*)&outp[(size_t)wid*32 + 2*c2] = make_float2(acc0 + bv.x, acc1 + bv.y);
    }
}

extern "C" void kernel_launch(void* const* d_in, const int* in_sizes, int n_in,
                              void* d_out, int out_size, void* d_ws, size_t ws_size,
                              hipStream_t stream)
{
    const float* x     = (const float*)d_in[0];
    const int*   ei    = (const int*)d_in[1];
    const float* W1    = (const float*)d_in[2];
    const float* at_s1 = (const float*)d_in[3];
    const float* at_d1 = (const float*)d_in[4];
    const float* b1    = (const float*)d_in[5];
    const float* W2    = (const float*)d_in[6];
    const float* at_s2 = (const float*)d_in[7];
    const float* at_d2 = (const float*)d_in[8];
    const float* b2    = (const float*)d_in[9];
    float* outp = (float*)d_out;

    const int N = in_sizes[0] / 128;
    const int E = in_sizes[1] / 2;
    const int Etot = E + N;

    const int NB = (N + 255) >> 8;             // dst buckets (dst>>8)
    const int NC = (Etot + 4095) / 4096;       // edge chunks
    const int T  = NB * NC;
    const int L1 = (T + 255) / 256;

    float* f = (float*)d_ws;
    size_t off = 0;
    uint*  hb2 = (uint*)(f + off); off += (size_t)N*64;
    float* h1  = f + off; off += (size_t)N*128;
    float* exb = f + off; off += (size_t)Etot*4;
    float* as1 = f + off; off += (size_t)N*4;
    float* ad1 = f + off; off += (size_t)N*4;
    uint*  h2b = (uint*)(f + off); off += (size_t)N*16;
    float* as2 = f + off; off += (size_t)N;
    float* ad2 = f + off; off += (size_t)N;
    ushort* wtb = (ushort*)(f + off); off += 8192;
    int* ib       = (int*)(f + off);
    int* offs     = ib;                        // N+1 (+pad)
    int* bh       = ib + N + 8;                // T
    int* bhs      = bh + T;                    // T
    int* partials2= bhs + T;                   // 256
    uint* epack   = (uint*)(partials2 + 256);  // Etot
    int* bsrc     = (int*)(epack + Etot);      // Etot

    const int GB = (N+63)/64;
    const int AB = (N+3)/4;

    k_prep <<<16, 256, 0, stream>>>(W1, wtb);
    k_g1b  <<<GB+NC, 512, 0, stream>>>(x, wtb, hb2, N, GB, ei, bh, E, Etot, NC, NB);
    k_a1sc <<<AB+L1, 256, 0, stream>>>(hb2, at_s1, at_d1, as1, ad1, N, AB,
                                       bh, bhs, partials2, T);
    if (L1 <= 256){
        k_bscan23<<<L1, 256, 0, stream>>>(bhs, partials2, L1, T);
    } else {
        k_bscan2s<<<1, 1, 0, stream>>>(bhs, bh, T);
    }
    k_bscat<<<NC, 256, 0, stream>>>(ei, bhs, epack, E, Etot, NC);
    k_bfin <<<NB, 256, 0, stream>>>(epack, bhs, bsrc, offs, N, NB, NC, Etot);
    k_agg1 <<<(N+3)/4, 256, 0, stream>>>(hb2, (const float4*)as1, (const float4*)ad1,
                                         offs, bsrc, b1, exb, h1, N);
    k_l2pre<<<(N+7)/8, 256, 0, stream>>>(h1, W2, at_s2, at_d2, h2b, as2, ad2, N);
    k_agg2 <<<(N+3)/4, 256, 0, stream>>>(h2b, as2, ad2, offs, bsrc, b2, exb, outp, N);
}

// Round 11
// 146.094 us; speedup vs baseline: 2.3953x; 1.1096x over previous
//
#include <hip/hip_runtime.h>
#include <math.h>

#define NEG_SLOPE 0.2f
typedef unsigned int uint;
typedef __attribute__((ext_vector_type(8))) short short8;
typedef __attribute__((ext_vector_type(4))) float floatx4;

__device__ __forceinline__ float lrelu(float x){ return x > 0.f ? x : NEG_SLOPE*x; }
__device__ __forceinline__ float sel4(float a,float b,float c,float d,int comp){
    return comp==0 ? a : (comp==1 ? b : (comp==2 ? c : d));
}
__device__ __forceinline__ uint f2bf(float f){
    uint u = __float_as_uint(f);
    return (u + 0x7FFFu + ((u>>16)&1u)) >> 16;
}
__device__ __forceinline__ float bf_lo(uint u){ return __uint_as_float(u<<16); }
__device__ __forceinline__ float bf_hi(uint u){ return __uint_as_float(u & 0xFFFF0000u); }
__device__ __forceinline__ float cexp(float x){ return __expf(fminf(x, 60.f)); }

// ---------------- prep: W1^T -> bf16 (16 blocks) + offs[N]=Etot ----------------
__global__ __launch_bounds__(256) void k_prep(const float* __restrict__ W,
                                              ushort* __restrict__ wtb,
                                              int* __restrict__ offs, int N, int Etot)
{
    if (blockIdx.x == 0 && threadIdx.x == 0) offs[N] = Etot;
    int flat = blockIdx.x*1024 + threadIdx.x*4;
    int k = flat >> 7, c = flat & 127;
    float4 wv = *(const float4*)&W[flat];
    wtb[(size_t)(c+0)*128 + k] = (ushort)f2bf(wv.x);
    wtb[(size_t)(c+1)*128 + k] = (ushort)f2bf(wv.y);
    wtb[(size_t)(c+2)*128 + k] = (ushort)f2bf(wv.z);
    wtb[(size_t)(c+3)*128 + k] = (ushort)f2bf(wv.w);
}

// ---------------- MERGED: MFMA GEMM1 (blocks < GB, 8 waves) + bucket histogram ----------------
__global__ __launch_bounds__(512) void k_g1b(const float* __restrict__ x,
    const ushort* __restrict__ wtb, uint* __restrict__ hb2, int N, int GB,
    const int* __restrict__ ei, int* __restrict__ bh, int E, int Etot, int NC, int NB)
{
    if (blockIdx.x >= GB){
        __shared__ uint hist[256];
        int c = blockIdx.x - GB;
        if (threadIdx.x < 256) hist[threadIdx.x] = 0;
        __syncthreads();
        int e0 = c*4096;
        #pragma unroll
        for (int r=0;r<8;r++){
            int e = e0 + r*512 + threadIdx.x;
            if (e < Etot){
                int d = (e < E) ? ei[E+e] : (e-E);
                atomicAdd(&hist[d>>8], 1u);
            }
        }
        __syncthreads();
        int b = threadIdx.x;
        if (b < NB) bh[(size_t)b*NC + c] = (int)hist[b];
        return;
    }
    __shared__ __align__(16) ushort xt[64][136];
    const int tid = threadIdx.x;
    const int row0 = blockIdx.x * 64;
    #pragma unroll
    for (int j=0;j<4;j++){
        int flat = j*2048 + tid*4;
        int r = flat >> 7, c = flat & 127;
        int gr = row0 + r;
        float4 xv = (gr < N) ? *(const float4*)&x[(size_t)gr*128 + c]
                             : make_float4(0.f,0.f,0.f,0.f);
        uint2 p;
        p.x = f2bf(xv.x) | (f2bf(xv.y)<<16);
        p.y = f2bf(xv.z) | (f2bf(xv.w)<<16);
        *(uint2*)&xt[r][c] = p;
    }
    __syncthreads();
    const int wv_ = tid >> 6, lane = tid & 63;
    const int l15 = lane & 15, hi = lane >> 4;
    const int rw = wv_ & 3, ch = wv_ >> 2;
    const int arow = rw*16 + l15;
    floatx4 acc[4];
    #pragma unroll
    for (int t=0;t<4;t++) acc[t] = (floatx4){0.f,0.f,0.f,0.f};
    #pragma unroll
    for (int ks=0; ks<4; ks++){
        short8 a = *(short8*)&xt[arow][ks*32 + hi*8];
        #pragma unroll
        for (int c4=0; c4<4; c4++){
            int ct = ch*4 + c4;
            short8 b = *(const short8*)&wtb[(size_t)(ct*16 + l15)*128 + ks*32 + hi*8];
            acc[c4] = __builtin_amdgcn_mfma_f32_16x16x32_bf16(a, b, acc[c4], 0, 0, 0);
        }
    }
    #pragma unroll
    for (int c4=0; c4<4; c4++){
        int ct = ch*4 + c4;
        #pragma unroll
        for (int r=0;r<4;r++){
            float v  = acc[c4][r];
            float pr = __shfl_xor(v, 1);
            int gr = row0 + rw*16 + (hi<<2) + r;
            if (((lane & 1) == 0) && gr < N)
                hb2[(size_t)gr*64 + ct*8 + (l15>>1)] = f2bf(v) | (f2bf(pr)<<16);
        }
    }
}

// ---------------- MERGED: alpha1 (blocks < AB) + bucket-scan level1 ----------------
__global__ __launch_bounds__(256) void k_a1sc(const uint* __restrict__ hb2,
        const float* __restrict__ at_s, const float* __restrict__ at_d,
        float* __restrict__ as1, float* __restrict__ ad1, int N, int AB,
        const int* __restrict__ bh, int* __restrict__ bhs, int* __restrict__ partials2, int T)
{
    __shared__ int sm[256];
    if (blockIdx.x >= AB){
        int bid = blockIdx.x - AB;
        int tid = threadIdx.x;
        int i = bid*256 + tid;
        int v = (i < T) ? bh[i] : 0;
        sm[tid] = v;
        __syncthreads();
        for (int d=1; d<256; d<<=1){
            int t = (tid >= d) ? sm[tid-d] : 0;
            __syncthreads();
            sm[tid] += t;
            __syncthreads();
        }
        if (i < T) bhs[i] = sm[tid] - v;
        if (tid == 255) partials2[bid] = sm[255];
        return;
    }
    int wid = (blockIdx.x << 2) + (threadIdx.x >> 6);
    int lane = threadIdx.x & 63;
    if (wid >= N) return;
    uint hv = hb2[(size_t)wid*64 + lane];
    float f0 = bf_lo(hv), f1 = bf_hi(hv);
    float2 asv = *(const float2*)&at_s[2*lane];
    float2 adv = *(const float2*)&at_d[2*lane];
    float sa = f0*asv.x + f1*asv.y;
    float da = f0*adv.x + f1*adv.y;
    #pragma unroll
    for (int d=8; d>=1; d>>=1){ sa += __shfl_xor(sa,d); da += __shfl_xor(da,d); }
    if ((lane & 15) == 0){
        int head = lane >> 4;
        as1[(size_t)wid*4 + head] = sa;
        ad1[(size_t)wid*4 + head] = da;
    }
}

// serial level-2 fallback (only if L1 > 256; produces FINAL bhs)
__global__ void k_bscan2s(int* __restrict__ bhs, const int* __restrict__ bh, int T){
    if (threadIdx.x == 0){
        int run = 0;
        for (int i=0;i<T;i++){ bhs[i] = run; run += bh[i]; }
    }
}

// ---------------- scatter edges to bucket-major order (inline level-2 scan) ----------------
__global__ __launch_bounds__(256) void k_bscat(const int* __restrict__ ei,
        const int* __restrict__ bhs, const int* __restrict__ partials2, int L1e,
        uint* __restrict__ epack, int E, int Etot, int NC, int NB)
{
    __shared__ int sm[256];
    __shared__ int pbase[256];
    __shared__ uint cnt[256];
    int c = blockIdx.x, tid = threadIdx.x;
    int v = (tid < L1e) ? partials2[tid] : 0;
    sm[tid] = v;
    __syncthreads();
    for (int d=1; d<256; d<<=1){
        int t = (tid >= d) ? sm[tid-d] : 0;
        __syncthreads();
        sm[tid] += t;
        __syncthreads();
    }
    if (tid < NB){
        int i = tid*NC + c;
        int boff = (L1e == 0 || (i>>8) == 0) ? 0 : sm[(i>>8)-1];
        pbase[tid] = bhs[i] + boff;
    }
    cnt[tid] = 0;
    __syncthreads();
    int e0 = c*4096;
    #pragma unroll
    for (int r=0;r<16;r++){
        int e = e0 + r*256 + tid;
        if (e < Etot){
            int d, s;
            if (e < E){ s = ei[e]; d = ei[E+e]; }
            else      { s = e - E; d = e - E; }
            int b = d >> 8;
            uint lr = atomicAdd(&cnt[b], 1u);
            epack[pbase[b] + (int)lr] = (uint)s | ((uint)(d & 255) << 16);
        }
    }
}

// ---------------- finalize: per-bucket node offsets + bsrc (inline level-2 scan) ----------------
__global__ __launch_bounds__(256) void k_bfin(const uint* __restrict__ epack,
        const int* __restrict__ bhs, const int* __restrict__ partials2, int L1e,
        int* __restrict__ bsrc, int* __restrict__ offs, int N, int NB, int NC, int Etot)
{
    __shared__ int sm[256];
    __shared__ int cnt[256], lofs[256], cnt2[256];
    int b = blockIdx.x, tid = threadIdx.x;
    int v = (tid < L1e) ? partials2[tid] : 0;
    sm[tid] = v;
    __syncthreads();
    for (int d=1; d<256; d<<=1){
        int t = (tid >= d) ? sm[tid-d] : 0;
        __syncthreads();
        sm[tid] += t;
        __syncthreads();
    }
    int i0 = b*NC;
    int start = bhs[i0] + ((L1e==0 || (i0>>8)==0) ? 0 : sm[(i0>>8)-1]);
    int end;
    if (b+1 < NB){
        int i1 = (b+1)*NC;
        end = bhs[i1] + ((L1e==0 || (i1>>8)==0) ? 0 : sm[(i1>>8)-1]);
    } else end = Etot;
    __syncthreads();
    cnt[tid] = 0; cnt2[tid] = 0;
    __syncthreads();
    for (int e = start + tid; e < end; e += 256)
        atomicAdd((uint*)&cnt[(epack[e] >> 16) & 255], 1u);
    __syncthreads();
    int v2 = cnt[tid];
    sm[tid] = v2;
    __syncthreads();
    for (int d=1; d<256; d<<=1){
        int t = (tid >= d) ? sm[tid-d] : 0;
        __syncthreads();
        sm[tid] += t;
        __syncthreads();
    }
    lofs[tid] = sm[tid] - v2;
    int nd = b*256 + tid;
    if (nd <= N) offs[nd] = start + sm[tid] - v2;
    __syncthreads();
    for (int e = start + tid; e < end; e += 256){
        uint u = epack[e];
        int dl = (u >> 16) & 255;
        int r = (int)atomicAdd((uint*)&cnt2[dl], 1u);
        bsrc[start + lofs[dl] + r] = (int)(u & 0xFFFFu);
    }
}

// ---------------- layer-1 softmax (max-free) + aggregate + bias + ELU -> bf16 h1 ----------------
__global__ __launch_bounds__(256) void k_agg1(const uint* __restrict__ hb2,
    const float4* __restrict__ as1v, const float4* __restrict__ ad1v,
    const int* __restrict__ offs, const int* __restrict__ bsrc,
    const float* __restrict__ b1, float* __restrict__ exb,
    uint* __restrict__ hb1, int N)
{
    __shared__ float wsh[4][64][4];   // [wave][edge][head]
    __shared__ int   ssh[4][64];      // [wave][edge] src<<6
    int wv   = threadIdx.x >> 6;
    int wid  = (blockIdx.x << 2) + wv;
    int lane = threadIdx.x & 63;
    if (wid >= N) return;
    int base = offs[wid];
    int deg  = offs[wid+1] - base;
    float4 adv = ad1v[wid];
    const int comp = lane >> 4;
    float acc0=0.f, acc1=0.f;

    if (deg <= 64){
        const bool act = lane < deg;
        int sreg = 0;
        float e0=0.f,e1=0.f,e2=0.f,e3=0.f;
        if (act){
            sreg = bsrc[base+lane];
            float4 av = as1v[sreg];
            e0=cexp(lrelu(av.x+adv.x)); e1=cexp(lrelu(av.y+adv.y));
            e2=cexp(lrelu(av.z+adv.z)); e3=cexp(lrelu(av.w+adv.w));
        }
        float s0=e0,s1=e1,s2=e2,s3=e3;
        #pragma unroll
        for (int d=32; d>=1; d>>=1){
            s0+=__shfl_xor(s0,d); s1+=__shfl_xor(s1,d);
            s2+=__shfl_xor(s2,d); s3+=__shfl_xor(s3,d);
        }
        if (act){
            ssh[wv][lane]    = sreg << 6;
            wsh[wv][lane][0] = e0/s0;
            wsh[wv][lane][1] = e1/s1;
            wsh[wv][lane][2] = e2/s2;
            wsh[wv][lane][3] = e3/s3;
        }
        int j=0;
        for (; j+7 < deg; j+=8){
            uint o0=ssh[wv][j+0]+lane, o1=ssh[wv][j+1]+lane;
            uint o2=ssh[wv][j+2]+lane, o3=ssh[wv][j+3]+lane;
            uint o4=ssh[wv][j+4]+lane, o5=ssh[wv][j+5]+lane;
            uint o6=ssh[wv][j+6]+lane, o7=ssh[wv][j+7]+lane;
            float w0=wsh[wv][j+0][comp], w1=wsh[wv][j+1][comp];
            float w2=wsh[wv][j+2][comp], w3=wsh[wv][j+3][comp];
            float w4=wsh[wv][j+4][comp], w5=wsh[wv][j+5][comp];
            float w6=wsh[wv][j+6][comp], w7=wsh[wv][j+7][comp];
            uint h0=hb2[o0], h1_=hb2[o1], h2_=hb2[o2], h3=hb2[o3];
            uint h4=hb2[o4], h5=hb2[o5], h6=hb2[o6], h7=hb2[o7];
            acc0 = fmaf(bf_lo(h0), w0, acc0); acc1 = fmaf(bf_hi(h0), w0, acc1);
            acc0 = fmaf(bf_lo(h1_),w1, acc0); acc1 = fmaf(bf_hi(h1_),w1, acc1);
            acc0 = fmaf(bf_lo(h2_),w2, acc0); acc1 = fmaf(bf_hi(h2_),w2, acc1);
            acc0 = fmaf(bf_lo(h3), w3, acc0); acc1 = fmaf(bf_hi(h3), w3, acc1);
            acc0 = fmaf(bf_lo(h4), w4, acc0); acc1 = fmaf(bf_hi(h4), w4, acc1);
            acc0 = fmaf(bf_lo(h5), w5, acc0); acc1 = fmaf(bf_hi(h5), w5, acc1);
            acc0 = fmaf(bf_lo(h6), w6, acc0); acc1 = fmaf(bf_hi(h6), w6, acc1);
            acc0 = fmaf(bf_lo(h7), w7, acc0); acc1 = fmaf(bf_hi(h7), w7, acc1);
        }
        for (; j+3 < deg; j+=4){
            uint oA=ssh[wv][j]+lane,   oB=ssh[wv][j+1]+lane;
            uint oC=ssh[wv][j+2]+lane, oD=ssh[wv][j+3]+lane;
            float wA=wsh[wv][j][comp],   wB=wsh[wv][j+1][comp];
            float wC=wsh[wv][j+2][comp], wD=wsh[wv][j+3][comp];
            uint hA=hb2[oA], hB=hb2[oB], hC=hb2[oC], hD=hb2[oD];
            acc0 = fmaf(bf_lo(hA), wA, acc0); acc1 = fmaf(bf_hi(hA), wA, acc1);
            acc0 = fmaf(bf_lo(hB), wB, acc0); acc1 = fmaf(bf_hi(hB), wB, acc1);
            acc0 = fmaf(bf_lo(hC), wC, acc0); acc1 = fmaf(bf_hi(hC), wC, acc1);
            acc0 = fmaf(bf_lo(hD), wD, acc0); acc1 = fmaf(bf_hi(hD), wD, acc1);
        }
        for (; j < deg; j++){
            uint oA = ssh[wv][j]+lane;
            float wA = wsh[wv][j][comp];
            uint hA = hb2[oA];
            acc0 = fmaf(bf_lo(hA), wA, acc0);
            acc1 = fmaf(bf_hi(hA), wA, acc1);
        }
    } else {
        float s0=0,s1=0,s2=0,s3=0;
        for (int j=lane; j<deg; j+=64){
            int s = bsrc[base+j];
            float4 av = as1v[s];
            float e0=cexp(lrelu(av.x+adv.x));
            float e1=cexp(lrelu(av.y+adv.y));
            float e2=cexp(lrelu(av.z+adv.z));
            float e3=cexp(lrelu(av.w+adv.w));
            s0+=e0; s1+=e1; s2+=e2; s3+=e3;
            *(float4*)&exb[(size_t)(base+j)*4] = make_float4(e0,e1,e2,e3);
        }
        #pragma unroll
        for (int d=32; d>=1; d>>=1){
            s0+=__shfl_xor(s0,d); s1+=__shfl_xor(s1,d);
            s2+=__shfl_xor(s2,d); s3+=__shfl_xor(s3,d);
        }
        float invc = 1.0f / sel4(s0,s1,s2,s3,comp);
        for (int j=0;j<deg;j++){
            int s = bsrc[base+j];
            float w = exb[(size_t)(base+j)*4 + comp]*invc;
            uint hv = hb2[((uint)s<<6)+lane];
            acc0 = fmaf(bf_lo(hv), w, acc0);
            acc1 = fmaf(bf_hi(hv), w, acc1);
        }
    }
    float2 bv = *(const float2*)&b1[2*lane];
    float r0 = acc0 + bv.x;
    float r1 = acc1 + bv.y;
    r0 = r0 > 0.f ? r0 : (__expf(r0) - 1.f);
    r1 = r1 > 0.f ? r1 : (__expf(r1) - 1.f);
    hb1[(size_t)wid*64 + lane] = f2bf(r0) | (f2bf(r1)<<16);
}

// ---------------- GEMM2 (h2 = bf16(h1) @ W2, bf16-packed out) + alpha2 ----------------
__global__ __launch_bounds__(256) void k_l2pre(const uint* __restrict__ hb1,
    const float* __restrict__ W2, const float* __restrict__ asrc2,
    const float* __restrict__ adst2, uint* __restrict__ h2b,
    float* __restrict__ as2, float* __restrict__ ad2, int N)
{
    __shared__ __align__(16) float w2s[4096];
    __shared__ float a2s[32], a2d[32];
    int tid = threadIdx.x;
    #pragma unroll
    for (int q=0;q<4;q++){
        int idx = q*1024 + tid*4;
        *(float4*)&w2s[idx] = *(const float4*)&W2[idx];
    }
    if (tid < 32){ a2s[tid] = asrc2[tid]; a2d[tid] = adst2[tid]; }
    __syncthreads();
    int node = blockIdx.x*8 + (tid>>5);
    if (node >= N) return;
    int c = tid & 31;
    float acc = 0.f;
    #pragma unroll
    for (int k=0;k<128;k+=8){
        uint4 u = *(const uint4*)&hb1[(size_t)node*64 + (k>>1)];
        acc = fmaf(bf_lo(u.x), w2s[(k+0)*32+c], acc);
        acc = fmaf(bf_hi(u.x), w2s[(k+1)*32+c], acc);
        acc = fmaf(bf_lo(u.y), w2s[(k+2)*32+c], acc);
        acc = fmaf(bf_hi(u.y), w2s[(k+3)*32+c], acc);
        acc = fmaf(bf_lo(u.z), w2s[(k+4)*32+c], acc);
        acc = fmaf(bf_hi(u.z), w2s[(k+5)*32+c], acc);
        acc = fmaf(bf_lo(u.w), w2s[(k+6)*32+c], acc);
        acc = fmaf(bf_hi(u.w), w2s[(k+7)*32+c], acc);
    }
    float pr = __shfl_xor(acc, 1);
    if ((c & 1) == 0)
        h2b[(size_t)node*16 + (c>>1)] = f2bf(acc) | (f2bf(pr)<<16);
    float ps = acc * a2s[c], pd = acc * a2d[c];
    #pragma unroll
    for (int d=16; d>=1; d>>=1){ ps += __shfl_xor(ps,d); pd += __shfl_xor(pd,d); }
    if (c == 0){ as2[node] = ps; ad2[node] = pd; }
}

// ---------------- layer-2 softmax (max-free) + aggregate + bias -> output ----------------
__global__ __launch_bounds__(256) void k_agg2(const uint* __restrict__ h2b,
    const float* __restrict__ as2, const float* __restrict__ ad2,
    const int* __restrict__ offs, const int* __restrict__ bsrc,
    const float* __restrict__ b2, float* __restrict__ exb,
    float* __restrict__ outp, int N)
{
    __shared__ float w2sh[4][64];
    __shared__ int   s2sh[4][64];     // src<<4
    int wv   = threadIdx.x >> 6;
    int wid  = (blockIdx.x << 2) + wv;
    int lane = threadIdx.x & 63;
    if (wid >= N) return;
    int base = offs[wid], deg = offs[wid+1] - base;
    float adn = ad2[wid];
    const int c2 = lane & 15, slot = lane >> 4;
    float acc0 = 0.f, acc1 = 0.f;

    if (deg <= 64){
        const bool act = lane < deg;
        int sreg = 0; float e = 0.f;
        if (act){ sreg = bsrc[base+lane]; e = cexp(lrelu(as2[sreg] + adn)); }
        float sum = e;
        #pragma unroll
        for (int d=32; d>=1; d>>=1) sum += __shfl_xor(sum,d);
        if (act){ s2sh[wv][lane] = sreg << 4; w2sh[wv][lane] = e/sum; }
        for (int j=slot; j<deg; j+=4){
            uint o  = (uint)(s2sh[wv][j] + c2);
            float w = w2sh[wv][j];
            uint u = h2b[o];
            acc0 = fmaf(bf_lo(u), w, acc0);
            acc1 = fmaf(bf_hi(u), w, acc1);
        }
    } else {
        float sum = 0.f;
        for (int j=lane; j<deg; j+=64){
            int s = bsrc[base+j];
            float ex = cexp(lrelu(as2[s] + adn));
            sum += ex;
            exb[base+j] = ex;
        }
        #pragma unroll
        for (int d=32; d>=1; d>>=1) sum += __shfl_xor(sum,d);
        float inv = 1.f/sum;
        for (int j=slot; j<deg; j+=4){
            int s  = bsrc[base+j];
            float w = exb[base+j]*inv;
            uint u = h2b[((uint)s<<4) + c2];
            acc0 = fmaf(bf_lo(u), w, acc0);
            acc1 = fmaf(bf_hi(u), w, acc1);
        }
    }
    acc0 += __shfl_xor(acc0, 16); acc0 += __shfl_xor(acc0, 32);
    acc1 += __shfl_xor(acc1, 16); acc1 += __shfl_xor(acc1, 32);
    if (lane < 16){
        float2 bv = *(const float2*)&b2[2*c2];
        *(float2*)&outp[(size_t)wid*32 + 2*c2] = make_float2(acc0 + bv.x, acc1 + bv.y);
    }
}

extern "C" void kernel_launch(void* const* d_in, const int* in_sizes, int n_in,
                              void* d_out, int out_size, void* d_ws, size_t ws_size,
                              hipStream_t stream)
{
    const float* x     = (const float*)d_in[0];
    const int*   ei    = (const int*)d_in[1];
    const float* W1    = (const float*)d_in[2];
    const float* at_s1 = (const float*)d_in[3];
    const float* at_d1 = (const float*)d_in[4];
    const float* b1    = (const float*)d_in[5];
    const float* W2    = (const float*)d_in[6];
    const float* at_s2 = (const float*)d_in[7];
    const float* at_d2 = (const float*)d_in[8];
    const float* b2    = (const float*)d_in[9];
    float* outp = (float*)d_out;

    const int N = in_sizes[0] / 128;
    const int E = in_sizes[1] / 2;
    const int Etot = E + N;

    const int NB = (N + 255) >> 8;             // dst buckets (dst>>8)
    const int NC = (Etot + 4095) / 4096;       // edge chunks
    const int T  = NB * NC;
    const int L1 = (T + 255) / 256;

    float* f = (float*)d_ws;
    size_t off = 0;
    uint*  hb2 = (uint*)(f + off); off += (size_t)N*64;   // bf16 h  [N][64]
    uint*  hb1 = (uint*)(f + off); off += (size_t)N*64;   // bf16 h1 [N][64]
    float* exb = f + off; off += (size_t)Etot*4;
    float* as1 = f + off; off += (size_t)N*4;
    float* ad1 = f + off; off += (size_t)N*4;
    uint*  h2b = (uint*)(f + off); off += (size_t)N*16;   // bf16 h2 [N][16]
    float* as2 = f + off; off += (size_t)N;
    float* ad2 = f + off; off += (size_t)N;
    ushort* wtb = (ushort*)(f + off); off += 8192;        // W1^T bf16 (32KB)
    int* ib       = (int*)(f + off);
    int* offs     = ib;                        // N+1 (+pad)
    int* bh       = ib + N + 8;                // T
    int* bhs      = bh + T;                    // T
    int* partials2= bhs + T;                   // 256
    uint* epack   = (uint*)(partials2 + 256);  // Etot
    int* bsrc     = (int*)(epack + Etot);      // Etot

    const int GB = (N+63)/64;
    const int AB = (N+3)/4;

    k_prep <<<16, 256, 0, stream>>>(W1, wtb, offs, N, Etot);
    k_g1b  <<<GB+NC, 512, 0, stream>>>(x, wtb, hb2, N, GB, ei, bh, E, Etot, NC, NB);
    k_a1sc <<<AB+L1, 256, 0, stream>>>(hb2, at_s1, at_d1, as1, ad1, N, AB,
                                       bh, bhs, partials2, T);
    if (L1 <= 256){
        k_bscat<<<NC, 256, 0, stream>>>(ei, bhs, partials2, L1, epack, E, Etot, NC, NB);
        k_bfin <<<NB, 256, 0, stream>>>(epack, bhs, partials2, L1, bsrc, offs, N, NB, NC, Etot);
    } else {
        k_bscan2s<<<1, 1, 0, stream>>>(bhs, bh, T);
        k_bscat<<<NC, 256, 0, stream>>>(ei, bhs, partials2, 0, epack, E, Etot, NC, NB);
        k_bfin <<<NB, 256, 0, stream>>>(epack, bhs, partials2, 0, bsrc, offs, N, NB, NC, Etot);
    }
    k_agg1 <<<(N+3)/4, 256, 0, stream>>>(hb2, (const float4*)as1, (const float4*)ad1,
                                         offs, bsrc, b1, exb, hb1, N);
    k_l2pre<<<(N+7)/8, 256, 0, stream>>>(hb1, W2, at_s2, at_d2, h2b, as2, ad2, N);
    k_agg2 <<<(N+3)/4, 256, 0, stream>>>(h2b, as2, ad2, offs, bsrc, b2, exb, outp, N);
}